// Round 6
// baseline (2128.828 us; speedup 1.0000x reference)
//
#include <hip/hip_runtime.h>
#include <math.h>

#define B_  256
#define T_  48
#define D_  89
#define H_  128
#define C_  64
#define NH_ 8
#define HD_ 8
#define N2T 96   // 2*T

// output layout (floats)
#define XIMP_OFF 0
#define LOSS_OFF 1093632
#define HID_OFF  1093633
#define Y_OFF    2666497
#define YS_OFF   2666753

typedef unsigned int uint_t;

__device__ __forceinline__ float wave_sum64(float v) {
    v += __shfl_xor(v, 32);
    v += __shfl_xor(v, 16);
    v += __shfl_xor(v, 8);
    v += __shfl_xor(v, 4);
    v += __shfl_xor(v, 2);
    v += __shfl_xor(v, 1);
    return v;
}

// pack two f32 into bf16x2 (RNE)
__device__ __forceinline__ uint_t pack2(float lo, float hi) {
    uint_t a = __float_as_uint(lo), b = __float_as_uint(hi);
    a = (a + 0x7fffu + ((a >> 16) & 1u)) >> 16;
    b = (b + 0x7fffu + ((b >> 16) & 1u)) >> 16;
    return a | (b << 16);
}
__device__ __forceinline__ float blo(uint_t w) { return __uint_as_float(w << 16); }
__device__ __forceinline__ float bhi(uint_t w) { return __uint_as_float(w & 0xffff0000u); }
__device__ __forceinline__ float sigm(float v) { return 1.f / (1.f + __expf(-v)); }

// 4-fma helper on a float4 against 2 packed uints
#define FMA4(v, w0, w1) do { \
    a0 = fmaf((v).x, blo(w0), a0); \
    a1 = fmaf((v).y, bhi(w0), a1); \
    a0 = fmaf((v).z, blo(w1), a0); \
    a1 = fmaf((v).w, bhi(w1), a1); } while (0)

// ---------------- prep: f32 transposes for the transformer-phase kernels only
__device__ __forceinline__ void tr_f32(const float* __restrict__ s, float* __restrict__ d,
                                       int li, int R, int C) {
    int r = li / C, c = li - r * C;
    d[c * R + r] = s[li];
}

__global__ void k_prep(const float* W_wo, const float* W_inp, const float* ain_w,
                       const float* aout_w, const float* ff1_w, const float* ff2_w,
                       const float* W_op1,
                       float* W_woT, float* W_inpT, float* ain_T,
                       float* aout_T, float* ff1_T, float* ff2_T, float* op1_T) {
    int i = blockIdx.x * 256 + threadIdx.x;
    if (i < 7921)         tr_f32(W_wo,   W_woT,  i,          89, 89);
    else if (i < 13617)   tr_f32(W_inp,  W_inpT, i - 7921,   64, 89);
    else if (i < 25905)   tr_f32(ain_w,  ain_T,  i - 13617, 192, 64);
    else if (i < 30001)   tr_f32(aout_w, aout_T, i - 25905,  64, 64);
    else if (i < 34097)   tr_f32(ff1_w,  ff1_T,  i - 30001,  64, 64);
    else if (i < 38193)   tr_f32(ff2_w,  ff2_T,  i - 34097,  64, 64);
    else if (i < 46385)   tr_f32(W_op1,  op1_T,  i - 38193, 128, 64);
}

// ---------------- Phase A
__global__ void k_phaseA(const float* __restrict__ last_obs,
                         const float* __restrict__ deltas,
                         const float* __restrict__ medians,
                         const float* __restrict__ W_woT, const float* __restrict__ b_wo,
                         const float* __restrict__ W_inpT, const float* __restrict__ b_inp,
                         float* __restrict__ data) {
    int bt = blockIdx.x;
    int b = bt / T_;
    int t = bt - b * T_;
    __shared__ float dd[D_], lo[D_], dec[D_];
    int tid = threadIdx.x;
    int base = (b * T_ + t) * D_;
    if (tid < D_) {
        float dv = deltas[base + tid] - medians[tid];
        dd[tid] = dv;
        lo[tid] = last_obs[base + tid];
    }
    __syncthreads();
    if (tid < D_) {
        float acc = b_wo[tid];
        for (int j = 0; j < D_; ++j) acc = fmaf(dd[j], W_woT[j * D_ + tid], acc);
        float dv = dd[tid];
        float s = (dv > 0.f) ? 1.f : ((dv < 0.f) ? -1.f : 0.f);
        dec[tid] = 0.5f * (1.f - tanhf(s * fabsf(acc)));
    }
    __syncthreads();
    int c = tid & 63;
    int half = tid >> 6;
    const float* src = half ? dec : lo;
    float acc = b_inp[c];
    for (int j = 0; j < D_; ++j) acc = fmaf(src[j], W_inpT[j * C_ + c], acc);
    int i = c >> 1;
    float div = __expf((float)i * -0.28782313662425574f);
    float ang = (float)t * div;
    float pe = (c & 1) ? cosf(ang) : sinf(ang);
    data[((b * N2T) + half * T_ + t) * C_ + c] = acc + pe;
}

// ---------------- qkv
__global__ void k_qkv(const float* __restrict__ data,
                      const float* __restrict__ ain_T, const float* __restrict__ ain_b,
                      float* __restrict__ qb, float* __restrict__ kb, float* __restrict__ vb) {
    int bn = blockIdx.x;
    int s = bn / N2T;
    int n = bn - s * N2T;
    __shared__ float row[C_];
    int tid = threadIdx.x;
    if (tid < C_) row[tid] = data[bn * C_ + tid];
    __syncthreads();
    float acc = ain_b[tid];
    for (int j = 0; j < C_; ++j) acc = fmaf(row[j], ain_T[j * 192 + tid], acc);
    int part = tid >> 6;
    int c = tid & 63;
    int h = c >> 3, d = c & 7;
    float* dst = (part == 0) ? qb : ((part == 1) ? kb : vb);
    dst[(((n * NH_ + h) * B_ + s) * HD_) + d] = acc;
}

// ---------------- attention
__global__ void k_attn(const float* __restrict__ qb, const float* __restrict__ kb,
                       const float* __restrict__ vb, float* __restrict__ attnO) {
    int n = blockIdx.x >> 3;
    int h = blockIdx.x & 7;
    __shared__ float k_lds[B_][HD_ + 1];
    __shared__ float v_lds[B_][HD_ + 1];
    int s = threadIdx.x;
    const float scale = 0.35355339059327373f;
    size_t base = ((size_t)blockIdx.x * B_ + s) * HD_;
    float q[HD_];
    #pragma unroll
    for (int d = 0; d < HD_; ++d) q[d] = qb[base + d] * scale;
    #pragma unroll
    for (int d = 0; d < HD_; ++d) { k_lds[s][d] = kb[base + d]; v_lds[s][d] = vb[base + d]; }
    __syncthreads();
    float m = -1e30f;
    for (int t = 0; t < B_; ++t) {
        float sc = 0.f;
        #pragma unroll
        for (int d = 0; d < HD_; ++d) sc = fmaf(q[d], k_lds[t][d], sc);
        m = fmaxf(m, sc);
    }
    float l = 0.f;
    float acc[HD_] = {0.f, 0.f, 0.f, 0.f, 0.f, 0.f, 0.f, 0.f};
    for (int t = 0; t < B_; ++t) {
        float sc = 0.f;
        #pragma unroll
        for (int d = 0; d < HD_; ++d) sc = fmaf(q[d], k_lds[t][d], sc);
        float p = __expf(sc - m);
        l += p;
        #pragma unroll
        for (int d = 0; d < HD_; ++d) acc[d] = fmaf(p, v_lds[t][d], acc[d]);
    }
    float inv = 1.f / l;
    float* op = attnO + ((size_t)s * N2T + n) * C_ + h * HD_;
    #pragma unroll
    for (int d = 0; d < HD_; ++d) op[d] = acc[d] * inv;
}

// ---------------- transformer post-attn
__global__ void k_transform(const float* __restrict__ data,
                            const float* __restrict__ attnO,
                            const float* __restrict__ aout_T, const float* __restrict__ aout_b,
                            const float* __restrict__ ln1_g, const float* __restrict__ ln1_b,
                            const float* __restrict__ ff1_T, const float* __restrict__ ff1_b,
                            const float* __restrict__ ff2_T, const float* __restrict__ ff2_b,
                            const float* __restrict__ ln2_g, const float* __restrict__ ln2_b,
                            const float* __restrict__ op1_T, const float* __restrict__ b_op1,
                            float* __restrict__ val) {
    int bn = blockIdx.x;
    __shared__ float orow[C_], x1s[C_], hbuf[C_], x2s[C_];
    int c = threadIdx.x;
    float d0 = data[bn * C_ + c];
    orow[c] = attnO[bn * C_ + c];
    __syncthreads();
    float acc = aout_b[c];
    for (int j = 0; j < C_; ++j) acc = fmaf(orow[j], aout_T[j * C_ + c], acc);
    float r = d0 + acc;
    float mean = wave_sum64(r) * (1.f / 64.f);
    float df = r - mean;
    float var = wave_sum64(df * df) * (1.f / 64.f);
    float x1 = df * rsqrtf(var + 1e-5f) * ln1_g[c] + ln1_b[c];
    x1s[c] = x1;
    __syncthreads();
    acc = ff1_b[c];
    for (int j = 0; j < C_; ++j) acc = fmaf(x1s[j], ff1_T[j * C_ + c], acc);
    float ge = 0.5f * acc * (1.f + erff(acc * 0.7071067811865475f));
    hbuf[c] = ge;
    __syncthreads();
    acc = ff2_b[c];
    for (int j = 0; j < C_; ++j) acc = fmaf(hbuf[j], ff2_T[j * C_ + c], acc);
    float r2 = x1 + acc;
    float mean2 = wave_sum64(r2) * (1.f / 64.f);
    float df2 = r2 - mean2;
    float var2 = wave_sum64(df2 * df2) * (1.f / 64.f);
    float x2 = df2 * rsqrtf(var2 + 1e-5f) * ln2_g[c] + ln2_b[c];
    x2s[c] = x2;
    __syncthreads();
    #pragma unroll
    for (int rep = 0; rep < 2; ++rep) {
        int k = c + rep * 64;
        float a2 = b_op1[k];
        for (int j = 0; j < C_; ++j) a2 = fmaf(x2s[j], op1_T[j * H_ + k], a2);
        val[(size_t)bn * H_ + k] = a2;
    }
}

// ---------------- h0 reduce
__global__ void k_reduce_h0(const float* __restrict__ val,
                            const float* __restrict__ W_op2, const float* __restrict__ b_op2,
                            float* __restrict__ h0) {
    int b = blockIdx.x;
    int h = threadIdx.x;
    float acc = b_op2[0];
    for (int n = 0; n < N2T; ++n)
        acc = fmaf(val[((size_t)b * N2T + n) * H_ + h], W_op2[n], acc);
    h0[b * H_ + h] = acc;
}

// ---------------- per-step mask denominator
__global__ void k_den(const float* __restrict__ mask, float* __restrict__ den) {
    int t = blockIdx.x;
    int tid = threadIdx.x;
    float s = 0.f;
    const int total = B_ * D_;
    for (int i = tid; i < total; i += 256) {
        int b = i / D_;
        int d = i - b * D_;
        s += mask[(b * T_ + t) * D_ + d];
    }
    s = wave_sum64(s);
    __shared__ float red[4];
    if ((tid & 63) == 0) red[tid >> 6] = s;
    __syncthreads();
    if (tid == 0) den[t] = red[0] + red[1] + red[2] + red[3];
}

// ---------------- recurrent scan: 256 blocks x 1024 threads, 1 batch elem/block.
// All six scan matrices bf16-packed in VGPRs, <=101 uints/thread.
// KEY FIX vs round 5: amdgpu_waves_per_eu(4,4) pins the allocator at
// 4 waves/SIMD (the only config a 1024-thread resident block can have),
// unlocking the full 128-VGPR budget so wreg[] stays register-resident
// instead of spilling to scratch (round 5: VGPR_Count=64, FETCH=1.9GB).
__global__ __launch_bounds__(1024) __attribute__((amdgpu_waves_per_eu(4, 4)))
void k_scan(const float* __restrict__ x, const float* __restrict__ mask,
            const float* __restrict__ deltas,
            const float* __restrict__ W_dh, const float* __restrict__ b_dh,
            const float* __restrict__ W_dx, const float* __restrict__ b_dx,
            const float* __restrict__ W_hist, const float* __restrict__ b_hist,
            const float* __restrict__ W_feat, const float* __restrict__ b_feat,
            const float* __restrict__ W_wc, const float* __restrict__ b_wc,
            const float* __restrict__ W_ih, const float* __restrict__ W_hh,
            const float* __restrict__ b_ih, const float* __restrict__ b_hh,
            const float* __restrict__ W_cls, const float* __restrict__ b_cls,
            const float* __restrict__ h0,
            float* __restrict__ out, float* __restrict__ num_part) {
    int b = blockIdx.x;
    int tid = threadIdx.x;

    __shared__ __align__(16) float h_s[H_];
    __shared__ __align__(16) float xt_s[92];
    __shared__ __align__(16) float dt_s[92];
    __shared__ __align__(16) float xr_s[92];
    __shared__ __align__(16) float xh_s[92];
    __shared__ __align__(16) float catg_s[180];   // [ximp(89) | m(89)]
    __shared__ __align__(16) float catb_s[180];   // [gx(89)   | m(89)]
    __shared__ __align__(16) float gis_p[2][384], ghs_p[2][384];
    __shared__ float p2[2][92], p3xu[2][92], p3b[3][92];
    __shared__ float diff_s[92];

    uint_t wreg[101];
    float bias0 = 0.f, bias1 = 0.f, bias2 = 0.f, dxw = 0.f, dxb = 0.f;

    if (tid < 384) {                       // A
        const float* wi = W_ih + (size_t)tid * 178;
        #pragma unroll
        for (int j = 0; j < 44; ++j) wreg[j] = pack2(wi[2 * j], wi[2 * j + 1]);
        const float* wh = W_hh + (size_t)tid * 128;
        #pragma unroll
        for (int j = 0; j < 32; ++j) wreg[44 + j] = pack2(wh[2 * j], wh[2 * j + 1]);
        bias0 = b_ih[tid];
        bias1 = b_hh[tid];
        if (tid < 89) {
            const float* wc = W_wc + (size_t)tid * 178;
            #pragma unroll
            for (int j = 0; j < 24; ++j) wreg[76 + j] = pack2(wc[96 + 2 * j], wc[97 + 2 * j]);
        }
        if (tid < 128) h_s[tid] = h0[b * H_ + tid];
    } else if (tid < 768) {                // B
        int o = tid - 384;
        const float* wi = W_ih + (size_t)o * 178;
        #pragma unroll
        for (int j = 0; j < 45; ++j) wreg[j] = pack2(wi[88 + 2 * j], wi[89 + 2 * j]);
        const float* wh = W_hh + (size_t)o * 128;
        #pragma unroll
        for (int j = 0; j < 32; ++j) wreg[45 + j] = pack2(wh[64 + 2 * j], wh[65 + 2 * j]);
        if (o < 89) {
            const float* wc = W_wc + (size_t)o * 178;
            #pragma unroll
            for (int j = 0; j < 17; ++j) wreg[77 + j] = pack2(wc[144 + 2 * j], wc[145 + 2 * j]);
        }
    } else if (tid < 896) {                // C
        int r = tid - 768;
        const float* wd = W_dh + r * 89;
        #pragma unroll
        for (int j = 0; j < 44; ++j) wreg[j] = pack2(wd[2 * j], wd[2 * j + 1]);
        wreg[44] = pack2(wd[88], 0.f);
        bias0 = b_dh[r];
        if (r < 89) {
            const float* wh = W_hist + r * 128;
            #pragma unroll
            for (int j = 0; j < 32; ++j) wreg[45 + j] = pack2(wh[64 + 2 * j], wh[65 + 2 * j]);
            const float* wf = W_feat + r * 89;
            #pragma unroll
            for (int j = 0; j < 24; ++j) {
                float lo = (2 * j == r) ? 0.f : wf[2 * j];
                float hi = (2 * j + 1 == r) ? 0.f : wf[2 * j + 1];
                wreg[77 + j] = pack2(lo, hi);
            }
            bias1 = b_feat[r];
            bias2 = b_wc[r];
        }
    } else {                               // D
        int r = tid - 896;
        if (r < 89) {
            const float* wh = W_hist + r * 128;
            #pragma unroll
            for (int j = 0; j < 32; ++j) wreg[j] = pack2(wh[2 * j], wh[2 * j + 1]);
            const float* wc = W_wc + (size_t)r * 178;
            #pragma unroll
            for (int j = 0; j < 24; ++j) wreg[32 + j] = pack2(wc[2 * j], wc[2 * j + 1]);
            #pragma unroll
            for (int j = 0; j < 24; ++j) wreg[56 + j] = pack2(wc[48 + 2 * j], wc[49 + 2 * j]);
            const float* wf = W_feat + r * 89;
            #pragma unroll
            for (int j = 0; j < 20; ++j) {
                float lo = (48 + 2 * j == r) ? 0.f : wf[48 + 2 * j];
                float hi = (49 + 2 * j == r) ? 0.f : wf[49 + 2 * j];
                wreg[80 + j] = pack2(lo, hi);
            }
            wreg[100] = pack2((r == 88) ? 0.f : wf[88], 0.f);
            bias0 = b_hist[r];
            dxw = W_dx[r * 90];
            dxb = b_dx[r];
        }
    }
    // prologue t=0 activations
    {
        int base = b * T_ * D_;
        if (tid >= 128 && tid < 217) xt_s[tid - 128] = x[base + tid - 128];
        else if (tid >= 224 && tid < 313) {
            float m = mask[base + tid - 224];
            catg_s[89 + tid - 224] = m;
            catb_s[89 + tid - 224] = m;
        }
        else if (tid >= 320 && tid < 409) dt_s[tid - 320] = deltas[base + tid - 320];
    }
    __syncthreads();

    for (int t = 0; t < T_; ++t) {
        // ---- P1: gamma_h decay (C, 128 threads)
        if (tid >= 768 && tid < 896) {
            int r = tid - 768;
            const float4* d4 = (const float4*)dt_s;
            float a0 = 0.f, a1 = 0.f;
            #pragma unroll
            for (int q = 0; q < 22; ++q) FMA4(d4[q], wreg[2 * q], wreg[2 * q + 1]);
            a0 = fmaf(dt_s[88], blo(wreg[44]), a0);
            h_s[r] *= __expf(-fmaxf(bias0 + a0 + a1, 0.f));
        }
        __syncthreads();
        // ---- P2a: x_h partials (D: h[0:64], C: h[64:128])
        if (tid >= 896 && tid < 985) {
            int r = tid - 896;
            const float4* h4 = (const float4*)h_s;
            float a0 = 0.f, a1 = 0.f;
            #pragma unroll
            for (int q = 0; q < 16; ++q) FMA4(h4[q], wreg[2 * q], wreg[2 * q + 1]);
            p2[0][r] = a0 + a1;
        } else if (tid >= 768 && tid < 857) {
            int r = tid - 768;
            const float4* h4 = (const float4*)(h_s + 64);
            float a0 = 0.f, a1 = 0.f;
            #pragma unroll
            for (int q = 0; q < 16; ++q) FMA4(h4[q], wreg[45 + 2 * q], wreg[46 + 2 * q]);
            p2[1][r] = a0 + a1;
        }
        __syncthreads();
        // ---- P2b: combine -> xh, xr, gx (D)
        if (tid >= 896 && tid < 985) {
            int r = tid - 896;
            float xh = p2[0][r] + p2[1][r] + bias0;
            xh_s[r] = xh;
            float m = catb_s[89 + r];
            xr_s[r] = m * xt_s[r] + (1.f - m) * xh;
            catb_s[r] = __expf(-fmaxf(dt_s[r] * dxw + dxb, 0.f));
        }
        __syncthreads();
        // ---- P3a: xu + beta partials
        if (tid < 89) {                                   // A: W_wc q2 (catb 96..143)
            const float4* c4 = (const float4*)(catb_s + 96);
            float a0 = 0.f, a1 = 0.f;
            #pragma unroll
            for (int q = 0; q < 12; ++q) FMA4(c4[q], wreg[76 + 2 * q], wreg[77 + 2 * q]);
            p3b[1][tid] = a0 + a1;
        } else if (tid >= 384 && tid < 473) {             // B: W_wc q3 (catb 144..177)
            int r = tid - 384;
            const float4* c4 = (const float4*)(catb_s + 144);
            float a0 = 0.f, a1 = 0.f;
            #pragma unroll
            for (int q = 0; q < 8; ++q) FMA4(c4[q], wreg[77 + 2 * q], wreg[78 + 2 * q]);
            float2 v2 = *(const float2*)(catb_s + 176);
            uint_t w = wreg[93];
            a0 = fmaf(v2.x, blo(w), a0);
            a1 = fmaf(v2.y, bhi(w), a1);
            p3b[2][r] = a0 + a1;
        } else if (tid >= 768 && tid < 857) {             // C: W_feat f0 (xr 0..47)
            int r = tid - 768;
            const float4* x4 = (const float4*)xr_s;
            float a0 = 0.f, a1 = 0.f;
            #pragma unroll
            for (int q = 0; q < 12; ++q) FMA4(x4[q], wreg[77 + 2 * q], wreg[78 + 2 * q]);
            p3xu[0][r] = a0 + a1;
        } else if (tid >= 896 && tid < 985) {             // D: W_feat f1 + W_wc q0+q1
            int r = tid - 896;
            const float4* x4 = (const float4*)(xr_s + 48);
            float a0 = 0.f, a1 = 0.f;
            #pragma unroll
            for (int q = 0; q < 10; ++q) FMA4(x4[q], wreg[80 + 2 * q], wreg[81 + 2 * q]);
            a0 = fmaf(xr_s[88], blo(wreg[100]), a0);
            p3xu[1][r] = a0 + a1;
            const float4* c4 = (const float4*)catb_s;
            a0 = 0.f; a1 = 0.f;
            #pragma unroll
            for (int q = 0; q < 12; ++q) FMA4(c4[q], wreg[32 + 2 * q], wreg[33 + 2 * q]);
            const float4* c4b = (const float4*)(catb_s + 48);
            #pragma unroll
            for (int q = 0; q < 12; ++q) FMA4(c4b[q], wreg[56 + 2 * q], wreg[57 + 2 * q]);
            p3b[0][r] = a0 + a1;
        }
        __syncthreads();
        // ---- P3b: combine -> x_comb, x_imp, diff (C)
        if (tid >= 768 && tid < 857) {
            int r = tid - 768;
            float xu = p3xu[0][r] + p3xu[1][r] + bias1;
            float beta = p3b[0][r] + p3b[1][r] + p3b[2][r] + bias2;
            float xc = beta * xu + (1.f - beta) * xh_s[r];
            float m = catb_s[89 + r];
            float xtv = xt_s[r];
            float xi = m * xtv + (1.f - m) * xc;
            catg_s[r] = xi;
            out[XIMP_OFF + (b * T_ + t) * D_ + r] = xi;
            diff_s[r] = fabsf(xtv - xc) * m;
        }
        __syncthreads();
        // ---- P4: gi/gh partials (A,B) + loss reduce (wave 15) + next-t loads (C, D w14)
        if (tid < 384) {
            const float4* g4 = (const float4*)catg_s;
            float a0 = 0.f, a1 = 0.f;
            #pragma unroll
            for (int q = 0; q < 22; ++q) FMA4(g4[q], wreg[2 * q], wreg[2 * q + 1]);
            gis_p[0][tid] = a0 + a1 + bias0;
            const float4* h4 = (const float4*)h_s;
            a0 = 0.f; a1 = 0.f;
            #pragma unroll
            for (int q = 0; q < 16; ++q) FMA4(h4[q], wreg[44 + 2 * q], wreg[45 + 2 * q]);
            ghs_p[0][tid] = a0 + a1 + bias1;
        } else if (tid < 768) {
            int o = tid - 384;
            const float4* g4 = (const float4*)(catg_s + 88);
            float a0 = 0.f, a1 = 0.f;
            #pragma unroll
            for (int q = 0; q < 22; ++q) FMA4(g4[q], wreg[2 * q], wreg[2 * q + 1]);
            float2 v2 = *(const float2*)(catg_s + 176);
            uint_t w = wreg[44];
            a0 = fmaf(v2.x, blo(w), a0);
            a1 = fmaf(v2.y, bhi(w), a1);
            gis_p[1][o] = a0 + a1;
            const float4* h4 = (const float4*)(h_s + 64);
            a0 = 0.f; a1 = 0.f;
            #pragma unroll
            for (int q = 0; q < 16; ++q) FMA4(h4[q], wreg[45 + 2 * q], wreg[46 + 2 * q]);
            ghs_p[1][o] = a0 + a1;
        } else if (tid >= 960) {
            int l = tid - 960;
            float s = diff_s[l];
            if (l < 25) s += diff_s[64 + l];
            s = wave_sum64(s);
            if (l == 0) num_part[t * B_ + b] = s;
        } else if (t + 1 < T_) {
            int base = (b * T_ + t + 1) * D_;
            if (tid < 896) {               // C: next xt + dt
                int r = tid - 768;
                if (r < 89) { xt_s[r] = x[base + r]; dt_s[r] = deltas[base + r]; }
            } else {                       // D wave 14: next m -> catb half
                int l = tid - 896;
                catb_s[89 + l] = mask[base + l];
                if (l < 25) catb_s[89 + 64 + l] = mask[base + 64 + l];
            }
        }
        __syncthreads();
        // ---- P5: GRU update + copy next-m into catg half
        if (tid < 128) {
            float r = sigm(gis_p[0][tid] + gis_p[1][tid] + ghs_p[0][tid] + ghs_p[1][tid]);
            float z = sigm(gis_p[0][128 + tid] + gis_p[1][128 + tid] +
                           ghs_p[0][128 + tid] + ghs_p[1][128 + tid]);
            float g = tanhf(gis_p[0][256 + tid] + gis_p[1][256 + tid] +
                            r * (ghs_p[0][256 + tid] + ghs_p[1][256 + tid]));
            float hn = (1.f - z) * g + z * h_s[tid];
            h_s[tid] = hn;
            out[HID_OFF + (size_t)(b * T_ + t) * H_ + tid] = hn;
        } else if (tid >= 128 && tid < 217 && t + 1 < T_) {
            int l = tid - 128;
            catg_s[89 + l] = catb_s[89 + l];
        }
        __syncthreads();
    }
    // classifier
    if (tid < 64) {
        float p = h_s[tid] * W_cls[tid] + h_s[tid + 64] * W_cls[tid + 64];
        p = wave_sum64(p);
        if (tid == 0) {
            float y = p + b_cls[0];
            out[Y_OFF + b] = y;
            out[YS_OFF + b] = 1.f / (1.f + __expf(-y));
        }
    }
}

// ---------------- final loss reduction
__global__ void k_loss(const float* __restrict__ num_part, const float* __restrict__ den,
                       float* __restrict__ out) {
    int tid = threadIdx.x;
    float v = 0.f;
    if (tid < T_) {
        float s = 0.f;
        const float* np_ = num_part + tid * B_;
        for (int b = 0; b < B_; ++b) s += np_[b];
        v = s / (den[tid] + 1e-5f);
    }
    v = wave_sum64(v);
    if (tid == 0) out[LOSS_OFF] = v;
}

extern "C" void kernel_launch(void* const* d_in, const int* in_sizes, int n_in,
                              void* d_out, int out_size, void* d_ws, size_t ws_size,
                              hipStream_t stream) {
    const float* x        = (const float*)d_in[0];
    const float* mask     = (const float*)d_in[1];
    const float* deltas   = (const float*)d_in[2];
    const float* last_obs = (const float*)d_in[3];
    const float* medians  = (const float*)d_in[4];
    const float* W_dh  = (const float*)d_in[5];
    const float* b_dh  = (const float*)d_in[6];
    const float* W_dx  = (const float*)d_in[7];
    const float* b_dx  = (const float*)d_in[8];
    const float* W_hist= (const float*)d_in[9];
    const float* b_hist= (const float*)d_in[10];
    const float* W_feat= (const float*)d_in[11];
    const float* b_feat= (const float*)d_in[12];
    const float* W_wc  = (const float*)d_in[13];
    const float* b_wc  = (const float*)d_in[14];
    const float* W_wo  = (const float*)d_in[15];
    const float* b_wo  = (const float*)d_in[16];
    const float* W_cls = (const float*)d_in[17];
    const float* b_cls = (const float*)d_in[18];
    const float* W_ih  = (const float*)d_in[19];
    const float* W_hh  = (const float*)d_in[20];
    const float* b_ih  = (const float*)d_in[21];
    const float* b_hh  = (const float*)d_in[22];
    const float* W_inp = (const float*)d_in[23];
    const float* b_inp = (const float*)d_in[24];
    const float* W_op1 = (const float*)d_in[25];
    const float* b_op1 = (const float*)d_in[26];
    const float* W_op2 = (const float*)d_in[27];
    const float* b_op2 = (const float*)d_in[28];
    const float* attn_in_w  = (const float*)d_in[29];
    const float* attn_in_b  = (const float*)d_in[30];
    const float* attn_out_w = (const float*)d_in[31];
    const float* attn_out_b = (const float*)d_in[32];
    const float* ln1_g = (const float*)d_in[33];
    const float* ln1_b = (const float*)d_in[34];
    const float* ln2_g = (const float*)d_in[35];
    const float* ln2_b = (const float*)d_in[36];
    const float* ff1_w = (const float*)d_in[37];
    const float* ff1_b = (const float*)d_in[38];
    const float* ff2_w = (const float*)d_in[39];
    const float* ff2_b = (const float*)d_in[40];

    float* out = (float*)d_out;
    float* ws = (float*)d_ws;

    float* data  = ws;
    float* qb    = data  + (size_t)B_ * N2T * C_;
    float* kb    = qb    + (size_t)N2T * NH_ * B_ * HD_;
    float* vb    = kb    + (size_t)N2T * NH_ * B_ * HD_;
    float* attnO = vb    + (size_t)N2T * NH_ * B_ * HD_;
    float* val   = attnO + (size_t)B_ * N2T * C_;
    float* h0    = val   + (size_t)B_ * N2T * H_;
    float* den   = h0    + (size_t)B_ * H_;
    float* nump  = den   + 64;
    float* W_woT = nump  + T_ * B_;
    float* W_inpT= W_woT + 7921;
    float* ain_T = W_inpT + 5696;
    float* aout_T= ain_T + 12288;
    float* ff1_T = aout_T + 4096;
    float* ff2_T = ff1_T + 4096;
    float* op1_T = ff2_T + 4096;

    k_prep<<<182, 256, 0, stream>>>(W_wo, W_inp, attn_in_w, attn_out_w, ff1_w, ff2_w, W_op1,
                                    W_woT, W_inpT, ain_T, aout_T, ff1_T, ff2_T, op1_T);
    k_phaseA<<<B_ * T_, 128, 0, stream>>>(last_obs, deltas, medians, W_woT, b_wo, W_inpT, b_inp, data);
    k_qkv<<<B_ * N2T, 192, 0, stream>>>(data, ain_T, attn_in_b, qb, kb, vb);
    k_attn<<<N2T * NH_, 256, 0, stream>>>(qb, kb, vb, attnO);
    k_transform<<<B_ * N2T, 64, 0, stream>>>(data, attnO, aout_T, attn_out_b,
                                             ln1_g, ln1_b, ff1_T, ff1_b, ff2_T, ff2_b,
                                             ln2_g, ln2_b, op1_T, b_op1, val);
    k_reduce_h0<<<B_, H_, 0, stream>>>(val, W_op2, b_op2, h0);
    k_den<<<T_, 256, 0, stream>>>(mask, den);
    k_scan<<<B_, 1024, 0, stream>>>(x, mask, deltas,
                                    W_dh, b_dh, W_dx, b_dx, W_hist, b_hist, W_feat, b_feat,
                                    W_wc, b_wc, W_ih, W_hh, b_ih, b_hh, W_cls, b_cls,
                                    h0, out, nump);
    k_loss<<<1, 64, 0, stream>>>(nump, den, out);
}

// Round 7
// 1624.066 us; speedup vs baseline: 1.3108x; 1.3108x over previous
//
#include <hip/hip_runtime.h>
#include <math.h>

#define B_  256
#define T_  48
#define D_  89
#define H_  128
#define C_  64
#define NH_ 8
#define HD_ 8
#define N2T 96   // 2*T

// output layout (floats)
#define XIMP_OFF 0
#define LOSS_OFF 1093632
#define HID_OFF  1093633
#define Y_OFF    2666497
#define YS_OFF   2666753

typedef unsigned int uint_t;
typedef uint_t u32x32 __attribute__((ext_vector_type(32)));
typedef uint_t u32x16 __attribute__((ext_vector_type(16)));

__device__ __forceinline__ float wave_sum64(float v) {
    v += __shfl_xor(v, 32);
    v += __shfl_xor(v, 16);
    v += __shfl_xor(v, 8);
    v += __shfl_xor(v, 4);
    v += __shfl_xor(v, 2);
    v += __shfl_xor(v, 1);
    return v;
}

// pack two f32 into bf16x2 (RNE)
__device__ __forceinline__ uint_t pack2(float lo, float hi) {
    uint_t a = __float_as_uint(lo), b = __float_as_uint(hi);
    a = (a + 0x7fffu + ((a >> 16) & 1u)) >> 16;
    b = (b + 0x7fffu + ((b >> 16) & 1u)) >> 16;
    return a | (b << 16);
}
__device__ __forceinline__ float blo(uint_t w) { return __uint_as_float(w << 16); }
__device__ __forceinline__ float bhi(uint_t w) { return __uint_as_float(w & 0xffff0000u); }
__device__ __forceinline__ float sigm(float v) { return 1.f / (1.f + __expf(-v)); }

// 4-fma helper on a float4 against 2 packed uints (accumulates into a0,a1)
#define FMA4(v, w0, w1) do { \
    a0 = fmaf((v).x, blo(w0), a0); \
    a1 = fmaf((v).y, bhi(w0), a1); \
    a0 = fmaf((v).z, blo(w1), a0); \
    a1 = fmaf((v).w, bhi(w1), a1); } while (0)

// ---------------- prep: f32 transposes for the transformer-phase kernels only
__device__ __forceinline__ void tr_f32(const float* __restrict__ s, float* __restrict__ d,
                                       int li, int R, int C) {
    int r = li / C, c = li - r * C;
    d[c * R + r] = s[li];
}

__global__ void k_prep(const float* W_wo, const float* W_inp, const float* ain_w,
                       const float* aout_w, const float* ff1_w, const float* ff2_w,
                       const float* W_op1,
                       float* W_woT, float* W_inpT, float* ain_T,
                       float* aout_T, float* ff1_T, float* ff2_T, float* op1_T) {
    int i = blockIdx.x * 256 + threadIdx.x;
    if (i < 7921)         tr_f32(W_wo,   W_woT,  i,          89, 89);
    else if (i < 13617)   tr_f32(W_inp,  W_inpT, i - 7921,   64, 89);
    else if (i < 25905)   tr_f32(ain_w,  ain_T,  i - 13617, 192, 64);
    else if (i < 30001)   tr_f32(aout_w, aout_T, i - 25905,  64, 64);
    else if (i < 34097)   tr_f32(ff1_w,  ff1_T,  i - 30001,  64, 64);
    else if (i < 38193)   tr_f32(ff2_w,  ff2_T,  i - 34097,  64, 64);
    else if (i < 46385)   tr_f32(W_op1,  op1_T,  i - 38193, 128, 64);
}

// ---------------- Phase A
__global__ void k_phaseA(const float* __restrict__ last_obs,
                         const float* __restrict__ deltas,
                         const float* __restrict__ medians,
                         const float* __restrict__ W_woT, const float* __restrict__ b_wo,
                         const float* __restrict__ W_inpT, const float* __restrict__ b_inp,
                         float* __restrict__ data) {
    int bt = blockIdx.x;
    int b = bt / T_;
    int t = bt - b * T_;
    __shared__ float dd[D_], lo[D_], dec[D_];
    int tid = threadIdx.x;
    int base = (b * T_ + t) * D_;
    if (tid < D_) {
        float dv = deltas[base + tid] - medians[tid];
        dd[tid] = dv;
        lo[tid] = last_obs[base + tid];
    }
    __syncthreads();
    if (tid < D_) {
        float acc = b_wo[tid];
        for (int j = 0; j < D_; ++j) acc = fmaf(dd[j], W_woT[j * D_ + tid], acc);
        float dv = dd[tid];
        float s = (dv > 0.f) ? 1.f : ((dv < 0.f) ? -1.f : 0.f);
        dec[tid] = 0.5f * (1.f - tanhf(s * fabsf(acc)));
    }
    __syncthreads();
    int c = tid & 63;
    int half = tid >> 6;
    const float* src = half ? dec : lo;
    float acc = b_inp[c];
    for (int j = 0; j < D_; ++j) acc = fmaf(src[j], W_inpT[j * C_ + c], acc);
    int i = c >> 1;
    float div = __expf((float)i * -0.28782313662425574f);
    float ang = (float)t * div;
    float pe = (c & 1) ? cosf(ang) : sinf(ang);
    data[((b * N2T) + half * T_ + t) * C_ + c] = acc + pe;
}

// ---------------- qkv
__global__ void k_qkv(const float* __restrict__ data,
                      const float* __restrict__ ain_T, const float* __restrict__ ain_b,
                      float* __restrict__ qb, float* __restrict__ kb, float* __restrict__ vb) {
    int bn = blockIdx.x;
    int s = bn / N2T;
    int n = bn - s * N2T;
    __shared__ float row[C_];
    int tid = threadIdx.x;
    if (tid < C_) row[tid] = data[bn * C_ + tid];
    __syncthreads();
    float acc = ain_b[tid];
    for (int j = 0; j < C_; ++j) acc = fmaf(row[j], ain_T[j * 192 + tid], acc);
    int part = tid >> 6;
    int c = tid & 63;
    int h = c >> 3, d = c & 7;
    float* dst = (part == 0) ? qb : ((part == 1) ? kb : vb);
    dst[(((n * NH_ + h) * B_ + s) * HD_) + d] = acc;
}

// ---------------- attention
__global__ void k_attn(const float* __restrict__ qb, const float* __restrict__ kb,
                       const float* __restrict__ vb, float* __restrict__ attnO) {
    int n = blockIdx.x >> 3;
    int h = blockIdx.x & 7;
    __shared__ float k_lds[B_][HD_ + 1];
    __shared__ float v_lds[B_][HD_ + 1];
    int s = threadIdx.x;
    const float scale = 0.35355339059327373f;
    size_t base = ((size_t)blockIdx.x * B_ + s) * HD_;
    float q[HD_];
    #pragma unroll
    for (int d = 0; d < HD_; ++d) q[d] = qb[base + d] * scale;
    #pragma unroll
    for (int d = 0; d < HD_; ++d) { k_lds[s][d] = kb[base + d]; v_lds[s][d] = vb[base + d]; }
    __syncthreads();
    float m = -1e30f;
    for (int t = 0; t < B_; ++t) {
        float sc = 0.f;
        #pragma unroll
        for (int d = 0; d < HD_; ++d) sc = fmaf(q[d], k_lds[t][d], sc);
        m = fmaxf(m, sc);
    }
    float l = 0.f;
    float acc[HD_] = {0.f, 0.f, 0.f, 0.f, 0.f, 0.f, 0.f, 0.f};
    for (int t = 0; t < B_; ++t) {
        float sc = 0.f;
        #pragma unroll
        for (int d = 0; d < HD_; ++d) sc = fmaf(q[d], k_lds[t][d], sc);
        float p = __expf(sc - m);
        l += p;
        #pragma unroll
        for (int d = 0; d < HD_; ++d) acc[d] = fmaf(p, v_lds[t][d], acc[d]);
    }
    float inv = 1.f / l;
    float* op = attnO + ((size_t)s * N2T + n) * C_ + h * HD_;
    #pragma unroll
    for (int d = 0; d < HD_; ++d) op[d] = acc[d] * inv;
}

// ---------------- transformer post-attn
__global__ void k_transform(const float* __restrict__ data,
                            const float* __restrict__ attnO,
                            const float* __restrict__ aout_T, const float* __restrict__ aout_b,
                            const float* __restrict__ ln1_g, const float* __restrict__ ln1_b,
                            const float* __restrict__ ff1_T, const float* __restrict__ ff1_b,
                            const float* __restrict__ ff2_T, const float* __restrict__ ff2_b,
                            const float* __restrict__ ln2_g, const float* __restrict__ ln2_b,
                            const float* __restrict__ op1_T, const float* __restrict__ b_op1,
                            float* __restrict__ val) {
    int bn = blockIdx.x;
    __shared__ float orow[C_], x1s[C_], hbuf[C_], x2s[C_];
    int c = threadIdx.x;
    float d0 = data[bn * C_ + c];
    orow[c] = attnO[bn * C_ + c];
    __syncthreads();
    float acc = aout_b[c];
    for (int j = 0; j < C_; ++j) acc = fmaf(orow[j], aout_T[j * C_ + c], acc);
    float r = d0 + acc;
    float mean = wave_sum64(r) * (1.f / 64.f);
    float df = r - mean;
    float var = wave_sum64(df * df) * (1.f / 64.f);
    float x1 = df * rsqrtf(var + 1e-5f) * ln1_g[c] + ln1_b[c];
    x1s[c] = x1;
    __syncthreads();
    acc = ff1_b[c];
    for (int j = 0; j < C_; ++j) acc = fmaf(x1s[j], ff1_T[j * C_ + c], acc);
    float ge = 0.5f * acc * (1.f + erff(acc * 0.7071067811865475f));
    hbuf[c] = ge;
    __syncthreads();
    acc = ff2_b[c];
    for (int j = 0; j < C_; ++j) acc = fmaf(hbuf[j], ff2_T[j * C_ + c], acc);
    float r2 = x1 + acc;
    float mean2 = wave_sum64(r2) * (1.f / 64.f);
    float df2 = r2 - mean2;
    float var2 = wave_sum64(df2 * df2) * (1.f / 64.f);
    float x2 = df2 * rsqrtf(var2 + 1e-5f) * ln2_g[c] + ln2_b[c];
    x2s[c] = x2;
    __syncthreads();
    #pragma unroll
    for (int rep = 0; rep < 2; ++rep) {
        int k = c + rep * 64;
        float a2 = b_op1[k];
        for (int j = 0; j < C_; ++j) a2 = fmaf(x2s[j], op1_T[j * H_ + k], a2);
        val[(size_t)bn * H_ + k] = a2;
    }
}

// ---------------- h0 reduce
__global__ void k_reduce_h0(const float* __restrict__ val,
                            const float* __restrict__ W_op2, const float* __restrict__ b_op2,
                            float* __restrict__ h0) {
    int b = blockIdx.x;
    int h = threadIdx.x;
    float acc = b_op2[0];
    for (int n = 0; n < N2T; ++n)
        acc = fmaf(val[((size_t)b * N2T + n) * H_ + h], W_op2[n], acc);
    h0[b * H_ + h] = acc;
}

// ---------------- per-step mask denominator
__global__ void k_den(const float* __restrict__ mask, float* __restrict__ den) {
    int t = blockIdx.x;
    int tid = threadIdx.x;
    float s = 0.f;
    const int total = B_ * D_;
    for (int i = tid; i < total; i += 256) {
        int b = i / D_;
        int d = i - b * D_;
        s += mask[(b * T_ + t) * D_ + d];
    }
    s = wave_sum64(s);
    __shared__ float red[4];
    if ((tid & 63) == 0) red[tid >> 6] = s;
    __syncthreads();
    if (tid == 0) den[t] = red[0] + red[1] + red[2] + red[3];
}

// ---------------- recurrent scan: 256 blocks x 1024 threads, 1 batch elem/block.
// W_ih/W_hh/W_dh/W_hist bf16-packed in NAMED ext-vector registers (v0,v1,v2 =
// 80 uints max; SSA values, bypassing PromoteAlloca which sent rounds 4-6's
// wreg[] arrays to scratch). W_feat/W_wc in LDS bf16. Wave-aligned roles:
//  A tid<384    : W_ih[o][0:88]->v0[0..31]+v1[0..11]; W_hh[o][0:64]->v1[12..31]+v2[0..11]
//  B 384..767   : W_ih[o][88:178]->v0+v1[0..11]+v2[12]; W_hh[o][64:128]->v1[12..31]+v2[0..11]
//  C 768..895   : W_dh[r]->v0+v1[0..11]+v2[12]; r<89: W_hist[r][64:128]->v1[12..31]+v2[0..11]
//  D 896..1023  : r<89: W_hist[r][0:64]->v0
__global__ __attribute__((amdgpu_flat_work_group_size(1024, 1024), amdgpu_waves_per_eu(4, 4)))
void k_scan(const float* __restrict__ x, const float* __restrict__ mask,
            const float* __restrict__ deltas,
            const float* __restrict__ W_dh, const float* __restrict__ b_dh,
            const float* __restrict__ W_dx, const float* __restrict__ b_dx,
            const float* __restrict__ W_hist, const float* __restrict__ b_hist,
            const float* __restrict__ W_feat, const float* __restrict__ b_feat,
            const float* __restrict__ W_wc, const float* __restrict__ b_wc,
            const float* __restrict__ W_ih, const float* __restrict__ W_hh,
            const float* __restrict__ b_ih, const float* __restrict__ b_hh,
            const float* __restrict__ W_cls, const float* __restrict__ b_cls,
            const float* __restrict__ h0,
            float* __restrict__ out, float* __restrict__ num_part) {
    int b = blockIdx.x;
    int tid = threadIdx.x;

    __shared__ __align__(16) float h_s[H_];
    __shared__ __align__(16) float xt_s[92];
    __shared__ __align__(16) float dt_s[92];
    __shared__ __align__(16) float xr_s[92];
    __shared__ __align__(16) float catg_s[180];   // [ximp(89) | m(89)]
    __shared__ __align__(16) float catb_s[180];   // [gx(89)   | m(89)]
    __shared__ __align__(16) float gis_p[2][384], ghs_p[2][384];
    __shared__ __align__(16) float p2[2][92];
    __shared__ float diff_s[92];
    __shared__ __align__(16) uint_t wwc_l[89 * 92];    // 32.7 KB, row stride 92 uints
    __shared__ __align__(16) uint_t wfeat_l[89 * 52];  // 18.5 KB, row stride 52 uints

    u32x32 v0 = (u32x32)0, v1 = (u32x32)0;
    u32x16 v2 = (u32x16)0;
    float bias0 = 0.f, bias1 = 0.f, bias2 = 0.f, biasF = 0.f, dxw = 0.f, dxb = 0.f;

    if (tid < 384) {                       // A
        const float* wi = W_ih + (size_t)tid * 178;
        #pragma unroll
        for (int j = 0; j < 32; ++j) v0[j] = pack2(wi[2 * j], wi[2 * j + 1]);
        #pragma unroll
        for (int j = 0; j < 12; ++j) v1[j] = pack2(wi[64 + 2 * j], wi[65 + 2 * j]);
        const float* wh = W_hh + (size_t)tid * 128;
        #pragma unroll
        for (int j = 0; j < 20; ++j) v1[12 + j] = pack2(wh[2 * j], wh[2 * j + 1]);
        #pragma unroll
        for (int j = 0; j < 12; ++j) v2[j] = pack2(wh[40 + 2 * j], wh[41 + 2 * j]);
        bias0 = b_ih[tid];
        bias1 = b_hh[tid];
        if (tid < 128) h_s[tid] = h0[b * H_ + tid];
    } else if (tid < 768) {                // B
        int o = tid - 384;
        const float* wi = W_ih + (size_t)o * 178;
        #pragma unroll
        for (int j = 0; j < 32; ++j) v0[j] = pack2(wi[88 + 2 * j], wi[89 + 2 * j]);
        #pragma unroll
        for (int j = 0; j < 12; ++j) v1[j] = pack2(wi[152 + 2 * j], wi[153 + 2 * j]);
        v2[12] = pack2(wi[176], wi[177]);
        const float* wh = W_hh + (size_t)o * 128;
        #pragma unroll
        for (int j = 0; j < 20; ++j) v1[12 + j] = pack2(wh[64 + 2 * j], wh[65 + 2 * j]);
        #pragma unroll
        for (int j = 0; j < 12; ++j) v2[j] = pack2(wh[104 + 2 * j], wh[105 + 2 * j]);
    } else if (tid < 896) {                // C
        int r = tid - 768;
        const float* wd = W_dh + r * 89;
        #pragma unroll
        for (int j = 0; j < 32; ++j) v0[j] = pack2(wd[2 * j], wd[2 * j + 1]);
        #pragma unroll
        for (int j = 0; j < 12; ++j) v1[j] = pack2(wd[64 + 2 * j], wd[65 + 2 * j]);
        v2[12] = pack2(wd[88], 0.f);
        bias0 = b_dh[r];
        if (r < 89) {
            const float* wh = W_hist + r * 128;
            #pragma unroll
            for (int j = 0; j < 20; ++j) v1[12 + j] = pack2(wh[64 + 2 * j], wh[65 + 2 * j]);
            #pragma unroll
            for (int j = 0; j < 12; ++j) v2[j] = pack2(wh[104 + 2 * j], wh[105 + 2 * j]);
        }
    } else {                               // D
        int r = tid - 896;
        if (r < 89) {
            const float* wh = W_hist + r * 128;
            #pragma unroll
            for (int j = 0; j < 32; ++j) v0[j] = pack2(wh[2 * j], wh[2 * j + 1]);
            bias1 = b_hist[r];
            biasF = b_feat[r];
            bias2 = b_wc[r];
            dxw = W_dx[r * 90];
            dxb = b_dx[r];
        }
    }
    // LDS weight staging (bf16): W_wc rows (stride 92), W_feat rows (stride 52, diag=0)
    for (int i = tid; i < 89 * 89; i += 1024) {
        int r = i / 89, c = i - r * 89;
        const float* wr = W_wc + (size_t)r * 178;
        wwc_l[r * 92 + c] = pack2(wr[2 * c], wr[2 * c + 1]);
    }
    for (int i = tid; i < 89 * 45; i += 1024) {
        int r = i / 45, c = i - r * 45;
        const float* wr = W_feat + r * 89;
        float lo, hi;
        if (c < 44) {
            lo = (2 * c == r) ? 0.f : wr[2 * c];
            hi = (2 * c + 1 == r) ? 0.f : wr[2 * c + 1];
        } else {
            lo = (88 == r) ? 0.f : wr[88];
            hi = 0.f;
        }
        wfeat_l[r * 52 + c] = pack2(lo, hi);
    }
    // prologue t=0 activations
    {
        int base = b * T_ * D_;
        if (tid >= 128 && tid < 217) xt_s[tid - 128] = x[base + tid - 128];
        else if (tid >= 224 && tid < 313) {
            float m = mask[base + tid - 224];
            catg_s[89 + tid - 224] = m;
            catb_s[89 + tid - 224] = m;
        }
        else if (tid >= 320 && tid < 409) dt_s[tid - 320] = deltas[base + tid - 320];
    }
    __syncthreads();

    for (int t = 0; t < T_; ++t) {
        // ---- P1: gamma_h decay (C: 128 threads, W_dh in v0/v1/v2)
        if (tid >= 768 && tid < 896) {
            int r = tid - 768;
            const float4* d4 = (const float4*)dt_s;
            float a0 = 0.f, a1 = 0.f;
            #pragma unroll
            for (int q = 0; q < 16; ++q) FMA4(d4[q], v0[2 * q], v0[2 * q + 1]);
            #pragma unroll
            for (int q = 0; q < 6; ++q) FMA4(d4[16 + q], v1[2 * q], v1[2 * q + 1]);
            a0 = fmaf(dt_s[88], blo(v2[12]), a0);
            h_s[r] *= __expf(-fmaxf(bias0 + a0 + a1, 0.f));
        }
        __syncthreads();
        // ---- P2a: x_h partials (D: h[0:64] via v0; C r<89: h[64:128] via v1/v2)
        if (tid >= 896 && tid < 985) {
            int r = tid - 896;
            const float4* h4 = (const float4*)h_s;
            float a0 = 0.f, a1 = 0.f;
            #pragma unroll
            for (int q = 0; q < 16; ++q) FMA4(h4[q], v0[2 * q], v0[2 * q + 1]);
            p2[0][r] = a0 + a1;
        } else if (tid >= 768 && tid < 857) {
            int r = tid - 768;
            const float4* h4 = (const float4*)(h_s + 64);
            float a0 = 0.f, a1 = 0.f;
            #pragma unroll
            for (int q = 0; q < 10; ++q) FMA4(h4[q], v1[12 + 2 * q], v1[13 + 2 * q]);
            #pragma unroll
            for (int q = 0; q < 6; ++q) FMA4(h4[10 + q], v2[2 * q], v2[2 * q + 1]);
            p2[1][r] = a0 + a1;
        }
        __syncthreads();
        // ---- P2b: combine -> xh (kept local), xr, gx (D)
        float xh_loc = 0.f, m_loc = 0.f, xt_loc = 0.f;
        if (tid >= 896 && tid < 985) {
            int r = tid - 896;
            xh_loc = p2[0][r] + p2[1][r] + bias1;
            m_loc = catb_s[89 + r];
            xt_loc = xt_s[r];
            xr_s[r] = m_loc * xt_loc + (1.f - m_loc) * xh_loc;
            catb_s[r] = __expf(-fmaxf(dt_s[r] * dxw + dxb, 0.f));
        }
        __syncthreads();
        // ---- P3: xu (W_feat LDS), beta (W_wc LDS), x_comb, x_imp, diff (D)
        if (tid >= 896 && tid < 985) {
            int r = tid - 896;
            const uint4* wf4 = (const uint4*)(wfeat_l + r * 52);
            const float4* x4 = (const float4*)xr_s;
            float a0 = 0.f, a1 = 0.f;
            #pragma unroll
            for (int q = 0; q < 11; ++q) {
                uint4 w = wf4[q];
                FMA4(x4[2 * q], w.x, w.y);
                FMA4(x4[2 * q + 1], w.z, w.w);
            }
            a0 = fmaf(xr_s[88], blo(wfeat_l[r * 52 + 44]), a0);
            float xu = a0 + a1 + biasF;
            const uint4* wc4 = (const uint4*)(wwc_l + r * 92);
            const float4* c4 = (const float4*)catb_s;
            a0 = 0.f; a1 = 0.f;
            #pragma unroll
            for (int q = 0; q < 22; ++q) {
                uint4 w = wc4[q];
                FMA4(c4[2 * q], w.x, w.y);
                FMA4(c4[2 * q + 1], w.z, w.w);
            }
            {
                float2 f2 = *(const float2*)(catb_s + 176);
                uint_t w = wwc_l[r * 92 + 88];
                a0 = fmaf(f2.x, blo(w), a0);
                a1 = fmaf(f2.y, bhi(w), a1);
            }
            float beta = a0 + a1 + bias2;
            float xc = beta * xu + (1.f - beta) * xh_loc;
            float xi = m_loc * xt_loc + (1.f - m_loc) * xc;
            catg_s[r] = xi;
            out[XIMP_OFF + (b * T_ + t) * D_ + r] = xi;
            diff_s[r] = fabsf(xt_loc - xc) * m_loc;
        }
        __syncthreads();
        // ---- P4: gi/gh partials (A,B) + loss reduce (wave 15) + next-t loads (C + wave 14)
        if (tid < 384) {
            const float4* g4 = (const float4*)catg_s;
            float a0 = 0.f, a1 = 0.f;
            #pragma unroll
            for (int q = 0; q < 16; ++q) FMA4(g4[q], v0[2 * q], v0[2 * q + 1]);
            #pragma unroll
            for (int q = 0; q < 6; ++q) FMA4(g4[16 + q], v1[2 * q], v1[2 * q + 1]);
            gis_p[0][tid] = a0 + a1 + bias0;
            const float4* h4 = (const float4*)h_s;
            a0 = 0.f; a1 = 0.f;
            #pragma unroll
            for (int q = 0; q < 10; ++q) FMA4(h4[q], v1[12 + 2 * q], v1[13 + 2 * q]);
            #pragma unroll
            for (int q = 0; q < 6; ++q) FMA4(h4[10 + q], v2[2 * q], v2[2 * q + 1]);
            ghs_p[0][tid] = a0 + a1 + bias1;
        } else if (tid < 768) {
            int o = tid - 384;
            const float4* g4 = (const float4*)(catg_s + 88);
            float a0 = 0.f, a1 = 0.f;
            #pragma unroll
            for (int q = 0; q < 16; ++q) FMA4(g4[q], v0[2 * q], v0[2 * q + 1]);
            #pragma unroll
            for (int q = 0; q < 6; ++q) FMA4(g4[16 + q], v1[2 * q], v1[2 * q + 1]);
            {
                float2 f2 = *(const float2*)(catg_s + 176);
                a0 = fmaf(f2.x, blo(v2[12]), a0);
                a1 = fmaf(f2.y, bhi(v2[12]), a1);
            }
            gis_p[1][o] = a0 + a1;
            const float4* h4 = (const float4*)(h_s + 64);
            a0 = 0.f; a1 = 0.f;
            #pragma unroll
            for (int q = 0; q < 10; ++q) FMA4(h4[q], v1[12 + 2 * q], v1[13 + 2 * q]);
            #pragma unroll
            for (int q = 0; q < 6; ++q) FMA4(h4[10 + q], v2[2 * q], v2[2 * q + 1]);
            ghs_p[1][o] = a0 + a1;
        } else if (tid >= 960) {
            int l = tid - 960;
            float s = diff_s[l];
            if (l < 25) s += diff_s[64 + l];
            s = wave_sum64(s);
            if (l == 0) num_part[t * B_ + b] = s;
        } else if (t + 1 < T_) {
            int base = (b * T_ + t + 1) * D_;
            if (tid < 896) {               // C: next xt + dt
                int r = tid - 768;
                if (r < 89) { xt_s[r] = x[base + r]; dt_s[r] = deltas[base + r]; }
            } else {                       // wave 14: next m -> catb half
                int l = tid - 896;
                catb_s[89 + l] = mask[base + l];
                if (l < 25) catb_s[89 + 64 + l] = mask[base + 64 + l];
            }
        }
        __syncthreads();
        // ---- P5: GRU update + copy next-m into catg half
        if (tid < 128) {
            float r = sigm(gis_p[0][tid] + gis_p[1][tid] + ghs_p[0][tid] + ghs_p[1][tid]);
            float z = sigm(gis_p[0][128 + tid] + gis_p[1][128 + tid] +
                           ghs_p[0][128 + tid] + ghs_p[1][128 + tid]);
            float g = tanhf(gis_p[0][256 + tid] + gis_p[1][256 + tid] +
                            r * (ghs_p[0][256 + tid] + ghs_p[1][256 + tid]));
            float hn = (1.f - z) * g + z * h_s[tid];
            h_s[tid] = hn;
            out[HID_OFF + (size_t)(b * T_ + t) * H_ + tid] = hn;
        } else if (tid >= 128 && tid < 217 && t + 1 < T_) {
            int l = tid - 128;
            catg_s[89 + l] = catb_s[89 + l];
        }
        __syncthreads();
    }
    // classifier
    if (tid < 64) {
        float p = h_s[tid] * W_cls[tid] + h_s[tid + 64] * W_cls[tid + 64];
        p = wave_sum64(p);
        if (tid == 0) {
            float y = p + b_cls[0];
            out[Y_OFF + b] = y;
            out[YS_OFF + b] = 1.f / (1.f + __expf(-y));
        }
    }
}

// ---------------- final loss reduction
__global__ void k_loss(const float* __restrict__ num_part, const float* __restrict__ den,
                       float* __restrict__ out) {
    int tid = threadIdx.x;
    float v = 0.f;
    if (tid < T_) {
        float s = 0.f;
        const float* np_ = num_part + tid * B_;
        for (int b = 0; b < B_; ++b) s += np_[b];
        v = s / (den[tid] + 1e-5f);
    }
    v = wave_sum64(v);
    if (tid == 0) out[LOSS_OFF] = v;
}

extern "C" void kernel_launch(void* const* d_in, const int* in_sizes, int n_in,
                              void* d_out, int out_size, void* d_ws, size_t ws_size,
                              hipStream_t stream) {
    const float* x        = (const float*)d_in[0];
    const float* mask     = (const float*)d_in[1];
    const float* deltas   = (const float*)d_in[2];
    const float* last_obs = (const float*)d_in[3];
    const float* medians  = (const float*)d_in[4];
    const float* W_dh  = (const float*)d_in[5];
    const float* b_dh  = (const float*)d_in[6];
    const float* W_dx  = (const float*)d_in[7];
    const float* b_dx  = (const float*)d_in[8];
    const float* W_hist= (const float*)d_in[9];
    const float* b_hist= (const float*)d_in[10];
    const float* W_feat= (const float*)d_in[11];
    const float* b_feat= (const float*)d_in[12];
    const float* W_wc  = (const float*)d_in[13];
    const float* b_wc  = (const float*)d_in[14];
    const float* W_wo  = (const float*)d_in[15];
    const float* b_wo  = (const float*)d_in[16];
    const float* W_cls = (const float*)d_in[17];
    const float* b_cls = (const float*)d_in[18];
    const float* W_ih  = (const float*)d_in[19];
    const float* W_hh  = (const float*)d_in[20];
    const float* b_ih  = (const float*)d_in[21];
    const float* b_hh  = (const float*)d_in[22];
    const float* W_inp = (const float*)d_in[23];
    const float* b_inp = (const float*)d_in[24];
    const float* W_op1 = (const float*)d_in[25];
    const float* b_op1 = (const float*)d_in[26];
    const float* W_op2 = (const float*)d_in[27];
    const float* b_op2 = (const float*)d_in[28];
    const float* attn_in_w  = (const float*)d_in[29];
    const float* attn_in_b  = (const float*)d_in[30];
    const float* attn_out_w = (const float*)d_in[31];
    const float* attn_out_b = (const float*)d_in[32];
    const float* ln1_g = (const float*)d_in[33];
    const float* ln1_b = (const float*)d_in[34];
    const float* ln2_g = (const float*)d_in[35];
    const float* ln2_b = (const float*)d_in[36];
    const float* ff1_w = (const float*)d_in[37];
    const float* ff1_b = (const float*)d_in[38];
    const float* ff2_w = (const float*)d_in[39];
    const float* ff2_b = (const float*)d_in[40];

    float* out = (float*)d_out;
    float* ws = (float*)d_ws;

    float* data  = ws;
    float* qb    = data  + (size_t)B_ * N2T * C_;
    float* kb    = qb    + (size_t)N2T * NH_ * B_ * HD_;
    float* vb    = kb    + (size_t)N2T * NH_ * B_ * HD_;
    float* attnO = vb    + (size_t)N2T * NH_ * B_ * HD_;
    float* val   = attnO + (size_t)B_ * N2T * C_;
    float* h0    = val   + (size_t)B_ * N2T * H_;
    float* den   = h0    + (size_t)B_ * H_;
    float* nump  = den   + 64;
    float* W_woT = nump  + T_ * B_;
    float* W_inpT= W_woT + 7921;
    float* ain_T = W_inpT + 5696;
    float* aout_T= ain_T + 12288;
    float* ff1_T = aout_T + 4096;
    float* ff2_T = ff1_T + 4096;
    float* op1_T = ff2_T + 4096;

    k_prep<<<182, 256, 0, stream>>>(W_wo, W_inp, attn_in_w, attn_out_w, ff1_w, ff2_w, W_op1,
                                    W_woT, W_inpT, ain_T, aout_T, ff1_T, ff2_T, op1_T);
    k_phaseA<<<B_ * T_, 128, 0, stream>>>(last_obs, deltas, medians, W_woT, b_wo, W_inpT, b_inp, data);
    k_qkv<<<B_ * N2T, 192, 0, stream>>>(data, ain_T, attn_in_b, qb, kb, vb);
    k_attn<<<N2T * NH_, 256, 0, stream>>>(qb, kb, vb, attnO);
    k_transform<<<B_ * N2T, 64, 0, stream>>>(data, attnO, aout_T, attn_out_b,
                                             ln1_g, ln1_b, ff1_T, ff1_b, ff2_T, ff2_b,
                                             ln2_g, ln2_b, op1_T, b_op1, val);
    k_reduce_h0<<<B_, H_, 0, stream>>>(val, W_op2, b_op2, h0);
    k_den<<<T_, 256, 0, stream>>>(mask, den);
    k_scan<<<B_, 1024, 0, stream>>>(x, mask, deltas,
                                    W_dh, b_dh, W_dx, b_dx, W_hist, b_hist, W_feat, b_feat,
                                    W_wc, b_wc, W_ih, W_hh, b_ih, b_hh, W_cls, b_cls,
                                    h0, out, nump);
    k_loss<<<1, 64, 0, stream>>>(nump, den, out);
}

// Round 8
// 1623.609 us; speedup vs baseline: 1.3112x; 1.0003x over previous
//
#include <hip/hip_runtime.h>
#include <math.h>

#define B_  256
#define T_  48
#define D_  89
#define H_  128
#define C_  64
#define NH_ 8
#define HD_ 8
#define N2T 96   // 2*T

// output layout (floats)
#define XIMP_OFF 0
#define LOSS_OFF 1093632
#define HID_OFF  1093633
#define Y_OFF    2666497
#define YS_OFF   2666753

typedef unsigned int uint_t;
typedef uint_t u32x32 __attribute__((ext_vector_type(32)));
typedef uint_t u32x16 __attribute__((ext_vector_type(16)));

__device__ __forceinline__ float wave_sum64(float v) {
    v += __shfl_xor(v, 32);
    v += __shfl_xor(v, 16);
    v += __shfl_xor(v, 8);
    v += __shfl_xor(v, 4);
    v += __shfl_xor(v, 2);
    v += __shfl_xor(v, 1);
    return v;
}

// pack two f32 into bf16x2 (RNE)
__device__ __forceinline__ uint_t pack2(float lo, float hi) {
    uint_t a = __float_as_uint(lo), b = __float_as_uint(hi);
    a = (a + 0x7fffu + ((a >> 16) & 1u)) >> 16;
    b = (b + 0x7fffu + ((b >> 16) & 1u)) >> 16;
    return a | (b << 16);
}
__device__ __forceinline__ float blo(uint_t w) { return __uint_as_float(w << 16); }
__device__ __forceinline__ float bhi(uint_t w) { return __uint_as_float(w & 0xffff0000u); }
__device__ __forceinline__ float sigm(float v) { return 1.f / (1.f + __expf(-v)); }

// 4-fma helper on a float4 against 2 packed uints (accumulates into a0,a1)
#define FMA4(v, w0, w1) do { \
    a0 = fmaf((v).x, blo(w0), a0); \
    a1 = fmaf((v).y, bhi(w0), a1); \
    a0 = fmaf((v).z, blo(w1), a0); \
    a1 = fmaf((v).w, bhi(w1), a1); } while (0)

// ---------------- prep: f32 transposes for the transformer-phase kernels only
__device__ __forceinline__ void tr_f32(const float* __restrict__ s, float* __restrict__ d,
                                       int li, int R, int C) {
    int r = li / C, c = li - r * C;
    d[c * R + r] = s[li];
}

__global__ void k_prep(const float* W_wo, const float* W_inp, const float* ain_w,
                       const float* aout_w, const float* ff1_w, const float* ff2_w,
                       const float* W_op1,
                       float* W_woT, float* W_inpT, float* ain_T,
                       float* aout_T, float* ff1_T, float* ff2_T, float* op1_T) {
    int i = blockIdx.x * 256 + threadIdx.x;
    if (i < 7921)         tr_f32(W_wo,   W_woT,  i,          89, 89);
    else if (i < 13617)   tr_f32(W_inp,  W_inpT, i - 7921,   64, 89);
    else if (i < 25905)   tr_f32(ain_w,  ain_T,  i - 13617, 192, 64);
    else if (i < 30001)   tr_f32(aout_w, aout_T, i - 25905,  64, 64);
    else if (i < 34097)   tr_f32(ff1_w,  ff1_T,  i - 30001,  64, 64);
    else if (i < 38193)   tr_f32(ff2_w,  ff2_T,  i - 34097,  64, 64);
    else if (i < 46385)   tr_f32(W_op1,  op1_T,  i - 38193, 128, 64);
}

// ---------------- Phase A
__global__ void k_phaseA(const float* __restrict__ last_obs,
                         const float* __restrict__ deltas,
                         const float* __restrict__ medians,
                         const float* __restrict__ W_woT, const float* __restrict__ b_wo,
                         const float* __restrict__ W_inpT, const float* __restrict__ b_inp,
                         float* __restrict__ data) {
    int bt = blockIdx.x;
    int b = bt / T_;
    int t = bt - b * T_;
    __shared__ float dd[D_], lo[D_], dec[D_];
    int tid = threadIdx.x;
    int base = (b * T_ + t) * D_;
    if (tid < D_) {
        float dv = deltas[base + tid] - medians[tid];
        dd[tid] = dv;
        lo[tid] = last_obs[base + tid];
    }
    __syncthreads();
    if (tid < D_) {
        float acc = b_wo[tid];
        for (int j = 0; j < D_; ++j) acc = fmaf(dd[j], W_woT[j * D_ + tid], acc);
        float dv = dd[tid];
        float s = (dv > 0.f) ? 1.f : ((dv < 0.f) ? -1.f : 0.f);
        dec[tid] = 0.5f * (1.f - tanhf(s * fabsf(acc)));
    }
    __syncthreads();
    int c = tid & 63;
    int half = tid >> 6;
    const float* src = half ? dec : lo;
    float acc = b_inp[c];
    for (int j = 0; j < D_; ++j) acc = fmaf(src[j], W_inpT[j * C_ + c], acc);
    int i = c >> 1;
    float div = __expf((float)i * -0.28782313662425574f);
    float ang = (float)t * div;
    float pe = (c & 1) ? cosf(ang) : sinf(ang);
    data[((b * N2T) + half * T_ + t) * C_ + c] = acc + pe;
}

// ---------------- qkv
__global__ void k_qkv(const float* __restrict__ data,
                      const float* __restrict__ ain_T, const float* __restrict__ ain_b,
                      float* __restrict__ qb, float* __restrict__ kb, float* __restrict__ vb) {
    int bn = blockIdx.x;
    int s = bn / N2T;
    int n = bn - s * N2T;
    __shared__ float row[C_];
    int tid = threadIdx.x;
    if (tid < C_) row[tid] = data[bn * C_ + tid];
    __syncthreads();
    float acc = ain_b[tid];
    for (int j = 0; j < C_; ++j) acc = fmaf(row[j], ain_T[j * 192 + tid], acc);
    int part = tid >> 6;
    int c = tid & 63;
    int h = c >> 3, d = c & 7;
    float* dst = (part == 0) ? qb : ((part == 1) ? kb : vb);
    dst[(((n * NH_ + h) * B_ + s) * HD_) + d] = acc;
}

// ---------------- attention
__global__ void k_attn(const float* __restrict__ qb, const float* __restrict__ kb,
                       const float* __restrict__ vb, float* __restrict__ attnO) {
    int n = blockIdx.x >> 3;
    int h = blockIdx.x & 7;
    __shared__ float k_lds[B_][HD_ + 1];
    __shared__ float v_lds[B_][HD_ + 1];
    int s = threadIdx.x;
    const float scale = 0.35355339059327373f;
    size_t base = ((size_t)blockIdx.x * B_ + s) * HD_;
    float q[HD_];
    #pragma unroll
    for (int d = 0; d < HD_; ++d) q[d] = qb[base + d] * scale;
    #pragma unroll
    for (int d = 0; d < HD_; ++d) { k_lds[s][d] = kb[base + d]; v_lds[s][d] = vb[base + d]; }
    __syncthreads();
    float m = -1e30f;
    for (int t = 0; t < B_; ++t) {
        float sc = 0.f;
        #pragma unroll
        for (int d = 0; d < HD_; ++d) sc = fmaf(q[d], k_lds[t][d], sc);
        m = fmaxf(m, sc);
    }
    float l = 0.f;
    float acc[HD_] = {0.f, 0.f, 0.f, 0.f, 0.f, 0.f, 0.f, 0.f};
    for (int t = 0; t < B_; ++t) {
        float sc = 0.f;
        #pragma unroll
        for (int d = 0; d < HD_; ++d) sc = fmaf(q[d], k_lds[t][d], sc);
        float p = __expf(sc - m);
        l += p;
        #pragma unroll
        for (int d = 0; d < HD_; ++d) acc[d] = fmaf(p, v_lds[t][d], acc[d]);
    }
    float inv = 1.f / l;
    float* op = attnO + ((size_t)s * N2T + n) * C_ + h * HD_;
    #pragma unroll
    for (int d = 0; d < HD_; ++d) op[d] = acc[d] * inv;
}

// ---------------- transformer post-attn
__global__ void k_transform(const float* __restrict__ data,
                            const float* __restrict__ attnO,
                            const float* __restrict__ aout_T, const float* __restrict__ aout_b,
                            const float* __restrict__ ln1_g, const float* __restrict__ ln1_b,
                            const float* __restrict__ ff1_T, const float* __restrict__ ff1_b,
                            const float* __restrict__ ff2_T, const float* __restrict__ ff2_b,
                            const float* __restrict__ ln2_g, const float* __restrict__ ln2_b,
                            const float* __restrict__ op1_T, const float* __restrict__ b_op1,
                            float* __restrict__ val) {
    int bn = blockIdx.x;
    __shared__ float orow[C_], x1s[C_], hbuf[C_], x2s[C_];
    int c = threadIdx.x;
    float d0 = data[bn * C_ + c];
    orow[c] = attnO[bn * C_ + c];
    __syncthreads();
    float acc = aout_b[c];
    for (int j = 0; j < C_; ++j) acc = fmaf(orow[j], aout_T[j * C_ + c], acc);
    float r = d0 + acc;
    float mean = wave_sum64(r) * (1.f / 64.f);
    float df = r - mean;
    float var = wave_sum64(df * df) * (1.f / 64.f);
    float x1 = df * rsqrtf(var + 1e-5f) * ln1_g[c] + ln1_b[c];
    x1s[c] = x1;
    __syncthreads();
    acc = ff1_b[c];
    for (int j = 0; j < C_; ++j) acc = fmaf(x1s[j], ff1_T[j * C_ + c], acc);
    float ge = 0.5f * acc * (1.f + erff(acc * 0.7071067811865475f));
    hbuf[c] = ge;
    __syncthreads();
    acc = ff2_b[c];
    for (int j = 0; j < C_; ++j) acc = fmaf(hbuf[j], ff2_T[j * C_ + c], acc);
    float r2 = x1 + acc;
    float mean2 = wave_sum64(r2) * (1.f / 64.f);
    float df2 = r2 - mean2;
    float var2 = wave_sum64(df2 * df2) * (1.f / 64.f);
    float x2 = df2 * rsqrtf(var2 + 1e-5f) * ln2_g[c] + ln2_b[c];
    x2s[c] = x2;
    __syncthreads();
    #pragma unroll
    for (int rep = 0; rep < 2; ++rep) {
        int k = c + rep * 64;
        float a2 = b_op1[k];
        for (int j = 0; j < C_; ++j) a2 = fmaf(x2s[j], op1_T[j * H_ + k], a2);
        val[(size_t)bn * H_ + k] = a2;
    }
}

// ---------------- h0 reduce
__global__ void k_reduce_h0(const float* __restrict__ val,
                            const float* __restrict__ W_op2, const float* __restrict__ b_op2,
                            float* __restrict__ h0) {
    int b = blockIdx.x;
    int h = threadIdx.x;
    float acc = b_op2[0];
    for (int n = 0; n < N2T; ++n)
        acc = fmaf(val[((size_t)b * N2T + n) * H_ + h], W_op2[n], acc);
    h0[b * H_ + h] = acc;
}

// ---------------- per-step mask denominator
__global__ void k_den(const float* __restrict__ mask, float* __restrict__ den) {
    int t = blockIdx.x;
    int tid = threadIdx.x;
    float s = 0.f;
    const int total = B_ * D_;
    for (int i = tid; i < total; i += 256) {
        int b = i / D_;
        int d = i - b * D_;
        s += mask[(b * T_ + t) * D_ + d];
    }
    s = wave_sum64(s);
    __shared__ float red[4];
    if ((tid & 63) == 0) red[tid >> 6] = s;
    __syncthreads();
    if (tid == 0) den[t] = red[0] + red[1] + red[2] + red[3];
}

// ---------------- recurrent scan: 256 blocks x 1024 threads, 1 batch elem/block.
// W_ih/W_hh/W_dh/W_hist bf16-packed in NAMED ext-vector registers (v0,v1,v2 =
// 80 uints max; SSA values, bypassing PromoteAlloca which sent rounds 4-6's
// wreg[] arrays to scratch). W_feat/W_wc in LDS bf16. Wave-aligned roles:
//  A tid<384    : W_ih[o][0:88]->v0[0..31]+v1[0..11]; W_hh[o][0:64]->v1[12..31]+v2[0..11]
//  B 384..767   : W_ih[o][88:178]->v0+v1[0..11]+v2[12]; W_hh[o][64:128]->v1[12..31]+v2[0..11]
//  C 768..895   : W_dh[r]->v0+v1[0..11]+v2[12]; r<89: W_hist[r][64:128]->v1[12..31]+v2[0..11]
//  D 896..1023  : r<89: W_hist[r][0:64]->v0
__global__ __attribute__((amdgpu_flat_work_group_size(1024, 1024), amdgpu_waves_per_eu(4, 4)))
void k_scan(const float* __restrict__ x, const float* __restrict__ mask,
            const float* __restrict__ deltas,
            const float* __restrict__ W_dh, const float* __restrict__ b_dh,
            const float* __restrict__ W_dx, const float* __restrict__ b_dx,
            const float* __restrict__ W_hist, const float* __restrict__ b_hist,
            const float* __restrict__ W_feat, const float* __restrict__ b_feat,
            const float* __restrict__ W_wc, const float* __restrict__ b_wc,
            const float* __restrict__ W_ih, const float* __restrict__ W_hh,
            const float* __restrict__ b_ih, const float* __restrict__ b_hh,
            const float* __restrict__ W_cls, const float* __restrict__ b_cls,
            const float* __restrict__ h0,
            float* __restrict__ out, float* __restrict__ num_part) {
    int b = blockIdx.x;
    int tid = threadIdx.x;

    __shared__ __align__(16) float h_s[H_];
    __shared__ __align__(16) float xt_s[92];
    __shared__ __align__(16) float dt_s[92];
    __shared__ __align__(16) float xr_s[92];
    __shared__ __align__(16) float catg_s[180];   // [ximp(89) | m(89)]
    __shared__ __align__(16) float catb_s[180];   // [gx(89)   | m(89)]
    __shared__ __align__(16) float gis_p[2][384], ghs_p[2][384];
    __shared__ __align__(16) float p2[2][92];
    __shared__ float diff_s[92];
    __shared__ __align__(16) uint_t wwc_l[89 * 92];    // 32.7 KB, row stride 92 uints
    __shared__ __align__(16) uint_t wfeat_l[89 * 52];  // 18.5 KB, row stride 52 uints

    u32x32 v0 = (u32x32)0, v1 = (u32x32)0;
    u32x16 v2 = (u32x16)0;
    float bias0 = 0.f, bias1 = 0.f, bias2 = 0.f, biasF = 0.f, dxw = 0.f, dxb = 0.f;

    if (tid < 384) {                       // A
        const float* wi = W_ih + (size_t)tid * 178;
        #pragma unroll
        for (int j = 0; j < 32; ++j) v0[j] = pack2(wi[2 * j], wi[2 * j + 1]);
        #pragma unroll
        for (int j = 0; j < 12; ++j) v1[j] = pack2(wi[64 + 2 * j], wi[65 + 2 * j]);
        const float* wh = W_hh + (size_t)tid * 128;
        #pragma unroll
        for (int j = 0; j < 20; ++j) v1[12 + j] = pack2(wh[2 * j], wh[2 * j + 1]);
        #pragma unroll
        for (int j = 0; j < 12; ++j) v2[j] = pack2(wh[40 + 2 * j], wh[41 + 2 * j]);
        bias0 = b_ih[tid];
        bias1 = b_hh[tid];
        if (tid < 128) h_s[tid] = h0[b * H_ + tid];
    } else if (tid < 768) {                // B
        int o = tid - 384;
        const float* wi = W_ih + (size_t)o * 178;
        #pragma unroll
        for (int j = 0; j < 32; ++j) v0[j] = pack2(wi[88 + 2 * j], wi[89 + 2 * j]);
        #pragma unroll
        for (int j = 0; j < 12; ++j) v1[j] = pack2(wi[152 + 2 * j], wi[153 + 2 * j]);
        v2[12] = pack2(wi[176], wi[177]);
        const float* wh = W_hh + (size_t)o * 128;
        #pragma unroll
        for (int j = 0; j < 20; ++j) v1[12 + j] = pack2(wh[64 + 2 * j], wh[65 + 2 * j]);
        #pragma unroll
        for (int j = 0; j < 12; ++j) v2[j] = pack2(wh[104 + 2 * j], wh[105 + 2 * j]);
    } else if (tid < 896) {                // C
        int r = tid - 768;
        const float* wd = W_dh + r * 89;
        #pragma unroll
        for (int j = 0; j < 32; ++j) v0[j] = pack2(wd[2 * j], wd[2 * j + 1]);
        #pragma unroll
        for (int j = 0; j < 12; ++j) v1[j] = pack2(wd[64 + 2 * j], wd[65 + 2 * j]);
        v2[12] = pack2(wd[88], 0.f);
        bias0 = b_dh[r];
        if (r < 89) {
            const float* wh = W_hist + r * 128;
            #pragma unroll
            for (int j = 0; j < 20; ++j) v1[12 + j] = pack2(wh[64 + 2 * j], wh[65 + 2 * j]);
            #pragma unroll
            for (int j = 0; j < 12; ++j) v2[j] = pack2(wh[104 + 2 * j], wh[105 + 2 * j]);
        }
    } else {                               // D
        int r = tid - 896;
        if (r < 89) {
            const float* wh = W_hist + r * 128;
            #pragma unroll
            for (int j = 0; j < 32; ++j) v0[j] = pack2(wh[2 * j], wh[2 * j + 1]);
            bias1 = b_hist[r];
            biasF = b_feat[r];
            bias2 = b_wc[r];
            dxw = W_dx[r * 90];
            dxb = b_dx[r];
        }
    }
    // LDS weight staging (bf16): W_wc rows (stride 92), W_feat rows (stride 52, diag=0)
    for (int i = tid; i < 89 * 89; i += 1024) {
        int r = i / 89, c = i - r * 89;
        const float* wr = W_wc + (size_t)r * 178;
        wwc_l[r * 92 + c] = pack2(wr[2 * c], wr[2 * c + 1]);
    }
    for (int i = tid; i < 89 * 45; i += 1024) {
        int r = i / 45, c = i - r * 45;
        const float* wr = W_feat + r * 89;
        float lo, hi;
        if (c < 44) {
            lo = (2 * c == r) ? 0.f : wr[2 * c];
            hi = (2 * c + 1 == r) ? 0.f : wr[2 * c + 1];
        } else {
            lo = (88 == r) ? 0.f : wr[88];
            hi = 0.f;
        }
        wfeat_l[r * 52 + c] = pack2(lo, hi);
    }
    // prologue t=0 activations
    {
        int base = b * T_ * D_;
        if (tid >= 128 && tid < 217) xt_s[tid - 128] = x[base + tid - 128];
        else if (tid >= 224 && tid < 313) {
            float m = mask[base + tid - 224];
            catg_s[89 + tid - 224] = m;
            catb_s[89 + tid - 224] = m;
        }
        else if (tid >= 320 && tid < 409) dt_s[tid - 320] = deltas[base + tid - 320];
    }
    __syncthreads();

    for (int t = 0; t < T_; ++t) {
        // ---- P1: gamma_h decay (C: 128 threads, W_dh in v0/v1/v2)
        if (tid >= 768 && tid < 896) {
            int r = tid - 768;
            const float4* d4 = (const float4*)dt_s;
            float a0 = 0.f, a1 = 0.f;
            #pragma unroll
            for (int q = 0; q < 16; ++q) FMA4(d4[q], v0[2 * q], v0[2 * q + 1]);
            #pragma unroll
            for (int q = 0; q < 6; ++q) FMA4(d4[16 + q], v1[2 * q], v1[2 * q + 1]);
            a0 = fmaf(dt_s[88], blo(v2[12]), a0);
            h_s[r] *= __expf(-fmaxf(bias0 + a0 + a1, 0.f));
        }
        __syncthreads();
        // ---- P2a: x_h partials (D: h[0:64] via v0; C r<89: h[64:128] via v1/v2)
        if (tid >= 896 && tid < 985) {
            int r = tid - 896;
            const float4* h4 = (const float4*)h_s;
            float a0 = 0.f, a1 = 0.f;
            #pragma unroll
            for (int q = 0; q < 16; ++q) FMA4(h4[q], v0[2 * q], v0[2 * q + 1]);
            p2[0][r] = a0 + a1;
        } else if (tid >= 768 && tid < 857) {
            int r = tid - 768;
            const float4* h4 = (const float4*)(h_s + 64);
            float a0 = 0.f, a1 = 0.f;
            #pragma unroll
            for (int q = 0; q < 10; ++q) FMA4(h4[q], v1[12 + 2 * q], v1[13 + 2 * q]);
            #pragma unroll
            for (int q = 0; q < 6; ++q) FMA4(h4[10 + q], v2[2 * q], v2[2 * q + 1]);
            p2[1][r] = a0 + a1;
        }
        __syncthreads();
        // ---- P2b: combine -> xh (kept local), xr, gx (D)
        float xh_loc = 0.f, m_loc = 0.f, xt_loc = 0.f;
        if (tid >= 896 && tid < 985) {
            int r = tid - 896;
            xh_loc = p2[0][r] + p2[1][r] + bias1;
            m_loc = catb_s[89 + r];
            xt_loc = xt_s[r];
            xr_s[r] = m_loc * xt_loc + (1.f - m_loc) * xh_loc;
            catb_s[r] = __expf(-fmaxf(dt_s[r] * dxw + dxb, 0.f));
        }
        __syncthreads();
        // ---- P3: xu (W_feat LDS), beta (W_wc LDS), x_comb, x_imp, diff (D)
        if (tid >= 896 && tid < 985) {
            int r = tid - 896;
            const uint4* wf4 = (const uint4*)(wfeat_l + r * 52);
            const float4* x4 = (const float4*)xr_s;
            float a0 = 0.f, a1 = 0.f;
            #pragma unroll
            for (int q = 0; q < 11; ++q) {
                uint4 w = wf4[q];
                FMA4(x4[2 * q], w.x, w.y);
                FMA4(x4[2 * q + 1], w.z, w.w);
            }
            a0 = fmaf(xr_s[88], blo(wfeat_l[r * 52 + 44]), a0);
            float xu = a0 + a1 + biasF;
            const uint4* wc4 = (const uint4*)(wwc_l + r * 92);
            const float4* c4 = (const float4*)catb_s;
            a0 = 0.f; a1 = 0.f;
            #pragma unroll
            for (int q = 0; q < 22; ++q) {
                uint4 w = wc4[q];
                FMA4(c4[2 * q], w.x, w.y);
                FMA4(c4[2 * q + 1], w.z, w.w);
            }
            {
                float2 f2 = *(const float2*)(catb_s + 176);
                uint_t w = wwc_l[r * 92 + 88];
                a0 = fmaf(f2.x, blo(w), a0);
                a1 = fmaf(f2.y, bhi(w), a1);
            }
            float beta = a0 + a1 + bias2;
            float xc = beta * xu + (1.f - beta) * xh_loc;
            float xi = m_loc * xt_loc + (1.f - m_loc) * xc;
            catg_s[r] = xi;
            out[XIMP_OFF + (b * T_ + t) * D_ + r] = xi;
            diff_s[r] = fabsf(xt_loc - xc) * m_loc;
        }
        __syncthreads();
        // ---- P4: gi/gh partials (A,B) + loss reduce (wave 15) + next-t loads (C + wave 14)
        if (tid < 384) {
            const float4* g4 = (const float4*)catg_s;
            float a0 = 0.f, a1 = 0.f;
            #pragma unroll
            for (int q = 0; q < 16; ++q) FMA4(g4[q], v0[2 * q], v0[2 * q + 1]);
            #pragma unroll
            for (int q = 0; q < 6; ++q) FMA4(g4[16 + q], v1[2 * q], v1[2 * q + 1]);
            gis_p[0][tid] = a0 + a1 + bias0;
            const float4* h4 = (const float4*)h_s;
            a0 = 0.f; a1 = 0.f;
            #pragma unroll
            for (int q = 0; q < 10; ++q) FMA4(h4[q], v1[12 + 2 * q], v1[13 + 2 * q]);
            #pragma unroll
            for (int q = 0; q < 6; ++q) FMA4(h4[10 + q], v2[2 * q], v2[2 * q + 1]);
            ghs_p[0][tid] = a0 + a1 + bias1;
        } else if (tid < 768) {
            int o = tid - 384;
            const float4* g4 = (const float4*)(catg_s + 88);
            float a0 = 0.f, a1 = 0.f;
            #pragma unroll
            for (int q = 0; q < 16; ++q) FMA4(g4[q], v0[2 * q], v0[2 * q + 1]);
            #pragma unroll
            for (int q = 0; q < 6; ++q) FMA4(g4[16 + q], v1[2 * q], v1[2 * q + 1]);
            {
                float2 f2 = *(const float2*)(catg_s + 176);
                a0 = fmaf(f2.x, blo(v2[12]), a0);
                a1 = fmaf(f2.y, bhi(v2[12]), a1);
            }
            gis_p[1][o] = a0 + a1;
            const float4* h4 = (const float4*)(h_s + 64);
            a0 = 0.f; a1 = 0.f;
            #pragma unroll
            for (int q = 0; q < 10; ++q) FMA4(h4[q], v1[12 + 2 * q], v1[13 + 2 * q]);
            #pragma unroll
            for (int q = 0; q < 6; ++q) FMA4(h4[10 + q], v2[2 * q], v2[2 * q + 1]);
            ghs_p[1][o] = a0 + a1;
        } else if (tid >= 960) {
            int l = tid - 960;
            float s = diff_s[l];
            if (l < 25) s += diff_s[64 + l];
            s = wave_sum64(s);
            if (l == 0) num_part[t * B_ + b] = s;
        } else if (t + 1 < T_) {
            int base = (b * T_ + t + 1) * D_;
            if (tid < 896) {               // C: next xt + dt
                int r = tid - 768;
                if (r < 89) { xt_s[r] = x[base + r]; dt_s[r] = deltas[base + r]; }
            } else {                       // wave 14: next m -> catb half
                int l = tid - 896;
                catb_s[89 + l] = mask[base + l];
                if (l < 25) catb_s[89 + 64 + l] = mask[base + 64 + l];
            }
        }
        __syncthreads();
        // ---- P5: GRU update + copy next-m into catg half
        if (tid < 128) {
            float r = sigm(gis_p[0][tid] + gis_p[1][tid] + ghs_p[0][tid] + ghs_p[1][tid]);
            float z = sigm(gis_p[0][128 + tid] + gis_p[1][128 + tid] +
                           ghs_p[0][128 + tid] + ghs_p[1][128 + tid]);
            float g = tanhf(gis_p[0][256 + tid] + gis_p[1][256 + tid] +
                            r * (ghs_p[0][256 + tid] + ghs_p[1][256 + tid]));
            float hn = (1.f - z) * g + z * h_s[tid];
            h_s[tid] = hn;
            out[HID_OFF + (size_t)(b * T_ + t) * H_ + tid] = hn;
        } else if (tid >= 128 && tid < 217 && t + 1 < T_) {
            int l = tid - 128;
            catg_s[89 + l] = catb_s[89 + l];
        }
        __syncthreads();
    }
    // classifier
    if (tid < 64) {
        float p = h_s[tid] * W_cls[tid] + h_s[tid + 64] * W_cls[tid + 64];
        p = wave_sum64(p);
        if (tid == 0) {
            float y = p + b_cls[0];
            out[Y_OFF + b] = y;
            out[YS_OFF + b] = 1.f / (1.f + __expf(-y));
        }
    }
}

// ---------------- final loss reduction
__global__ void k_loss(const float* __restrict__ num_part, const float* __restrict__ den,
                       float* __restrict__ out) {
    int tid = threadIdx.x;
    float v = 0.f;
    if (tid < T_) {
        float s = 0.f;
        const float* np_ = num_part + tid * B_;
        for (int b = 0; b < B_; ++b) s += np_[b];
        v = s / (den[tid] + 1e-5f);
    }
    v = wave_sum64(v);
    if (tid == 0) out[LOSS_OFF] = v;
}

extern "C" void kernel_launch(void* const* d_in, const int* in_sizes, int n_in,
                              void* d_out, int out_size, void* d_ws, size_t ws_size,
                              hipStream_t stream) {
    const float* x        = (const float*)d_in[0];
    const float* mask     = (const float*)d_in[1];
    const float* deltas   = (const float*)d_in[2];
    const float* last_obs = (const float*)d_in[3];
    const float* medians  = (const float*)d_in[4];
    const float* W_dh  = (const float*)d_in[5];
    const float* b_dh  = (const float*)d_in[6];
    const float* W_dx  = (const float*)d_in[7];
    const float* b_dx  = (const float*)d_in[8];
    const float* W_hist= (const float*)d_in[9];
    const float* b_hist= (const float*)d_in[10];
    const float* W_feat= (const float*)d_in[11];
    const float* b_feat= (const float*)d_in[12];
    const float* W_wc  = (const float*)d_in[13];
    const float* b_wc  = (const float*)d_in[14];
    const float* W_wo  = (const float*)d_in[15];
    const float* b_wo  = (const float*)d_in[16];
    const float* W_cls = (const float*)d_in[17];
    const float* b_cls = (const float*)d_in[18];
    const float* W_ih  = (const float*)d_in[19];
    const float* W_hh  = (const float*)d_in[20];
    const float* b_ih  = (const float*)d_in[21];
    const float* b_hh  = (const float*)d_in[22];
    const float* W_inp = (const float*)d_in[23];
    const float* b_inp = (const float*)d_in[24];
    const float* W_op1 = (const float*)d_in[25];
    const float* b_op1 = (const float*)d_in[26];
    const float* W_op2 = (const float*)d_in[27];
    const float* b_op2 = (const float*)d_in[28];
    const float* attn_in_w  = (const float*)d_in[29];
    const float* attn_in_b  = (const float*)d_in[30];
    const float* attn_out_w = (const float*)d_in[31];
    const float* attn_out_b = (const float*)d_in[32];
    const float* ln1_g = (const float*)d_in[33];
    const float* ln1_b = (const float*)d_in[34];
    const float* ln2_g = (const float*)d_in[35];
    const float* ln2_b = (const float*)d_in[36];
    const float* ff1_w = (const float*)d_in[37];
    const float* ff1_b = (const float*)d_in[38];
    const float* ff2_w = (const float*)d_in[39];
    const float* ff2_b = (const float*)d_in[40];

    float* out = (float*)d_out;
    float* ws = (float*)d_ws;

    float* data  = ws;
    float* qb    = data  + (size_t)B_ * N2T * C_;
    float* kb    = qb    + (size_t)N2T * NH_ * B_ * HD_;
    float* vb    = kb    + (size_t)N2T * NH_ * B_ * HD_;
    float* attnO = vb    + (size_t)N2T * NH_ * B_ * HD_;
    float* val   = attnO + (size_t)B_ * N2T * C_;
    float* h0    = val   + (size_t)B_ * N2T * H_;
    float* den   = h0    + (size_t)B_ * H_;
    float* nump  = den   + 64;
    float* W_woT = nump  + T_ * B_;
    float* W_inpT= W_woT + 7921;
    float* ain_T = W_inpT + 5696;
    float* aout_T= ain_T + 12288;
    float* ff1_T = aout_T + 4096;
    float* ff2_T = ff1_T + 4096;
    float* op1_T = ff2_T + 4096;

    k_prep<<<182, 256, 0, stream>>>(W_wo, W_inp, attn_in_w, attn_out_w, ff1_w, ff2_w, W_op1,
                                    W_woT, W_inpT, ain_T, aout_T, ff1_T, ff2_T, op1_T);
    k_phaseA<<<B_ * T_, 128, 0, stream>>>(last_obs, deltas, medians, W_woT, b_wo, W_inpT, b_inp, data);
    k_qkv<<<B_ * N2T, 192, 0, stream>>>(data, ain_T, attn_in_b, qb, kb, vb);
    k_attn<<<N2T * NH_, 256, 0, stream>>>(qb, kb, vb, attnO);
    k_transform<<<B_ * N2T, 64, 0, stream>>>(data, attnO, aout_T, attn_out_b,
                                             ln1_g, ln1_b, ff1_T, ff1_b, ff2_T, ff2_b,
                                             ln2_g, ln2_b, op1_T, b_op1, val);
    k_reduce_h0<<<B_, H_, 0, stream>>>(val, W_op2, b_op2, h0);
    k_den<<<T_, 256, 0, stream>>>(mask, den);
    k_scan<<<B_, 1024, 0, stream>>>(x, mask, deltas,
                                    W_dh, b_dh, W_dx, b_dx, W_hist, b_hist, W_feat, b_feat,
                                    W_wc, b_wc, W_ih, W_hh, b_ih, b_hh, W_cls, b_cls,
                                    h0, out, nump);
    k_loss<<<1, 64, 0, stream>>>(nump, den, out);
}

// Round 9
// 868.034 us; speedup vs baseline: 2.4525x; 1.8704x over previous
//
#include <hip/hip_runtime.h>
#include <math.h>

#define B_  256
#define T_  48
#define D_  89
#define H_  128
#define C_  64
#define NH_ 8
#define HD_ 8
#define N2T 96   // 2*T

// output layout (floats)
#define XIMP_OFF 0
#define LOSS_OFF 1093632
#define HID_OFF  1093633
#define Y_OFF    2666497
#define YS_OFF   2666753

typedef unsigned int uint_t;

__device__ __forceinline__ float wave_sum64(float v) {
    v += __shfl_xor(v, 32);
    v += __shfl_xor(v, 16);
    v += __shfl_xor(v, 8);
    v += __shfl_xor(v, 4);
    v += __shfl_xor(v, 2);
    v += __shfl_xor(v, 1);
    return v;
}

// pack two f32 into bf16x2 (RNE)
__device__ __forceinline__ uint_t pack2(float lo, float hi) {
    uint_t a = __float_as_uint(lo), b = __float_as_uint(hi);
    a = (a + 0x7fffu + ((a >> 16) & 1u)) >> 16;
    b = (b + 0x7fffu + ((b >> 16) & 1u)) >> 16;
    return a | (b << 16);
}
__device__ __forceinline__ float blo(uint_t w) { return __uint_as_float(w << 16); }
__device__ __forceinline__ float bhi(uint_t w) { return __uint_as_float(w & 0xffff0000u); }
__device__ __forceinline__ float sigm(float v) { return 1.f / (1.f + __expf(-v)); }

// ---------------- prep: f32 transposes for the transformer-phase kernels only
__device__ __forceinline__ void tr_f32(const float* __restrict__ s, float* __restrict__ d,
                                       int li, int R, int C) {
    int r = li / C, c = li - r * C;
    d[c * R + r] = s[li];
}

__global__ void k_prep(const float* W_wo, const float* W_inp, const float* ain_w,
                       const float* aout_w, const float* ff1_w, const float* ff2_w,
                       const float* W_op1,
                       float* W_woT, float* W_inpT, float* ain_T,
                       float* aout_T, float* ff1_T, float* ff2_T, float* op1_T) {
    int i = blockIdx.x * 256 + threadIdx.x;
    if (i < 7921)         tr_f32(W_wo,   W_woT,  i,          89, 89);
    else if (i < 13617)   tr_f32(W_inp,  W_inpT, i - 7921,   64, 89);
    else if (i < 25905)   tr_f32(ain_w,  ain_T,  i - 13617, 192, 64);
    else if (i < 30001)   tr_f32(aout_w, aout_T, i - 25905,  64, 64);
    else if (i < 34097)   tr_f32(ff1_w,  ff1_T,  i - 30001,  64, 64);
    else if (i < 38193)   tr_f32(ff2_w,  ff2_T,  i - 34097,  64, 64);
    else if (i < 46385)   tr_f32(W_op1,  op1_T,  i - 38193, 128, 64);
}

// ---------------- Phase A
__global__ void k_phaseA(const float* __restrict__ last_obs,
                         const float* __restrict__ deltas,
                         const float* __restrict__ medians,
                         const float* __restrict__ W_woT, const float* __restrict__ b_wo,
                         const float* __restrict__ W_inpT, const float* __restrict__ b_inp,
                         float* __restrict__ data) {
    int bt = blockIdx.x;
    int b = bt / T_;
    int t = bt - b * T_;
    __shared__ float dd[D_], lo[D_], dec[D_];
    int tid = threadIdx.x;
    int base = (b * T_ + t) * D_;
    if (tid < D_) {
        float dv = deltas[base + tid] - medians[tid];
        dd[tid] = dv;
        lo[tid] = last_obs[base + tid];
    }
    __syncthreads();
    if (tid < D_) {
        float acc = b_wo[tid];
        for (int j = 0; j < D_; ++j) acc = fmaf(dd[j], W_woT[j * D_ + tid], acc);
        float dv = dd[tid];
        float s = (dv > 0.f) ? 1.f : ((dv < 0.f) ? -1.f : 0.f);
        dec[tid] = 0.5f * (1.f - tanhf(s * fabsf(acc)));
    }
    __syncthreads();
    int c = tid & 63;
    int half = tid >> 6;
    const float* src = half ? dec : lo;
    float acc = b_inp[c];
    for (int j = 0; j < D_; ++j) acc = fmaf(src[j], W_inpT[j * C_ + c], acc);
    int i = c >> 1;
    float div = __expf((float)i * -0.28782313662425574f);
    float ang = (float)t * div;
    float pe = (c & 1) ? cosf(ang) : sinf(ang);
    data[((b * N2T) + half * T_ + t) * C_ + c] = acc + pe;
}

// ---------------- qkv
__global__ void k_qkv(const float* __restrict__ data,
                      const float* __restrict__ ain_T, const float* __restrict__ ain_b,
                      float* __restrict__ qb, float* __restrict__ kb, float* __restrict__ vb) {
    int bn = blockIdx.x;
    int s = bn / N2T;
    int n = bn - s * N2T;
    __shared__ float row[C_];
    int tid = threadIdx.x;
    if (tid < C_) row[tid] = data[bn * C_ + tid];
    __syncthreads();
    float acc = ain_b[tid];
    for (int j = 0; j < C_; ++j) acc = fmaf(row[j], ain_T[j * 192 + tid], acc);
    int part = tid >> 6;
    int c = tid & 63;
    int h = c >> 3, d = c & 7;
    float* dst = (part == 0) ? qb : ((part == 1) ? kb : vb);
    dst[(((n * NH_ + h) * B_ + s) * HD_) + d] = acc;
}

// ---------------- attention
__global__ void k_attn(const float* __restrict__ qb, const float* __restrict__ kb,
                       const float* __restrict__ vb, float* __restrict__ attnO) {
    int n = blockIdx.x >> 3;
    int h = blockIdx.x & 7;
    __shared__ float k_lds[B_][HD_ + 1];
    __shared__ float v_lds[B_][HD_ + 1];
    int s = threadIdx.x;
    const float scale = 0.35355339059327373f;
    size_t base = ((size_t)blockIdx.x * B_ + s) * HD_;
    float q[HD_];
    #pragma unroll
    for (int d = 0; d < HD_; ++d) q[d] = qb[base + d] * scale;
    #pragma unroll
    for (int d = 0; d < HD_; ++d) { k_lds[s][d] = kb[base + d]; v_lds[s][d] = vb[base + d]; }
    __syncthreads();
    float m = -1e30f;
    for (int t = 0; t < B_; ++t) {
        float sc = 0.f;
        #pragma unroll
        for (int d = 0; d < HD_; ++d) sc = fmaf(q[d], k_lds[t][d], sc);
        m = fmaxf(m, sc);
    }
    float l = 0.f;
    float acc[HD_] = {0.f, 0.f, 0.f, 0.f, 0.f, 0.f, 0.f, 0.f};
    for (int t = 0; t < B_; ++t) {
        float sc = 0.f;
        #pragma unroll
        for (int d = 0; d < HD_; ++d) sc = fmaf(q[d], k_lds[t][d], sc);
        float p = __expf(sc - m);
        l += p;
        #pragma unroll
        for (int d = 0; d < HD_; ++d) acc[d] = fmaf(p, v_lds[t][d], acc[d]);
    }
    float inv = 1.f / l;
    float* op = attnO + ((size_t)s * N2T + n) * C_ + h * HD_;
    #pragma unroll
    for (int d = 0; d < HD_; ++d) op[d] = acc[d] * inv;
}

// ---------------- transformer post-attn
__global__ void k_transform(const float* __restrict__ data,
                            const float* __restrict__ attnO,
                            const float* __restrict__ aout_T, const float* __restrict__ aout_b,
                            const float* __restrict__ ln1_g, const float* __restrict__ ln1_b,
                            const float* __restrict__ ff1_T, const float* __restrict__ ff1_b,
                            const float* __restrict__ ff2_T, const float* __restrict__ ff2_b,
                            const float* __restrict__ ln2_g, const float* __restrict__ ln2_b,
                            const float* __restrict__ op1_T, const float* __restrict__ b_op1,
                            float* __restrict__ val) {
    int bn = blockIdx.x;
    __shared__ float orow[C_], x1s[C_], hbuf[C_], x2s[C_];
    int c = threadIdx.x;
    float d0 = data[bn * C_ + c];
    orow[c] = attnO[bn * C_ + c];
    __syncthreads();
    float acc = aout_b[c];
    for (int j = 0; j < C_; ++j) acc = fmaf(orow[j], aout_T[j * C_ + c], acc);
    float r = d0 + acc;
    float mean = wave_sum64(r) * (1.f / 64.f);
    float df = r - mean;
    float var = wave_sum64(df * df) * (1.f / 64.f);
    float x1 = df * rsqrtf(var + 1e-5f) * ln1_g[c] + ln1_b[c];
    x1s[c] = x1;
    __syncthreads();
    acc = ff1_b[c];
    for (int j = 0; j < C_; ++j) acc = fmaf(x1s[j], ff1_T[j * C_ + c], acc);
    float ge = 0.5f * acc * (1.f + erff(acc * 0.7071067811865475f));
    hbuf[c] = ge;
    __syncthreads();
    acc = ff2_b[c];
    for (int j = 0; j < C_; ++j) acc = fmaf(hbuf[j], ff2_T[j * C_ + c], acc);
    float r2 = x1 + acc;
    float mean2 = wave_sum64(r2) * (1.f / 64.f);
    float df2 = r2 - mean2;
    float var2 = wave_sum64(df2 * df2) * (1.f / 64.f);
    float x2 = df2 * rsqrtf(var2 + 1e-5f) * ln2_g[c] + ln2_b[c];
    x2s[c] = x2;
    __syncthreads();
    #pragma unroll
    for (int rep = 0; rep < 2; ++rep) {
        int k = c + rep * 64;
        float a2 = b_op1[k];
        for (int j = 0; j < C_; ++j) a2 = fmaf(x2s[j], op1_T[j * H_ + k], a2);
        val[(size_t)bn * H_ + k] = a2;
    }
}

// ---------------- h0 reduce
__global__ void k_reduce_h0(const float* __restrict__ val,
                            const float* __restrict__ W_op2, const float* __restrict__ b_op2,
                            float* __restrict__ h0) {
    int b = blockIdx.x;
    int h = threadIdx.x;
    float acc = b_op2[0];
    for (int n = 0; n < N2T; ++n)
        acc = fmaf(val[((size_t)b * N2T + n) * H_ + h], W_op2[n], acc);
    h0[b * H_ + h] = acc;
}

// ---------------- per-step mask denominator
__global__ void k_den(const float* __restrict__ mask, float* __restrict__ den) {
    int t = blockIdx.x;
    int tid = threadIdx.x;
    float s = 0.f;
    const int total = B_ * D_;
    for (int i = tid; i < total; i += 256) {
        int b = i / D_;
        int d = i - b * D_;
        s += mask[(b * T_ + t) * D_ + d];
    }
    s = wave_sum64(s);
    __shared__ float red[4];
    if ((tid & 63) == 0) red[tid >> 6] = s;
    __syncthreads();
    if (tid == 0) den[t] = red[0] + red[1] + red[2] + red[3];
}

// ---------------- recurrent scan: 256 blocks x 512 threads, 1 batch elem/block.
// Wave-level (row, j-slice) decomposition: lane = 8*oo + jj; a wave computes 8
// outputs (rows o0..o0+7) with 8 j-slices each -> every weight load touches 8
// CONTIGUOUS 32-64B row segments (~8-16 cache lines/wave-load, vs 64 for the
// round-1 row-per-thread pattern). 3x shfl_xor reduces over jj. Weights stream
// f32 from d_in (proven-cacheable; FETCH stays ~MB). W_feat/W_wc staged once
// into LDS bf16. No per-thread weight state -> nothing for the compiler to
// spill (rounds 4-8's failure mode).
__global__ __launch_bounds__(512)
void k_scan(const float* __restrict__ x, const float* __restrict__ mask,
            const float* __restrict__ deltas,
            const float* __restrict__ W_dh, const float* __restrict__ b_dh,
            const float* __restrict__ W_dx, const float* __restrict__ b_dx,
            const float* __restrict__ W_hist, const float* __restrict__ b_hist,
            const float* __restrict__ W_feat, const float* __restrict__ b_feat,
            const float* __restrict__ W_wc, const float* __restrict__ b_wc,
            const float* __restrict__ W_ih, const float* __restrict__ W_hh,
            const float* __restrict__ b_ih, const float* __restrict__ b_hh,
            const float* __restrict__ W_cls, const float* __restrict__ b_cls,
            const float* __restrict__ h0,
            float* __restrict__ out, float* __restrict__ num_part) {
    int b = blockIdx.x;
    int tid = threadIdx.x;
    int wave = tid >> 6;
    int lane = tid & 63;
    int oo = lane >> 3;       // row within chunk
    int jj = lane & 7;        // j-slice

    __shared__ __align__(16) float h_s[H_];
    __shared__ __align__(16) float xt_s[96], dt_s[96], xr_s[96], xh_s[96], diff_s[96];
    __shared__ __align__(16) float catg_s[184];   // [ximp(89) | m(89)]
    __shared__ __align__(16) float catb_s[184];   // [gx(89)   | m(89)]
    __shared__ __align__(16) float gis[384], ghs[384];
    __shared__ __align__(16) uint_t wwc_l[7921];   // W_wc bf16 pairs, row stride 89
    __shared__ __align__(16) uint_t wfeat_l[4005]; // W_feat bf16 pairs (diag=0), stride 45

    // ---- one-time staging
    for (int i = tid; i < 7921; i += 512) {
        int r = i / 89, c = i - r * 89;
        const float* wr = W_wc + (size_t)r * 178;
        wwc_l[i] = pack2(wr[2 * c], wr[2 * c + 1]);
    }
    for (int i = tid; i < 4005; i += 512) {
        int r = i / 45, c = i - r * 45;
        const float* wr = W_feat + r * 89;
        float lo = (2 * c == r) ? 0.f : wr[2 * c];
        float hi = (c == 44 || 2 * c + 1 == r) ? 0.f : wr[2 * c + 1];
        wfeat_l[i] = pack2(lo, hi);
    }
    if (tid < 128) h_s[tid] = h0[b * H_ + tid];
    if (tid >= 480 && tid < 487) xr_s[89 + tid - 480] = 0.f;   // pad for wfeat uint44
    {
        int base = b * T_ * D_;
        if (tid >= 128 && tid < 217) xt_s[tid - 128] = x[base + tid - 128];
        else if (tid >= 224 && tid < 313) {
            float m = mask[base + tid - 224];
            catg_s[89 + tid - 224] = m;
            catb_s[89 + tid - 224] = m;
        }
        else if (tid >= 320 && tid < 409) dt_s[tid - 320] = deltas[base + tid - 320];
    }
    __syncthreads();

    for (int t = 0; t < T_; ++t) {
        // ---- P1: gamma_h decay. 128 outputs = 16 chunks, 2/wave. K=89 scalar.
        for (int c = wave; c < 16; c += 8) {
            int o = c * 8 + oo;
            const float* wd = W_dh + o * 89;
            float a0 = 0.f;
            #pragma unroll
            for (int it = 0; it < 11; ++it) {
                int j = jj + 8 * it;
                a0 = fmaf(wd[j], dt_s[j], a0);
            }
            if (jj == 0) a0 = fmaf(wd[88], dt_s[88], a0);
            a0 += __shfl_xor(a0, 1); a0 += __shfl_xor(a0, 2); a0 += __shfl_xor(a0, 4);
            if (jj == 0) h_s[o] *= __expf(-fmaxf(a0 + b_dh[o], 0.f));
        }
        __syncthreads();
        // ---- P2: x_h, x_r, gamma_x. 89 outputs = 12 chunks. K=128 float2.
        for (int c = wave; c < 12; c += 8) {
            int o = c * 8 + oo;
            int ro = (o < 89) ? o : 88;
            const float* wr = W_hist + ro * 128;
            float a0 = 0.f, a1 = 0.f;
            #pragma unroll
            for (int it = 0; it < 8; ++it) {
                int j2 = jj + 8 * it;
                float2 w = *(const float2*)(wr + 2 * j2);
                float2 hv = *(const float2*)(h_s + 2 * j2);
                a0 = fmaf(w.x, hv.x, a0);
                a1 = fmaf(w.y, hv.y, a1);
            }
            float acc = a0 + a1;
            acc += __shfl_xor(acc, 1); acc += __shfl_xor(acc, 2); acc += __shfl_xor(acc, 4);
            if (jj == 0 && o < 89) {
                float xh = acc + b_hist[o];
                xh_s[o] = xh;
                float m = catb_s[89 + o];
                xr_s[o] = m * xt_s[o] + (1.f - m) * xh;
                catb_s[o] = __expf(-fmaxf(dt_s[o] * W_dx[o * 90] + b_dx[o], 0.f));
            }
        }
        __syncthreads();
        // ---- P3: xu (LDS bf16 W_feat), beta (LDS bf16 W_wc), x_comb, x_imp.
        for (int c = wave; c < 12; c += 8) {
            int o = c * 8 + oo;
            int ro = (o < 89) ? o : 88;
            const uint_t* wf = wfeat_l + ro * 45;
            float a0 = 0.f, a1 = 0.f;
            #pragma unroll
            for (int it = 0; it < 5; ++it) {
                int j2 = jj + 8 * it;
                uint_t w = wf[j2];
                float2 xv = *(const float2*)(xr_s + 2 * j2);
                a0 = fmaf(blo(w), xv.x, a0);
                a1 = fmaf(bhi(w), xv.y, a1);
            }
            if (jj < 5) {
                int j2 = 40 + jj;
                uint_t w = wf[j2];
                float2 xv = *(const float2*)(xr_s + 2 * j2);
                a0 = fmaf(blo(w), xv.x, a0);
                a1 = fmaf(bhi(w), xv.y, a1);
            }
            float xu = a0 + a1;
            xu += __shfl_xor(xu, 1); xu += __shfl_xor(xu, 2); xu += __shfl_xor(xu, 4);
            const uint_t* wc = wwc_l + ro * 89;
            float c0 = 0.f, c1 = 0.f;
            #pragma unroll
            for (int it = 0; it < 11; ++it) {
                int j2 = jj + 8 * it;
                uint_t w = wc[j2];
                float2 cv = *(const float2*)(catb_s + 2 * j2);
                c0 = fmaf(blo(w), cv.x, c0);
                c1 = fmaf(bhi(w), cv.y, c1);
            }
            if (jj == 0) {
                uint_t w = wc[88];
                float2 cv = *(const float2*)(catb_s + 176);
                c0 = fmaf(blo(w), cv.x, c0);
                c1 = fmaf(bhi(w), cv.y, c1);
            }
            float bt = c0 + c1;
            bt += __shfl_xor(bt, 1); bt += __shfl_xor(bt, 2); bt += __shfl_xor(bt, 4);
            if (jj == 0 && o < 89) {
                float xuf = xu + b_feat[o];
                float btf = bt + b_wc[o];
                float xc = btf * xuf + (1.f - btf) * xh_s[o];
                float m = catb_s[89 + o];
                float xtv = xt_s[o];
                float xi = m * xtv + (1.f - m) * xc;
                catg_s[o] = xi;
                out[XIMP_OFF + (b * T_ + t) * D_ + o] = xi;
                diff_s[o] = fabsf(xtv - xc) * m;
            }
        }
        __syncthreads();
        // ---- P4: gi (K=178) + gh (K=128). 384 outputs = 48 chunks, 6/wave.
        for (int c = wave; c < 48; c += 8) {
            int o = c * 8 + oo;
            const float* wi = W_ih + (size_t)o * 178;
            const float* wh = W_hh + (size_t)o * 128;
            float g0 = 0.f, g1 = 0.f;
            #pragma unroll
            for (int it = 0; it < 11; ++it) {
                int j2 = jj + 8 * it;
                float2 w = *(const float2*)(wi + 2 * j2);
                float2 xv = *(const float2*)(catg_s + 2 * j2);
                g0 = fmaf(w.x, xv.x, g0);
                g1 = fmaf(w.y, xv.y, g1);
            }
            if (jj == 0) {
                float2 w = *(const float2*)(wi + 176);
                float2 xv = *(const float2*)(catg_s + 176);
                g0 = fmaf(w.x, xv.x, g0);
                g1 = fmaf(w.y, xv.y, g1);
            }
            float e0 = 0.f, e1 = 0.f;
            #pragma unroll
            for (int it = 0; it < 8; ++it) {
                int j2 = jj + 8 * it;
                float2 w = *(const float2*)(wh + 2 * j2);
                float2 hv = *(const float2*)(h_s + 2 * j2);
                e0 = fmaf(w.x, hv.x, e0);
                e1 = fmaf(w.y, hv.y, e1);
            }
            float gi_a = g0 + g1, gh_a = e0 + e1;
            gi_a += __shfl_xor(gi_a, 1); gi_a += __shfl_xor(gi_a, 2); gi_a += __shfl_xor(gi_a, 4);
            gh_a += __shfl_xor(gh_a, 1); gh_a += __shfl_xor(gh_a, 2); gh_a += __shfl_xor(gh_a, 4);
            if (jj == 0) {
                gis[o] = gi_a + b_ih[o];
                ghs[o] = gh_a + b_hh[o];
            }
        }
        __syncthreads();
        // ---- P5: GRU update (waves 0-1) | loss reduce (wave 7) | prefetch (waves 2-6)
        if (tid < 128) {
            float r = sigm(gis[tid] + ghs[tid]);
            float z = sigm(gis[128 + tid] + ghs[128 + tid]);
            float g = tanhf(gis[256 + tid] + r * ghs[256 + tid]);
            float hn = (1.f - z) * g + z * h_s[tid];
            h_s[tid] = hn;
            out[HID_OFF + (size_t)(b * T_ + t) * H_ + tid] = hn;
        } else if (tid >= 448) {
            int l = tid - 448;
            float s = diff_s[l] + ((l < 25) ? diff_s[64 + l] : 0.f);
            s = wave_sum64(s);
            if (l == 0) num_part[t * B_ + b] = s;
        } else if (t + 1 < T_) {
            int nb = (b * T_ + t + 1) * D_;
            if (tid < 217) xt_s[tid - 128] = x[nb + tid - 128];
            else if (tid >= 224 && tid < 313) {
                float m = mask[nb + tid - 224];
                catg_s[89 + tid - 224] = m;
                catb_s[89 + tid - 224] = m;
            }
            else if (tid >= 320 && tid < 409) dt_s[tid - 320] = deltas[nb + tid - 320];
        }
        __syncthreads();
    }
    // classifier
    if (tid < 64) {
        float p = h_s[tid] * W_cls[tid] + h_s[tid + 64] * W_cls[tid + 64];
        p = wave_sum64(p);
        if (tid == 0) {
            float y = p + b_cls[0];
            out[Y_OFF + b] = y;
            out[YS_OFF + b] = 1.f / (1.f + __expf(-y));
        }
    }
}

// ---------------- final loss reduction
__global__ void k_loss(const float* __restrict__ num_part, const float* __restrict__ den,
                       float* __restrict__ out) {
    int tid = threadIdx.x;
    float v = 0.f;
    if (tid < T_) {
        float s = 0.f;
        const float* np_ = num_part + tid * B_;
        for (int b = 0; b < B_; ++b) s += np_[b];
        v = s / (den[tid] + 1e-5f);
    }
    v = wave_sum64(v);
    if (tid == 0) out[LOSS_OFF] = v;
}

extern "C" void kernel_launch(void* const* d_in, const int* in_sizes, int n_in,
                              void* d_out, int out_size, void* d_ws, size_t ws_size,
                              hipStream_t stream) {
    const float* x        = (const float*)d_in[0];
    const float* mask     = (const float*)d_in[1];
    const float* deltas   = (const float*)d_in[2];
    const float* last_obs = (const float*)d_in[3];
    const float* medians  = (const float*)d_in[4];
    const float* W_dh  = (const float*)d_in[5];
    const float* b_dh  = (const float*)d_in[6];
    const float* W_dx  = (const float*)d_in[7];
    const float* b_dx  = (const float*)d_in[8];
    const float* W_hist= (const float*)d_in[9];
    const float* b_hist= (const float*)d_in[10];
    const float* W_feat= (const float*)d_in[11];
    const float* b_feat= (const float*)d_in[12];
    const float* W_wc  = (const float*)d_in[13];
    const float* b_wc  = (const float*)d_in[14];
    const float* W_wo  = (const float*)d_in[15];
    const float* b_wo  = (const float*)d_in[16];
    const float* W_cls = (const float*)d_in[17];
    const float* b_cls = (const float*)d_in[18];
    const float* W_ih  = (const float*)d_in[19];
    const float* W_hh  = (const float*)d_in[20];
    const float* b_ih  = (const float*)d_in[21];
    const float* b_hh  = (const float*)d_in[22];
    const float* W_inp = (const float*)d_in[23];
    const float* b_inp = (const float*)d_in[24];
    const float* W_op1 = (const float*)d_in[25];
    const float* b_op1 = (const float*)d_in[26];
    const float* W_op2 = (const float*)d_in[27];
    const float* b_op2 = (const float*)d_in[28];
    const float* attn_in_w  = (const float*)d_in[29];
    const float* attn_in_b  = (const float*)d_in[30];
    const float* attn_out_w = (const float*)d_in[31];
    const float* attn_out_b = (const float*)d_in[32];
    const float* ln1_g = (const float*)d_in[33];
    const float* ln1_b = (const float*)d_in[34];
    const float* ln2_g = (const float*)d_in[35];
    const float* ln2_b = (const float*)d_in[36];
    const float* ff1_w = (const float*)d_in[37];
    const float* ff1_b = (const float*)d_in[38];
    const float* ff2_w = (const float*)d_in[39];
    const float* ff2_b = (const float*)d_in[40];

    float* out = (float*)d_out;
    float* ws = (float*)d_ws;

    float* data  = ws;
    float* qb    = data  + (size_t)B_ * N2T * C_;
    float* kb    = qb    + (size_t)N2T * NH_ * B_ * HD_;
    float* vb    = kb    + (size_t)N2T * NH_ * B_ * HD_;
    float* attnO = vb    + (size_t)N2T * NH_ * B_ * HD_;
    float* val   = attnO + (size_t)B_ * N2T * C_;
    float* h0    = val   + (size_t)B_ * N2T * H_;
    float* den   = h0    + (size_t)B_ * H_;
    float* nump  = den   + 64;
    float* W_woT = nump  + T_ * B_;
    float* W_inpT= W_woT + 7921;
    float* ain_T = W_inpT + 5696;
    float* aout_T= ain_T + 12288;
    float* ff1_T = aout_T + 4096;
    float* ff2_T = ff1_T + 4096;
    float* op1_T = ff2_T + 4096;

    k_prep<<<182, 256, 0, stream>>>(W_wo, W_inp, attn_in_w, attn_out_w, ff1_w, ff2_w, W_op1,
                                    W_woT, W_inpT, ain_T, aout_T, ff1_T, ff2_T, op1_T);
    k_phaseA<<<B_ * T_, 128, 0, stream>>>(last_obs, deltas, medians, W_woT, b_wo, W_inpT, b_inp, data);
    k_qkv<<<B_ * N2T, 192, 0, stream>>>(data, ain_T, attn_in_b, qb, kb, vb);
    k_attn<<<N2T * NH_, 256, 0, stream>>>(qb, kb, vb, attnO);
    k_transform<<<B_ * N2T, 64, 0, stream>>>(data, attnO, aout_T, attn_out_b,
                                             ln1_g, ln1_b, ff1_T, ff1_b, ff2_T, ff2_b,
                                             ln2_g, ln2_b, op1_T, b_op1, val);
    k_reduce_h0<<<B_, H_, 0, stream>>>(val, W_op2, b_op2, h0);
    k_den<<<T_, 256, 0, stream>>>(mask, den);
    k_scan<<<B_, 512, 0, stream>>>(x, mask, deltas,
                                   W_dh, b_dh, W_dx, b_dx, W_hist, b_hist, W_feat, b_feat,
                                   W_wc, b_wc, W_ih, W_hh, b_ih, b_hh, W_cls, b_cls,
                                   h0, out, nump);
    k_loss<<<1, 64, 0, stream>>>(nump, den, out);
}

// Round 10
// 625.948 us; speedup vs baseline: 3.4010x; 1.3868x over previous
//
#include <hip/hip_runtime.h>
#include <math.h>

#define B_  256
#define T_  48
#define D_  89
#define H_  128
#define C_  64
#define NH_ 8
#define HD_ 8
#define N2T 96   // 2*T

// output layout (floats)
#define XIMP_OFF 0
#define LOSS_OFF 1093632
#define HID_OFF  1093633
#define Y_OFF    2666497
#define YS_OFF   2666753

typedef unsigned int uint_t;

__device__ __forceinline__ float wave_sum64(float v) {
    v += __shfl_xor(v, 32);
    v += __shfl_xor(v, 16);
    v += __shfl_xor(v, 8);
    v += __shfl_xor(v, 4);
    v += __shfl_xor(v, 2);
    v += __shfl_xor(v, 1);
    return v;
}

// pack two f32 into bf16x2 (RNE)
__device__ __forceinline__ uint_t pack2(float lo, float hi) {
    uint_t a = __float_as_uint(lo), b = __float_as_uint(hi);
    a = (a + 0x7fffu + ((a >> 16) & 1u)) >> 16;
    b = (b + 0x7fffu + ((b >> 16) & 1u)) >> 16;
    return a | (b << 16);
}
__device__ __forceinline__ float blo(uint_t w) { return __uint_as_float(w << 16); }
__device__ __forceinline__ float bhi(uint_t w) { return __uint_as_float(w & 0xffff0000u); }
__device__ __forceinline__ float sigm(float v) { return 1.f / (1.f + __expf(-v)); }

// ---------------- prep: f32 transposes for the transformer-phase kernels only
__device__ __forceinline__ void tr_f32(const float* __restrict__ s, float* __restrict__ d,
                                       int li, int R, int C) {
    int r = li / C, c = li - r * C;
    d[c * R + r] = s[li];
}

__global__ void k_prep(const float* W_wo, const float* W_inp, const float* ain_w,
                       const float* aout_w, const float* ff1_w, const float* ff2_w,
                       const float* W_op1,
                       float* W_woT, float* W_inpT, float* ain_T,
                       float* aout_T, float* ff1_T, float* ff2_T, float* op1_T) {
    int i = blockIdx.x * 256 + threadIdx.x;
    if (i < 7921)         tr_f32(W_wo,   W_woT,  i,          89, 89);
    else if (i < 13617)   tr_f32(W_inp,  W_inpT, i - 7921,   64, 89);
    else if (i < 25905)   tr_f32(ain_w,  ain_T,  i - 13617, 192, 64);
    else if (i < 30001)   tr_f32(aout_w, aout_T, i - 25905,  64, 64);
    else if (i < 34097)   tr_f32(ff1_w,  ff1_T,  i - 30001,  64, 64);
    else if (i < 38193)   tr_f32(ff2_w,  ff2_T,  i - 34097,  64, 64);
    else if (i < 46385)   tr_f32(W_op1,  op1_T,  i - 38193, 128, 64);
}

// ---------------- pack scan weights to bf16 row-major (NOT transposed)
__global__ void k_pack(const float* __restrict__ W_dh, const float* __restrict__ W_hist,
                       const float* __restrict__ W_ih, const float* __restrict__ W_hh,
                       uint_t* __restrict__ wdh_b, uint_t* __restrict__ whist_b,
                       uint_t* __restrict__ wih_b, uint_t* __restrict__ whh_b) {
    int i = blockIdx.x * 256 + threadIdx.x;
    if (i < 5760) {                       // W_dh: 128 rows x 45 uints (K=89, pad hi=0)
        int r = i / 45, c = i - r * 45;
        const float* src = W_dh + r * 89;
        float lo = (2 * c < 89) ? src[2 * c] : 0.f;
        float hi = (2 * c + 1 < 89) ? src[2 * c + 1] : 0.f;
        wdh_b[i] = pack2(lo, hi);
    } else if (i < 11456) {               // W_hist: 89 rows x 64 uints (K=128)
        int j = i - 5760;
        int r = j / 64, c = j - r * 64;
        const float* src = W_hist + r * 128;
        whist_b[j] = pack2(src[2 * c], src[2 * c + 1]);
    } else if (i < 45632) {               // W_ih: 384 rows x 89 uints (K=178)
        int j = i - 11456;
        int r = j / 89, c = j - r * 89;
        const float* src = W_ih + (size_t)r * 178;
        wih_b[j] = pack2(src[2 * c], src[2 * c + 1]);
    } else if (i < 70208) {               // W_hh: 384 rows x 64 uints (K=128)
        int j = i - 45632;
        int r = j / 64, c = j - r * 64;
        const float* src = W_hh + (size_t)r * 128;
        whh_b[j] = pack2(src[2 * c], src[2 * c + 1]);
    }
}

// ---------------- Phase A
__global__ void k_phaseA(const float* __restrict__ last_obs,
                         const float* __restrict__ deltas,
                         const float* __restrict__ medians,
                         const float* __restrict__ W_woT, const float* __restrict__ b_wo,
                         const float* __restrict__ W_inpT, const float* __restrict__ b_inp,
                         float* __restrict__ data) {
    int bt = blockIdx.x;
    int b = bt / T_;
    int t = bt - b * T_;
    __shared__ float dd[D_], lo[D_], dec[D_];
    int tid = threadIdx.x;
    int base = (b * T_ + t) * D_;
    if (tid < D_) {
        float dv = deltas[base + tid] - medians[tid];
        dd[tid] = dv;
        lo[tid] = last_obs[base + tid];
    }
    __syncthreads();
    if (tid < D_) {
        float acc = b_wo[tid];
        for (int j = 0; j < D_; ++j) acc = fmaf(dd[j], W_woT[j * D_ + tid], acc);
        float dv = dd[tid];
        float s = (dv > 0.f) ? 1.f : ((dv < 0.f) ? -1.f : 0.f);
        dec[tid] = 0.5f * (1.f - tanhf(s * fabsf(acc)));
    }
    __syncthreads();
    int c = tid & 63;
    int half = tid >> 6;
    const float* src = half ? dec : lo;
    float acc = b_inp[c];
    for (int j = 0; j < D_; ++j) acc = fmaf(src[j], W_inpT[j * C_ + c], acc);
    int i = c >> 1;
    float div = __expf((float)i * -0.28782313662425574f);
    float ang = (float)t * div;
    float pe = (c & 1) ? cosf(ang) : sinf(ang);
    data[((b * N2T) + half * T_ + t) * C_ + c] = acc + pe;
}

// ---------------- qkv
__global__ void k_qkv(const float* __restrict__ data,
                      const float* __restrict__ ain_T, const float* __restrict__ ain_b,
                      float* __restrict__ qb, float* __restrict__ kb, float* __restrict__ vb) {
    int bn = blockIdx.x;
    int s = bn / N2T;
    int n = bn - s * N2T;
    __shared__ float row[C_];
    int tid = threadIdx.x;
    if (tid < C_) row[tid] = data[bn * C_ + tid];
    __syncthreads();
    float acc = ain_b[tid];
    for (int j = 0; j < C_; ++j) acc = fmaf(row[j], ain_T[j * 192 + tid], acc);
    int part = tid >> 6;
    int c = tid & 63;
    int h = c >> 3, d = c & 7;
    float* dst = (part == 0) ? qb : ((part == 1) ? kb : vb);
    dst[(((n * NH_ + h) * B_ + s) * HD_) + d] = acc;
}

// ---------------- attention
__global__ void k_attn(const float* __restrict__ qb, const float* __restrict__ kb,
                       const float* __restrict__ vb, float* __restrict__ attnO) {
    int n = blockIdx.x >> 3;
    int h = blockIdx.x & 7;
    __shared__ float k_lds[B_][HD_ + 1];
    __shared__ float v_lds[B_][HD_ + 1];
    int s = threadIdx.x;
    const float scale = 0.35355339059327373f;
    size_t base = ((size_t)blockIdx.x * B_ + s) * HD_;
    float q[HD_];
    #pragma unroll
    for (int d = 0; d < HD_; ++d) q[d] = qb[base + d] * scale;
    #pragma unroll
    for (int d = 0; d < HD_; ++d) { k_lds[s][d] = kb[base + d]; v_lds[s][d] = vb[base + d]; }
    __syncthreads();
    float m = -1e30f;
    for (int t = 0; t < B_; ++t) {
        float sc = 0.f;
        #pragma unroll
        for (int d = 0; d < HD_; ++d) sc = fmaf(q[d], k_lds[t][d], sc);
        m = fmaxf(m, sc);
    }
    float l = 0.f;
    float acc[HD_] = {0.f, 0.f, 0.f, 0.f, 0.f, 0.f, 0.f, 0.f};
    for (int t = 0; t < B_; ++t) {
        float sc = 0.f;
        #pragma unroll
        for (int d = 0; d < HD_; ++d) sc = fmaf(q[d], k_lds[t][d], sc);
        float p = __expf(sc - m);
        l += p;
        #pragma unroll
        for (int d = 0; d < HD_; ++d) acc[d] = fmaf(p, v_lds[t][d], acc[d]);
    }
    float inv = 1.f / l;
    float* op = attnO + ((size_t)s * N2T + n) * C_ + h * HD_;
    #pragma unroll
    for (int d = 0; d < HD_; ++d) op[d] = acc[d] * inv;
}

// ---------------- transformer post-attn
__global__ void k_transform(const float* __restrict__ data,
                            const float* __restrict__ attnO,
                            const float* __restrict__ aout_T, const float* __restrict__ aout_b,
                            const float* __restrict__ ln1_g, const float* __restrict__ ln1_b,
                            const float* __restrict__ ff1_T, const float* __restrict__ ff1_b,
                            const float* __restrict__ ff2_T, const float* __restrict__ ff2_b,
                            const float* __restrict__ ln2_g, const float* __restrict__ ln2_b,
                            const float* __restrict__ op1_T, const float* __restrict__ b_op1,
                            float* __restrict__ val) {
    int bn = blockIdx.x;
    __shared__ float orow[C_], x1s[C_], hbuf[C_], x2s[C_];
    int c = threadIdx.x;
    float d0 = data[bn * C_ + c];
    orow[c] = attnO[bn * C_ + c];
    __syncthreads();
    float acc = aout_b[c];
    for (int j = 0; j < C_; ++j) acc = fmaf(orow[j], aout_T[j * C_ + c], acc);
    float r = d0 + acc;
    float mean = wave_sum64(r) * (1.f / 64.f);
    float df = r - mean;
    float var = wave_sum64(df * df) * (1.f / 64.f);
    float x1 = df * rsqrtf(var + 1e-5f) * ln1_g[c] + ln1_b[c];
    x1s[c] = x1;
    __syncthreads();
    acc = ff1_b[c];
    for (int j = 0; j < C_; ++j) acc = fmaf(x1s[j], ff1_T[j * C_ + c], acc);
    float ge = 0.5f * acc * (1.f + erff(acc * 0.7071067811865475f));
    hbuf[c] = ge;
    __syncthreads();
    acc = ff2_b[c];
    for (int j = 0; j < C_; ++j) acc = fmaf(hbuf[j], ff2_T[j * C_ + c], acc);
    float r2 = x1 + acc;
    float mean2 = wave_sum64(r2) * (1.f / 64.f);
    float df2 = r2 - mean2;
    float var2 = wave_sum64(df2 * df2) * (1.f / 64.f);
    float x2 = df2 * rsqrtf(var2 + 1e-5f) * ln2_g[c] + ln2_b[c];
    x2s[c] = x2;
    __syncthreads();
    #pragma unroll
    for (int rep = 0; rep < 2; ++rep) {
        int k = c + rep * 64;
        float a2 = b_op1[k];
        for (int j = 0; j < C_; ++j) a2 = fmaf(x2s[j], op1_T[j * H_ + k], a2);
        val[(size_t)bn * H_ + k] = a2;
    }
}

// ---------------- h0 reduce
__global__ void k_reduce_h0(const float* __restrict__ val,
                            const float* __restrict__ W_op2, const float* __restrict__ b_op2,
                            float* __restrict__ h0) {
    int b = blockIdx.x;
    int h = threadIdx.x;
    float acc = b_op2[0];
    for (int n = 0; n < N2T; ++n)
        acc = fmaf(val[((size_t)b * N2T + n) * H_ + h], W_op2[n], acc);
    h0[b * H_ + h] = acc;
}

// ---------------- per-step mask denominator
__global__ void k_den(const float* __restrict__ mask, float* __restrict__ den) {
    int t = blockIdx.x;
    int tid = threadIdx.x;
    float s = 0.f;
    const int total = B_ * D_;
    for (int i = tid; i < total; i += 256) {
        int b = i / D_;
        int d = i - b * D_;
        s += mask[(b * T_ + t) * D_ + d];
    }
    s = wave_sum64(s);
    __shared__ float red[4];
    if ((tid & 63) == 0) red[tid >> 6] = s;
    __syncthreads();
    if (tid == 0) den[t] = red[0] + red[1] + red[2] + red[3];
}

// ---------------- recurrent scan: 256 blocks x 1024 threads (16 waves), 1 batch/block.
// Round-9 wave-level (row, j-slice) pattern (proven: FETCH 9MB, scan 660us) with:
//  * 16 waves (4/SIMD) for 2x latency hiding
//  * gh merged into the x_h phase (both need only post-decay h) -> balanced chunks
//  * streamed weights bf16-packed row-major in d_ws (half the L2 stream)
__global__ __launch_bounds__(1024)
void k_scan(const float* __restrict__ x, const float* __restrict__ mask,
            const float* __restrict__ deltas,
            const uint_t* __restrict__ wdh_b, const float* __restrict__ b_dh,
            const float* __restrict__ W_dx, const float* __restrict__ b_dx,
            const uint_t* __restrict__ whist_b, const float* __restrict__ b_hist,
            const float* __restrict__ W_feat, const float* __restrict__ b_feat,
            const float* __restrict__ W_wc, const float* __restrict__ b_wc,
            const uint_t* __restrict__ wih_b, const uint_t* __restrict__ whh_b,
            const float* __restrict__ b_ih, const float* __restrict__ b_hh,
            const float* __restrict__ W_cls, const float* __restrict__ b_cls,
            const float* __restrict__ h0,
            float* __restrict__ out, float* __restrict__ num_part) {
    int b = blockIdx.x;
    int tid = threadIdx.x;
    int wave = tid >> 6;
    int lane = tid & 63;
    int oo = lane >> 3;       // row within chunk
    int jj = lane & 7;        // j-slice

    __shared__ __align__(16) float h_s[H_];
    __shared__ __align__(16) float xt_s[96], dt_s[96], xr_s[96], xh_s[96], diff_s[96];
    __shared__ __align__(16) float catg_s[184];   // [ximp(89) | m(89)]
    __shared__ __align__(16) float catb_s[184];   // [gx(89)   | m(89)]
    __shared__ __align__(16) float gis[384], ghs[384];
    __shared__ __align__(16) uint_t wwc_l[7921];   // W_wc bf16 pairs, row stride 89
    __shared__ __align__(16) uint_t wfeat_l[4005]; // W_feat bf16 pairs (diag=0), stride 45

    // ---- one-time staging
    for (int i = tid; i < 7921; i += 1024) {
        int r = i / 89, c = i - r * 89;
        const float* wr = W_wc + (size_t)r * 178;
        wwc_l[i] = pack2(wr[2 * c], wr[2 * c + 1]);
    }
    for (int i = tid; i < 4005; i += 1024) {
        int r = i / 45, c = i - r * 45;
        const float* wr = W_feat + r * 89;
        float lo = (2 * c == r) ? 0.f : wr[2 * c];
        float hi = (c == 44 || 2 * c + 1 == r) ? 0.f : wr[2 * c + 1];
        wfeat_l[i] = pack2(lo, hi);
    }
    if (tid < 128) h_s[tid] = h0[b * H_ + tid];
    if (tid >= 512 && tid < 519) {        // zero pads (avoid 0*NaN on tails)
        int l = tid - 512;
        xr_s[89 + l] = 0.f;
        dt_s[89 + l] = 0.f;
    }
    {
        int base = b * T_ * D_;
        if (tid >= 128 && tid < 217) xt_s[tid - 128] = x[base + tid - 128];
        else if (tid >= 224 && tid < 313) {
            float m = mask[base + tid - 224];
            catg_s[89 + tid - 224] = m;
            catb_s[89 + tid - 224] = m;
        }
        else if (tid >= 320 && tid < 409) dt_s[tid - 320] = deltas[base + tid - 320];
    }
    __syncthreads();

    for (int t = 0; t < T_; ++t) {
        // ---- P1: gamma_h decay. 128 outputs = 16 chunks, exactly 1/wave. K=89 bf16.
        {
            int o = wave * 8 + oo;
            const uint_t* wr = wdh_b + o * 45;
            float a0 = 0.f, a1 = 0.f;
            #pragma unroll
            for (int it = 0; it < 5; ++it) {
                int j = jj + 8 * it;
                uint_t w = wr[j];
                float2 dv = *(const float2*)(dt_s + 2 * j);
                a0 = fmaf(blo(w), dv.x, a0);
                a1 = fmaf(bhi(w), dv.y, a1);
            }
            if (jj < 5) {
                int j = 40 + jj;
                uint_t w = wr[j];
                float2 dv = *(const float2*)(dt_s + 2 * j);
                a0 = fmaf(blo(w), dv.x, a0);
                a1 = fmaf(bhi(w), dv.y, a1);
            }
            float acc = a0 + a1;
            acc += __shfl_xor(acc, 1); acc += __shfl_xor(acc, 2); acc += __shfl_xor(acc, 4);
            if (jj == 0) h_s[o] *= __expf(-fmaxf(acc + b_dh[o], 0.f));
        }
        __syncthreads();
        // ---- P2': x_h (chunks 0-11) + gh (chunks 12-59). Both K=128 bf16 over h_s.
        for (int c = wave; c < 60; c += 16) {
            if (c < 12) {
                int o = c * 8 + oo;
                int ro = (o < 89) ? o : 88;
                const uint_t* wr = whist_b + ro * 64;
                float a0 = 0.f, a1 = 0.f;
                #pragma unroll
                for (int it = 0; it < 8; ++it) {
                    int j = jj + 8 * it;
                    uint_t w = wr[j];
                    float2 hv = *(const float2*)(h_s + 2 * j);
                    a0 = fmaf(blo(w), hv.x, a0);
                    a1 = fmaf(bhi(w), hv.y, a1);
                }
                float acc = a0 + a1;
                acc += __shfl_xor(acc, 1); acc += __shfl_xor(acc, 2); acc += __shfl_xor(acc, 4);
                if (jj == 0 && o < 89) {
                    float xh = acc + b_hist[o];
                    xh_s[o] = xh;
                    float m = catb_s[89 + o];
                    xr_s[o] = m * xt_s[o] + (1.f - m) * xh;
                    catb_s[o] = __expf(-fmaxf(dt_s[o] * W_dx[o * 90] + b_dx[o], 0.f));
                }
            } else {
                int o = (c - 12) * 8 + oo;
                const uint_t* wr = whh_b + o * 64;
                float a0 = 0.f, a1 = 0.f;
                #pragma unroll
                for (int it = 0; it < 8; ++it) {
                    int j = jj + 8 * it;
                    uint_t w = wr[j];
                    float2 hv = *(const float2*)(h_s + 2 * j);
                    a0 = fmaf(blo(w), hv.x, a0);
                    a1 = fmaf(bhi(w), hv.y, a1);
                }
                float acc = a0 + a1;
                acc += __shfl_xor(acc, 1); acc += __shfl_xor(acc, 2); acc += __shfl_xor(acc, 4);
                if (jj == 0) ghs[o] = acc + b_hh[o];
            }
        }
        __syncthreads();
        // ---- P3: xu (LDS bf16 W_feat), beta (LDS bf16 W_wc), x_comb, x_imp.
        for (int c = wave; c < 12; c += 16) {
            int o = c * 8 + oo;
            int ro = (o < 89) ? o : 88;
            const uint_t* wf = wfeat_l + ro * 45;
            float a0 = 0.f, a1 = 0.f;
            #pragma unroll
            for (int it = 0; it < 5; ++it) {
                int j2 = jj + 8 * it;
                uint_t w = wf[j2];
                float2 xv = *(const float2*)(xr_s + 2 * j2);
                a0 = fmaf(blo(w), xv.x, a0);
                a1 = fmaf(bhi(w), xv.y, a1);
            }
            if (jj < 5) {
                int j2 = 40 + jj;
                uint_t w = wf[j2];
                float2 xv = *(const float2*)(xr_s + 2 * j2);
                a0 = fmaf(blo(w), xv.x, a0);
                a1 = fmaf(bhi(w), xv.y, a1);
            }
            float xu = a0 + a1;
            xu += __shfl_xor(xu, 1); xu += __shfl_xor(xu, 2); xu += __shfl_xor(xu, 4);
            const uint_t* wc = wwc_l + ro * 89;
            float c0 = 0.f, c1 = 0.f;
            #pragma unroll
            for (int it = 0; it < 11; ++it) {
                int j2 = jj + 8 * it;
                uint_t w = wc[j2];
                float2 cv = *(const float2*)(catb_s + 2 * j2);
                c0 = fmaf(blo(w), cv.x, c0);
                c1 = fmaf(bhi(w), cv.y, c1);
            }
            if (jj == 0) {
                uint_t w = wc[88];
                float2 cv = *(const float2*)(catb_s + 176);
                c0 = fmaf(blo(w), cv.x, c0);
                c1 = fmaf(bhi(w), cv.y, c1);
            }
            float bt = c0 + c1;
            bt += __shfl_xor(bt, 1); bt += __shfl_xor(bt, 2); bt += __shfl_xor(bt, 4);
            if (jj == 0 && o < 89) {
                float xuf = xu + b_feat[o];
                float btf = bt + b_wc[o];
                float xc = btf * xuf + (1.f - btf) * xh_s[o];
                float m = catb_s[89 + o];
                float xtv = xt_s[o];
                float xi = m * xtv + (1.f - m) * xc;
                catg_s[o] = xi;
                out[XIMP_OFF + (b * T_ + t) * D_ + o] = xi;
                diff_s[o] = fabsf(xtv - xc) * m;
            }
        }
        __syncthreads();
        // ---- P4': gi (K=178 bf16). 48 chunks = 3/wave.
        for (int c = wave; c < 48; c += 16) {
            int o = c * 8 + oo;
            const uint_t* wr = wih_b + o * 89;
            float a0 = 0.f, a1 = 0.f;
            #pragma unroll
            for (int it = 0; it < 11; ++it) {
                int j = jj + 8 * it;
                uint_t w = wr[j];
                float2 xv = *(const float2*)(catg_s + 2 * j);
                a0 = fmaf(blo(w), xv.x, a0);
                a1 = fmaf(bhi(w), xv.y, a1);
            }
            if (jj == 0) {
                uint_t w = wr[88];
                float2 xv = *(const float2*)(catg_s + 176);
                a0 = fmaf(blo(w), xv.x, a0);
                a1 = fmaf(bhi(w), xv.y, a1);
            }
            float acc = a0 + a1;
            acc += __shfl_xor(acc, 1); acc += __shfl_xor(acc, 2); acc += __shfl_xor(acc, 4);
            if (jj == 0) gis[o] = acc + b_ih[o];
        }
        __syncthreads();
        // ---- P5: GRU (waves 0-1) | prefetch (tid 128-409) | loss reduce (wave 15)
        if (tid < 128) {
            float r = sigm(gis[tid] + ghs[tid]);
            float z = sigm(gis[128 + tid] + ghs[128 + tid]);
            float g = tanhf(gis[256 + tid] + r * ghs[256 + tid]);
            float hn = (1.f - z) * g + z * h_s[tid];
            h_s[tid] = hn;
            out[HID_OFF + (size_t)(b * T_ + t) * H_ + tid] = hn;
        } else if (tid >= 960) {
            int l = tid - 960;
            float s = diff_s[l] + ((l < 25) ? diff_s[64 + l] : 0.f);
            s = wave_sum64(s);
            if (l == 0) num_part[t * B_ + b] = s;
        } else if (t + 1 < T_) {
            int nb = (b * T_ + t + 1) * D_;
            if (tid < 217) xt_s[tid - 128] = x[nb + tid - 128];
            else if (tid >= 224 && tid < 313) {
                float m = mask[nb + tid - 224];
                catg_s[89 + tid - 224] = m;
                catb_s[89 + tid - 224] = m;
            }
            else if (tid >= 320 && tid < 409) dt_s[tid - 320] = deltas[nb + tid - 320];
        }
        __syncthreads();
    }
    // classifier
    if (tid < 64) {
        float p = h_s[tid] * W_cls[tid] + h_s[tid + 64] * W_cls[tid + 64];
        p = wave_sum64(p);
        if (tid == 0) {
            float y = p + b_cls[0];
            out[Y_OFF + b] = y;
            out[YS_OFF + b] = 1.f / (1.f + __expf(-y));
        }
    }
}

// ---------------- final loss reduction
__global__ void k_loss(const float* __restrict__ num_part, const float* __restrict__ den,
                       float* __restrict__ out) {
    int tid = threadIdx.x;
    float v = 0.f;
    if (tid < T_) {
        float s = 0.f;
        const float* np_ = num_part + tid * B_;
        for (int b = 0; b < B_; ++b) s += np_[b];
        v = s / (den[tid] + 1e-5f);
    }
    v = wave_sum64(v);
    if (tid == 0) out[LOSS_OFF] = v;
}

extern "C" void kernel_launch(void* const* d_in, const int* in_sizes, int n_in,
                              void* d_out, int out_size, void* d_ws, size_t ws_size,
                              hipStream_t stream) {
    const float* x        = (const float*)d_in[0];
    const float* mask     = (const float*)d_in[1];
    const float* deltas   = (const float*)d_in[2];
    const float* last_obs = (const float*)d_in[3];
    const float* medians  = (const float*)d_in[4];
    const float* W_dh  = (const float*)d_in[5];
    const float* b_dh  = (const float*)d_in[6];
    const float* W_dx  = (const float*)d_in[7];
    const float* b_dx  = (const float*)d_in[8];
    const float* W_hist= (const float*)d_in[9];
    const float* b_hist= (const float*)d_in[10];
    const float* W_feat= (const float*)d_in[11];
    const float* b_feat= (const float*)d_in[12];
    const float* W_wc  = (const float*)d_in[13];
    const float* b_wc  = (const float*)d_in[14];
    const float* W_wo  = (const float*)d_in[15];
    const float* b_wo  = (const float*)d_in[16];
    const float* W_cls = (const float*)d_in[17];
    const float* b_cls = (const float*)d_in[18];
    const float* W_ih  = (const float*)d_in[19];
    const float* W_hh  = (const float*)d_in[20];
    const float* b_ih  = (const float*)d_in[21];
    const float* b_hh  = (const float*)d_in[22];
    const float* W_inp = (const float*)d_in[23];
    const float* b_inp = (const float*)d_in[24];
    const float* W_op1 = (const float*)d_in[25];
    const float* b_op1 = (const float*)d_in[26];
    const float* W_op2 = (const float*)d_in[27];
    const float* b_op2 = (const float*)d_in[28];
    const float* attn_in_w  = (const float*)d_in[29];
    const float* attn_in_b  = (const float*)d_in[30];
    const float* attn_out_w = (const float*)d_in[31];
    const float* attn_out_b = (const float*)d_in[32];
    const float* ln1_g = (const float*)d_in[33];
    const float* ln1_b = (const float*)d_in[34];
    const float* ln2_g = (const float*)d_in[35];
    const float* ln2_b = (const float*)d_in[36];
    const float* ff1_w = (const float*)d_in[37];
    const float* ff1_b = (const float*)d_in[38];
    const float* ff2_w = (const float*)d_in[39];
    const float* ff2_b = (const float*)d_in[40];

    float* out = (float*)d_out;
    float* ws = (float*)d_ws;

    float* data  = ws;
    float* qb    = data  + (size_t)B_ * N2T * C_;
    float* kb    = qb    + (size_t)N2T * NH_ * B_ * HD_;
    float* vb    = kb    + (size_t)N2T * NH_ * B_ * HD_;
    float* attnO = vb    + (size_t)N2T * NH_ * B_ * HD_;
    float* val   = attnO + (size_t)B_ * N2T * C_;
    float* h0    = val   + (size_t)B_ * N2T * H_;
    float* den   = h0    + (size_t)B_ * H_;
    float* nump  = den   + 64;
    float* W_woT = nump  + T_ * B_;
    float* W_inpT= W_woT + 7921;
    float* ain_T = W_inpT + 5696;
    float* aout_T= ain_T + 12288;
    float* ff1_T = aout_T + 4096;
    float* ff2_T = ff1_T + 4096;
    float* op1_T = ff2_T + 4096;
    uint_t* wdh_b   = (uint_t*)(op1_T + 8192);
    uint_t* whist_b = wdh_b + 5760;
    uint_t* wih_b   = whist_b + 5696;
    uint_t* whh_b   = wih_b + 34176;

    k_prep<<<182, 256, 0, stream>>>(W_wo, W_inp, attn_in_w, attn_out_w, ff1_w, ff2_w, W_op1,
                                    W_woT, W_inpT, ain_T, aout_T, ff1_T, ff2_T, op1_T);
    k_pack<<<275, 256, 0, stream>>>(W_dh, W_hist, W_ih, W_hh, wdh_b, whist_b, wih_b, whh_b);
    k_phaseA<<<B_ * T_, 128, 0, stream>>>(last_obs, deltas, medians, W_woT, b_wo, W_inpT, b_inp, data);
    k_qkv<<<B_ * N2T, 192, 0, stream>>>(data, ain_T, attn_in_b, qb, kb, vb);
    k_attn<<<N2T * NH_, 256, 0, stream>>>(qb, kb, vb, attnO);
    k_transform<<<B_ * N2T, 64, 0, stream>>>(data, attnO, aout_T, attn_out_b,
                                             ln1_g, ln1_b, ff1_T, ff1_b, ff2_T, ff2_b,
                                             ln2_g, ln2_b, op1_T, b_op1, val);
    k_reduce_h0<<<B_, H_, 0, stream>>>(val, W_op2, b_op2, h0);
    k_den<<<T_, 256, 0, stream>>>(mask, den);
    k_scan<<<B_, 1024, 0, stream>>>(x, mask, deltas,
                                    wdh_b, b_dh, W_dx, b_dx, whist_b, b_hist, W_feat, b_feat,
                                    W_wc, b_wc, wih_b, whh_b, b_ih, b_hh, W_cls, b_cls,
                                    h0, out, nump);
    k_loss<<<1, 64, 0, stream>>>(nump, den, out);
}

// Round 11
// 625.504 us; speedup vs baseline: 3.4034x; 1.0007x over previous
//
#include <hip/hip_runtime.h>
#include <math.h>

#define B_  256
#define T_  48
#define D_  89
#define H_  128
#define C_  64
#define NH_ 8
#define HD_ 8
#define N2T 96   // 2*T

// output layout (floats)
#define XIMP_OFF 0
#define LOSS_OFF 1093632
#define HID_OFF  1093633
#define Y_OFF    2666497
#define YS_OFF   2666753

typedef unsigned int uint_t;

__device__ __forceinline__ float wave_sum64(float v) {
    v += __shfl_xor(v, 32);
    v += __shfl_xor(v, 16);
    v += __shfl_xor(v, 8);
    v += __shfl_xor(v, 4);
    v += __shfl_xor(v, 2);
    v += __shfl_xor(v, 1);
    return v;
}

// pack two f32 into bf16x2 (RNE)
__device__ __forceinline__ uint_t pack2(float lo, float hi) {
    uint_t a = __float_as_uint(lo), b = __float_as_uint(hi);
    a = (a + 0x7fffu + ((a >> 16) & 1u)) >> 16;
    b = (b + 0x7fffu + ((b >> 16) & 1u)) >> 16;
    return a | (b << 16);
}
__device__ __forceinline__ float blo(uint_t w) { return __uint_as_float(w << 16); }
__device__ __forceinline__ float bhi(uint_t w) { return __uint_as_float(w & 0xffff0000u); }
__device__ __forceinline__ float sigm(float v) { return 1.f / (1.f + __expf(-v)); }

// ---------------- prep: f32 transposes for the transformer-phase kernels only
__device__ __forceinline__ void tr_f32(const float* __restrict__ s, float* __restrict__ d,
                                       int li, int R, int C) {
    int r = li / C, c = li - r * C;
    d[c * R + r] = s[li];
}

__global__ void k_prep(const float* W_wo, const float* W_inp, const float* ain_w,
                       const float* aout_w, const float* ff1_w, const float* ff2_w,
                       const float* W_op1,
                       float* W_woT, float* W_inpT, float* ain_T,
                       float* aout_T, float* ff1_T, float* ff2_T, float* op1_T) {
    int i = blockIdx.x * 256 + threadIdx.x;
    if (i < 7921)         tr_f32(W_wo,   W_woT,  i,          89, 89);
    else if (i < 13617)   tr_f32(W_inp,  W_inpT, i - 7921,   64, 89);
    else if (i < 25905)   tr_f32(ain_w,  ain_T,  i - 13617, 192, 64);
    else if (i < 30001)   tr_f32(aout_w, aout_T, i - 25905,  64, 64);
    else if (i < 34097)   tr_f32(ff1_w,  ff1_T,  i - 30001,  64, 64);
    else if (i < 38193)   tr_f32(ff2_w,  ff2_T,  i - 34097,  64, 64);
    else if (i < 46385)   tr_f32(W_op1,  op1_T,  i - 38193, 128, 64);
}

// ---------------- pack scan weights to bf16 row-major; W_ih split x/m halves
__global__ void k_pack(const float* __restrict__ W_dh, const float* __restrict__ W_hist,
                       const float* __restrict__ W_ih, const float* __restrict__ W_hh,
                       uint_t* __restrict__ wdh_b, uint_t* __restrict__ whist_b,
                       uint_t* __restrict__ wihx_b, uint_t* __restrict__ wihm_b,
                       uint_t* __restrict__ whh_b) {
    int i = blockIdx.x * 256 + threadIdx.x;
    if (i < 5760) {                       // W_dh: 128 x 45 uints (K=89, pad)
        int r = i / 45, c = i - r * 45;
        const float* src = W_dh + r * 89;
        float lo = (2 * c < 89) ? src[2 * c] : 0.f;
        float hi = (2 * c + 1 < 89) ? src[2 * c + 1] : 0.f;
        wdh_b[i] = pack2(lo, hi);
    } else if (i < 11456) {               // W_hist: 89 x 64 uints (K=128)
        int j = i - 5760;
        int r = j / 64, c = j - r * 64;
        const float* src = W_hist + r * 128;
        whist_b[j] = pack2(src[2 * c], src[2 * c + 1]);
    } else if (i < 28736) {               // W_ih x-part: 384 x 45 (cols 0..88)
        int j = i - 11456;
        int r = j / 45, c = j - r * 45;
        const float* src = W_ih + (size_t)r * 178;
        float lo = src[2 * c];
        float hi = (2 * c + 1 < 89) ? src[2 * c + 1] : 0.f;
        wihx_b[j] = pack2(lo, hi);
    } else if (i < 46016) {               // W_ih m-part: 384 x 45 (cols 89..177)
        int j = i - 28736;
        int r = j / 45, c = j - r * 45;
        const float* src = W_ih + (size_t)r * 178 + 89;
        float lo = src[2 * c];
        float hi = (2 * c + 1 < 89) ? src[2 * c + 1] : 0.f;
        wihm_b[j] = pack2(lo, hi);
    } else if (i < 70592) {               // W_hh: 384 x 64 uints (K=128)
        int j = i - 46016;
        int r = j / 64, c = j - r * 64;
        const float* src = W_hh + (size_t)r * 128;
        whh_b[j] = pack2(src[2 * c], src[2 * c + 1]);
    }
}

// ---------------- Phase A
__global__ void k_phaseA(const float* __restrict__ last_obs,
                         const float* __restrict__ deltas,
                         const float* __restrict__ medians,
                         const float* __restrict__ W_woT, const float* __restrict__ b_wo,
                         const float* __restrict__ W_inpT, const float* __restrict__ b_inp,
                         float* __restrict__ data) {
    int bt = blockIdx.x;
    int b = bt / T_;
    int t = bt - b * T_;
    __shared__ float dd[D_], lo[D_], dec[D_];
    int tid = threadIdx.x;
    int base = (b * T_ + t) * D_;
    if (tid < D_) {
        float dv = deltas[base + tid] - medians[tid];
        dd[tid] = dv;
        lo[tid] = last_obs[base + tid];
    }
    __syncthreads();
    if (tid < D_) {
        float acc = b_wo[tid];
        for (int j = 0; j < D_; ++j) acc = fmaf(dd[j], W_woT[j * D_ + tid], acc);
        float dv = dd[tid];
        float s = (dv > 0.f) ? 1.f : ((dv < 0.f) ? -1.f : 0.f);
        dec[tid] = 0.5f * (1.f - tanhf(s * fabsf(acc)));
    }
    __syncthreads();
    int c = tid & 63;
    int half = tid >> 6;
    const float* src = half ? dec : lo;
    float acc = b_inp[c];
    for (int j = 0; j < D_; ++j) acc = fmaf(src[j], W_inpT[j * C_ + c], acc);
    int i = c >> 1;
    float div = __expf((float)i * -0.28782313662425574f);
    float ang = (float)t * div;
    float pe = (c & 1) ? cosf(ang) : sinf(ang);
    data[((b * N2T) + half * T_ + t) * C_ + c] = acc + pe;
}

// ---------------- qkv
__global__ void k_qkv(const float* __restrict__ data,
                      const float* __restrict__ ain_T, const float* __restrict__ ain_b,
                      float* __restrict__ qb, float* __restrict__ kb, float* __restrict__ vb) {
    int bn = blockIdx.x;
    int s = bn / N2T;
    int n = bn - s * N2T;
    __shared__ float row[C_];
    int tid = threadIdx.x;
    if (tid < C_) row[tid] = data[bn * C_ + tid];
    __syncthreads();
    float acc = ain_b[tid];
    for (int j = 0; j < C_; ++j) acc = fmaf(row[j], ain_T[j * 192 + tid], acc);
    int part = tid >> 6;
    int c = tid & 63;
    int h = c >> 3, d = c & 7;
    float* dst = (part == 0) ? qb : ((part == 1) ? kb : vb);
    dst[(((n * NH_ + h) * B_ + s) * HD_) + d] = acc;
}

// ---------------- attention
__global__ void k_attn(const float* __restrict__ qb, const float* __restrict__ kb,
                       const float* __restrict__ vb, float* __restrict__ attnO) {
    int n = blockIdx.x >> 3;
    int h = blockIdx.x & 7;
    __shared__ float k_lds[B_][HD_ + 1];
    __shared__ float v_lds[B_][HD_ + 1];
    int s = threadIdx.x;
    const float scale = 0.35355339059327373f;
    size_t base = ((size_t)blockIdx.x * B_ + s) * HD_;
    float q[HD_];
    #pragma unroll
    for (int d = 0; d < HD_; ++d) q[d] = qb[base + d] * scale;
    #pragma unroll
    for (int d = 0; d < HD_; ++d) { k_lds[s][d] = kb[base + d]; v_lds[s][d] = vb[base + d]; }
    __syncthreads();
    float m = -1e30f;
    for (int t = 0; t < B_; ++t) {
        float sc = 0.f;
        #pragma unroll
        for (int d = 0; d < HD_; ++d) sc = fmaf(q[d], k_lds[t][d], sc);
        m = fmaxf(m, sc);
    }
    float l = 0.f;
    float acc[HD_] = {0.f, 0.f, 0.f, 0.f, 0.f, 0.f, 0.f, 0.f};
    for (int t = 0; t < B_; ++t) {
        float sc = 0.f;
        #pragma unroll
        for (int d = 0; d < HD_; ++d) sc = fmaf(q[d], k_lds[t][d], sc);
        float p = __expf(sc - m);
        l += p;
        #pragma unroll
        for (int d = 0; d < HD_; ++d) acc[d] = fmaf(p, v_lds[t][d], acc[d]);
    }
    float inv = 1.f / l;
    float* op = attnO + ((size_t)s * N2T + n) * C_ + h * HD_;
    #pragma unroll
    for (int d = 0; d < HD_; ++d) op[d] = acc[d] * inv;
}

// ---------------- transformer post-attn
__global__ void k_transform(const float* __restrict__ data,
                            const float* __restrict__ attnO,
                            const float* __restrict__ aout_T, const float* __restrict__ aout_b,
                            const float* __restrict__ ln1_g, const float* __restrict__ ln1_b,
                            const float* __restrict__ ff1_T, const float* __restrict__ ff1_b,
                            const float* __restrict__ ff2_T, const float* __restrict__ ff2_b,
                            const float* __restrict__ ln2_g, const float* __restrict__ ln2_b,
                            const float* __restrict__ op1_T, const float* __restrict__ b_op1,
                            float* __restrict__ val) {
    int bn = blockIdx.x;
    __shared__ float orow[C_], x1s[C_], hbuf[C_], x2s[C_];
    int c = threadIdx.x;
    float d0 = data[bn * C_ + c];
    orow[c] = attnO[bn * C_ + c];
    __syncthreads();
    float acc = aout_b[c];
    for (int j = 0; j < C_; ++j) acc = fmaf(orow[j], aout_T[j * C_ + c], acc);
    float r = d0 + acc;
    float mean = wave_sum64(r) * (1.f / 64.f);
    float df = r - mean;
    float var = wave_sum64(df * df) * (1.f / 64.f);
    float x1 = df * rsqrtf(var + 1e-5f) * ln1_g[c] + ln1_b[c];
    x1s[c] = x1;
    __syncthreads();
    acc = ff1_b[c];
    for (int j = 0; j < C_; ++j) acc = fmaf(x1s[j], ff1_T[j * C_ + c], acc);
    float ge = 0.5f * acc * (1.f + erff(acc * 0.7071067811865475f));
    hbuf[c] = ge;
    __syncthreads();
    acc = ff2_b[c];
    for (int j = 0; j < C_; ++j) acc = fmaf(hbuf[j], ff2_T[j * C_ + c], acc);
    float r2 = x1 + acc;
    float mean2 = wave_sum64(r2) * (1.f / 64.f);
    float df2 = r2 - mean2;
    float var2 = wave_sum64(df2 * df2) * (1.f / 64.f);
    float x2 = df2 * rsqrtf(var2 + 1e-5f) * ln2_g[c] + ln2_b[c];
    x2s[c] = x2;
    __syncthreads();
    #pragma unroll
    for (int rep = 0; rep < 2; ++rep) {
        int k = c + rep * 64;
        float a2 = b_op1[k];
        for (int j = 0; j < C_; ++j) a2 = fmaf(x2s[j], op1_T[j * H_ + k], a2);
        val[(size_t)bn * H_ + k] = a2;
    }
}

// ---------------- h0 reduce
__global__ void k_reduce_h0(const float* __restrict__ val,
                            const float* __restrict__ W_op2, const float* __restrict__ b_op2,
                            float* __restrict__ h0) {
    int b = blockIdx.x;
    int h = threadIdx.x;
    float acc = b_op2[0];
    for (int n = 0; n < N2T; ++n)
        acc = fmaf(val[((size_t)b * N2T + n) * H_ + h], W_op2[n], acc);
    h0[b * H_ + h] = acc;
}

// ---------------- per-step mask denominator
__global__ void k_den(const float* __restrict__ mask, float* __restrict__ den) {
    int t = blockIdx.x;
    int tid = threadIdx.x;
    float s = 0.f;
    const int total = B_ * D_;
    for (int i = tid; i < total; i += 256) {
        int b = i / D_;
        int d = i - b * D_;
        s += mask[(b * T_ + t) * D_ + d];
    }
    s = wave_sum64(s);
    __shared__ float red[4];
    if ((tid & 63) == 0) red[tid >> 6] = s;
    __syncthreads();
    if (tid == 0) den[t] = red[0] + red[1] + red[2] + red[3];
}

// ---------------- recurrent scan: 256 blocks x 1024 threads (16 waves), 1 batch/block.
// Critical-path restructure vs round 10: gx is computed AT PREFETCH TIME (only
// needs dt), so beta = W_wc.[gx,m] and gi_m = W_ih[:,89:].m move into P1
// (parallel with h-decay). P4 keeps only gi_x = W_ih[:,:89].ximp (half-width).
// Phase balance (chunks over 16 waves): P1=76, P2=60, P3=12, P4=48.
__global__ __launch_bounds__(1024)
void k_scan(const float* __restrict__ x, const float* __restrict__ mask,
            const float* __restrict__ deltas,
            const uint_t* __restrict__ wdh_b, const float* __restrict__ b_dh,
            const float* __restrict__ W_dx, const float* __restrict__ b_dx,
            const uint_t* __restrict__ whist_b, const float* __restrict__ b_hist,
            const float* __restrict__ W_feat, const float* __restrict__ b_feat,
            const float* __restrict__ W_wc, const float* __restrict__ b_wc,
            const uint_t* __restrict__ wihx_b, const uint_t* __restrict__ wihm_b,
            const uint_t* __restrict__ whh_b,
            const float* __restrict__ b_ih, const float* __restrict__ b_hh,
            const float* __restrict__ W_cls, const float* __restrict__ b_cls,
            const float* __restrict__ h0,
            float* __restrict__ out, float* __restrict__ num_part) {
    int b = blockIdx.x;
    int tid = threadIdx.x;
    int wave = tid >> 6;
    int lane = tid & 63;
    int oo = lane >> 3;       // row within chunk
    int jj = lane & 7;        // j-slice

    __shared__ __align__(16) float h_s[H_];
    __shared__ __align__(16) float xt_s[96], dt_s[96], xr_s[96], xh_s[96];
    __shared__ __align__(16) float m_s[96], gx_s[96], ximp_s[96], beta_s[96], diff_s[96];
    __shared__ __align__(16) float gis[384], ghs[384];
    __shared__ __align__(16) uint_t wwcg_l[4005];  // W_wc gx-half bf16, 89 rows x 45
    __shared__ __align__(16) uint_t wwcm_l[4005];  // W_wc m-half bf16, 89 rows x 45
    __shared__ __align__(16) uint_t wfeat_l[4005]; // W_feat bf16 (diag=0), 89 x 45

    // per-thread scalars for the gx-at-prefetch role (threads 320..408)
    float dxw = 0.f, dxb = 0.f;
    if (tid >= 320 && tid < 409) {
        int o = tid - 320;
        dxw = W_dx[o * 90];
        dxb = b_dx[o];
    }

    // ---- one-time LDS staging
    for (int i = tid; i < 4005; i += 1024) {
        int r = i / 45, c = i - r * 45;
        const float* wr = W_wc + (size_t)r * 178;
        float lo = wr[2 * c];
        float hi = (2 * c + 1 < 89) ? wr[2 * c + 1] : 0.f;
        wwcg_l[i] = pack2(lo, hi);
        const float* wm = wr + 89;
        float lo2 = wm[2 * c];
        float hi2 = (2 * c + 1 < 89) ? wm[2 * c + 1] : 0.f;
        wwcm_l[i] = pack2(lo2, hi2);
        const float* wf = W_feat + r * 89;
        float lo3 = (2 * c == r) ? 0.f : wf[2 * c];
        float hi3 = (2 * c + 1 >= 89 || 2 * c + 1 == r) ? 0.f : wf[2 * c + 1];
        wfeat_l[i] = pack2(lo3, hi3);
    }
    if (tid < 128) h_s[tid] = h0[b * H_ + tid];
    if (tid >= 416 && tid < 419) {        // zero pads (avoid NaN*0 on tails)
        int l = tid - 416;
        dt_s[89 + l] = 0.f; xr_s[89 + l] = 0.f; m_s[89 + l] = 0.f;
        gx_s[89 + l] = 0.f; ximp_s[89 + l] = 0.f;
    }
    {
        int base = b * T_ * D_;
        if (tid >= 128 && tid < 217) xt_s[tid - 128] = x[base + tid - 128];
        else if (tid >= 224 && tid < 313) m_s[tid - 224] = mask[base + tid - 224];
        else if (tid >= 320 && tid < 409) {
            int o = tid - 320;
            float dv = deltas[base + o];
            dt_s[o] = dv;
            gx_s[o] = __expf(-fmaxf(dv * dxw + dxb, 0.f));
        }
    }
    __syncthreads();

    for (int t = 0; t < T_; ++t) {
        // ---- P1: h-decay (16 chunks) | beta (12 chunks) | gi_m (48 chunks)
        for (int c = wave; c < 76; c += 16) {
            if (c < 16) {
                int o = c * 8 + oo;
                const uint_t* wr = wdh_b + o * 45;
                float a0 = 0.f, a1 = 0.f;
                #pragma unroll
                for (int it = 0; it < 5; ++it) {
                    int j = jj + 8 * it;
                    uint_t w = wr[j];
                    float2 dv = *(const float2*)(dt_s + 2 * j);
                    a0 = fmaf(blo(w), dv.x, a0);
                    a1 = fmaf(bhi(w), dv.y, a1);
                }
                if (jj < 5) {
                    int j = 40 + jj;
                    uint_t w = wr[j];
                    float2 dv = *(const float2*)(dt_s + 2 * j);
                    a0 = fmaf(blo(w), dv.x, a0);
                    a1 = fmaf(bhi(w), dv.y, a1);
                }
                float acc = a0 + a1;
                acc += __shfl_xor(acc, 1); acc += __shfl_xor(acc, 2); acc += __shfl_xor(acc, 4);
                if (jj == 0) h_s[o] *= __expf(-fmaxf(acc + b_dh[o], 0.f));
            } else if (c < 28) {
                int o = (c - 16) * 8 + oo;
                int ro = (o < 89) ? o : 88;
                const uint_t* wg = wwcg_l + ro * 45;
                const uint_t* wm = wwcm_l + ro * 45;
                float a0 = 0.f, a1 = 0.f;
                #pragma unroll
                for (int it = 0; it < 5; ++it) {
                    int j = jj + 8 * it;
                    uint_t w1 = wg[j], w2 = wm[j];
                    float2 gv = *(const float2*)(gx_s + 2 * j);
                    float2 mv = *(const float2*)(m_s + 2 * j);
                    a0 = fmaf(blo(w1), gv.x, a0);
                    a1 = fmaf(bhi(w1), gv.y, a1);
                    a0 = fmaf(blo(w2), mv.x, a0);
                    a1 = fmaf(bhi(w2), mv.y, a1);
                }
                if (jj < 5) {
                    int j = 40 + jj;
                    uint_t w1 = wg[j], w2 = wm[j];
                    float2 gv = *(const float2*)(gx_s + 2 * j);
                    float2 mv = *(const float2*)(m_s + 2 * j);
                    a0 = fmaf(blo(w1), gv.x, a0);
                    a1 = fmaf(bhi(w1), gv.y, a1);
                    a0 = fmaf(blo(w2), mv.x, a0);
                    a1 = fmaf(bhi(w2), mv.y, a1);
                }
                float acc = a0 + a1;
                acc += __shfl_xor(acc, 1); acc += __shfl_xor(acc, 2); acc += __shfl_xor(acc, 4);
                if (jj == 0 && o < 89) beta_s[o] = acc + b_wc[o];
            } else {
                int o = (c - 28) * 8 + oo;
                const uint_t* wr = wihm_b + o * 45;
                float a0 = 0.f, a1 = 0.f;
                #pragma unroll
                for (int it = 0; it < 5; ++it) {
                    int j = jj + 8 * it;
                    uint_t w = wr[j];
                    float2 mv = *(const float2*)(m_s + 2 * j);
                    a0 = fmaf(blo(w), mv.x, a0);
                    a1 = fmaf(bhi(w), mv.y, a1);
                }
                if (jj < 5) {
                    int j = 40 + jj;
                    uint_t w = wr[j];
                    float2 mv = *(const float2*)(m_s + 2 * j);
                    a0 = fmaf(blo(w), mv.x, a0);
                    a1 = fmaf(bhi(w), mv.y, a1);
                }
                float acc = a0 + a1;
                acc += __shfl_xor(acc, 1); acc += __shfl_xor(acc, 2); acc += __shfl_xor(acc, 4);
                if (jj == 0) gis[o] = acc + b_ih[o];
            }
        }
        __syncthreads();
        // ---- P2: x_h (chunks 0-11) + gh (chunks 12-59). Both K=128 over h_s.
        for (int c = wave; c < 60; c += 16) {
            if (c < 12) {
                int o = c * 8 + oo;
                int ro = (o < 89) ? o : 88;
                const uint_t* wr = whist_b + ro * 64;
                float a0 = 0.f, a1 = 0.f;
                #pragma unroll
                for (int it = 0; it < 8; ++it) {
                    int j = jj + 8 * it;
                    uint_t w = wr[j];
                    float2 hv = *(const float2*)(h_s + 2 * j);
                    a0 = fmaf(blo(w), hv.x, a0);
                    a1 = fmaf(bhi(w), hv.y, a1);
                }
                float acc = a0 + a1;
                acc += __shfl_xor(acc, 1); acc += __shfl_xor(acc, 2); acc += __shfl_xor(acc, 4);
                if (jj == 0 && o < 89) {
                    float xh = acc + b_hist[o];
                    xh_s[o] = xh;
                    float m = m_s[o];
                    xr_s[o] = m * xt_s[o] + (1.f - m) * xh;
                }
            } else {
                int o = (c - 12) * 8 + oo;
                const uint_t* wr = whh_b + o * 64;
                float a0 = 0.f, a1 = 0.f;
                #pragma unroll
                for (int it = 0; it < 8; ++it) {
                    int j = jj + 8 * it;
                    uint_t w = wr[j];
                    float2 hv = *(const float2*)(h_s + 2 * j);
                    a0 = fmaf(blo(w), hv.x, a0);
                    a1 = fmaf(bhi(w), hv.y, a1);
                }
                float acc = a0 + a1;
                acc += __shfl_xor(acc, 1); acc += __shfl_xor(acc, 2); acc += __shfl_xor(acc, 4);
                if (jj == 0) ghs[o] = acc + b_hh[o];
            }
        }
        __syncthreads();
        // ---- P3: xu dot (12 chunks) + combine using precomputed beta.
        for (int c = wave; c < 12; c += 16) {
            int o = c * 8 + oo;
            int ro = (o < 89) ? o : 88;
            const uint_t* wf = wfeat_l + ro * 45;
            float a0 = 0.f, a1 = 0.f;
            #pragma unroll
            for (int it = 0; it < 5; ++it) {
                int j = jj + 8 * it;
                uint_t w = wf[j];
                float2 xv = *(const float2*)(xr_s + 2 * j);
                a0 = fmaf(blo(w), xv.x, a0);
                a1 = fmaf(bhi(w), xv.y, a1);
            }
            if (jj < 5) {
                int j = 40 + jj;
                uint_t w = wf[j];
                float2 xv = *(const float2*)(xr_s + 2 * j);
                a0 = fmaf(blo(w), xv.x, a0);
                a1 = fmaf(bhi(w), xv.y, a1);
            }
            float xu = a0 + a1;
            xu += __shfl_xor(xu, 1); xu += __shfl_xor(xu, 2); xu += __shfl_xor(xu, 4);
            if (jj == 0 && o < 89) {
                float xuf = xu + b_feat[o];
                float btf = beta_s[o];
                float xc = btf * xuf + (1.f - btf) * xh_s[o];
                float m = m_s[o];
                float xtv = xt_s[o];
                float xi = m * xtv + (1.f - m) * xc;
                ximp_s[o] = xi;
                out[XIMP_OFF + (b * T_ + t) * D_ + o] = xi;
                diff_s[o] = fabsf(xtv - xc) * m;
            }
        }
        __syncthreads();
        // ---- P4: gi_x = W_ih[:, :89] . ximp (48 chunks, half-width).
        for (int c = wave; c < 48; c += 16) {
            int o = c * 8 + oo;
            const uint_t* wr = wihx_b + o * 45;
            float a0 = 0.f, a1 = 0.f;
            #pragma unroll
            for (int it = 0; it < 5; ++it) {
                int j = jj + 8 * it;
                uint_t w = wr[j];
                float2 xv = *(const float2*)(ximp_s + 2 * j);
                a0 = fmaf(blo(w), xv.x, a0);
                a1 = fmaf(bhi(w), xv.y, a1);
            }
            if (jj < 5) {
                int j = 40 + jj;
                uint_t w = wr[j];
                float2 xv = *(const float2*)(ximp_s + 2 * j);
                a0 = fmaf(blo(w), xv.x, a0);
                a1 = fmaf(bhi(w), xv.y, a1);
            }
            float acc = a0 + a1;
            acc += __shfl_xor(acc, 1); acc += __shfl_xor(acc, 2); acc += __shfl_xor(acc, 4);
            if (jj == 0) gis[o] += acc;
        }
        __syncthreads();
        // ---- P5: GRU (waves 0-1) | prefetch+gx (tid 128-408) | loss (wave 15)
        if (tid < 128) {
            float r = sigm(gis[tid] + ghs[tid]);
            float z = sigm(gis[128 + tid] + ghs[128 + tid]);
            float g = tanhf(gis[256 + tid] + r * ghs[256 + tid]);
            float hn = (1.f - z) * g + z * h_s[tid];
            h_s[tid] = hn;
            out[HID_OFF + (size_t)(b * T_ + t) * H_ + tid] = hn;
        } else if (tid >= 960) {
            int l = tid - 960;
            float s = diff_s[l] + ((l < 25) ? diff_s[64 + l] : 0.f);
            s = wave_sum64(s);
            if (l == 0) num_part[t * B_ + b] = s;
        } else if (t + 1 < T_) {
            int nb = (b * T_ + t + 1) * D_;
            if (tid < 217) xt_s[tid - 128] = x[nb + tid - 128];
            else if (tid >= 224 && tid < 313) m_s[tid - 224] = mask[nb + tid - 224];
            else if (tid >= 320 && tid < 409) {
                int o = tid - 320;
                float dv = deltas[nb + o];
                dt_s[o] = dv;
                gx_s[o] = __expf(-fmaxf(dv * dxw + dxb, 0.f));
            }
        }
        __syncthreads();
    }
    // classifier
    if (tid < 64) {
        float p = h_s[tid] * W_cls[tid] + h_s[tid + 64] * W_cls[tid + 64];
        p = wave_sum64(p);
        if (tid == 0) {
            float y = p + b_cls[0];
            out[Y_OFF + b] = y;
            out[YS_OFF + b] = 1.f / (1.f + __expf(-y));
        }
    }
}

// ---------------- final loss reduction
__global__ void k_loss(const float* __restrict__ num_part, const float* __restrict__ den,
                       float* __restrict__ out) {
    int tid = threadIdx.x;
    float v = 0.f;
    if (tid < T_) {
        float s = 0.f;
        const float* np_ = num_part + tid * B_;
        for (int b = 0; b < B_; ++b) s += np_[b];
        v = s / (den[tid] + 1e-5f);
    }
    v = wave_sum64(v);
    if (tid == 0) out[LOSS_OFF] = v;
}

extern "C" void kernel_launch(void* const* d_in, const int* in_sizes, int n_in,
                              void* d_out, int out_size, void* d_ws, size_t ws_size,
                              hipStream_t stream) {
    const float* x        = (const float*)d_in[0];
    const float* mask     = (const float*)d_in[1];
    const float* deltas   = (const float*)d_in[2];
    const float* last_obs = (const float*)d_in[3];
    const float* medians  = (const float*)d_in[4];
    const float* W_dh  = (const float*)d_in[5];
    const float* b_dh  = (const float*)d_in[6];
    const float* W_dx  = (const float*)d_in[7];
    const float* b_dx  = (const float*)d_in[8];
    const float* W_hist= (const float*)d_in[9];
    const float* b_hist= (const float*)d_in[10];
    const float* W_feat= (const float*)d_in[11];
    const float* b_feat= (const float*)d_in[12];
    const float* W_wc  = (const float*)d_in[13];
    const float* b_wc  = (const float*)d_in[14];
    const float* W_wo  = (const float*)d_in[15];
    const float* b_wo  = (const float*)d_in[16];
    const float* W_cls = (const float*)d_in[17];
    const float* b_cls = (const float*)d_in[18];
    const float* W_ih  = (const float*)d_in[19];
    const float* W_hh  = (const float*)d_in[20];
    const float* b_ih  = (const float*)d_in[21];
    const float* b_hh  = (const float*)d_in[22];
    const float* W_inp = (const float*)d_in[23];
    const float* b_inp = (const float*)d_in[24];
    const float* W_op1 = (const float*)d_in[25];
    const float* b_op1 = (const float*)d_in[26];
    const float* W_op2 = (const float*)d_in[27];
    const float* b_op2 = (const float*)d_in[28];
    const float* attn_in_w  = (const float*)d_in[29];
    const float* attn_in_b  = (const float*)d_in[30];
    const float* attn_out_w = (const float*)d_in[31];
    const float* attn_out_b = (const float*)d_in[32];
    const float* ln1_g = (const float*)d_in[33];
    const float* ln1_b = (const float*)d_in[34];
    const float* ln2_g = (const float*)d_in[35];
    const float* ln2_b = (const float*)d_in[36];
    const float* ff1_w = (const float*)d_in[37];
    const float* ff1_b = (const float*)d_in[38];
    const float* ff2_w = (const float*)d_in[39];
    const float* ff2_b = (const float*)d_in[40];

    float* out = (float*)d_out;
    float* ws = (float*)d_ws;

    float* data  = ws;
    float* qb    = data  + (size_t)B_ * N2T * C_;
    float* kb    = qb    + (size_t)N2T * NH_ * B_ * HD_;
    float* vb    = kb    + (size_t)N2T * NH_ * B_ * HD_;
    float* attnO = vb    + (size_t)N2T * NH_ * B_ * HD_;
    float* val   = attnO + (size_t)B_ * N2T * C_;
    float* h0    = val   + (size_t)B_ * N2T * H_;
    float* den   = h0    + (size_t)B_ * H_;
    float* nump  = den   + 64;
    float* W_woT = nump  + T_ * B_;
    float* W_inpT= W_woT + 7921;
    float* ain_T = W_inpT + 5696;
    float* aout_T= ain_T + 12288;
    float* ff1_T = aout_T + 4096;
    float* ff2_T = ff1_T + 4096;
    float* op1_T = ff2_T + 4096;
    uint_t* wdh_b   = (uint_t*)(op1_T + 8192);
    uint_t* whist_b = wdh_b + 5760;
    uint_t* wihx_b  = whist_b + 5696;
    uint_t* wihm_b  = wihx_b + 17280;
    uint_t* whh_b   = wihm_b + 17280;

    k_prep<<<182, 256, 0, stream>>>(W_wo, W_inp, attn_in_w, attn_out_w, ff1_w, ff2_w, W_op1,
                                    W_woT, W_inpT, ain_T, aout_T, ff1_T, ff2_T, op1_T);
    k_pack<<<276, 256, 0, stream>>>(W_dh, W_hist, W_ih, W_hh,
                                    wdh_b, whist_b, wihx_b, wihm_b, whh_b);
    k_phaseA<<<B_ * T_, 128, 0, stream>>>(last_obs, deltas, medians, W_woT, b_wo, W_inpT, b_inp, data);
    k_qkv<<<B_ * N2T, 192, 0, stream>>>(data, ain_T, attn_in_b, qb, kb, vb);
    k_attn<<<N2T * NH_, 256, 0, stream>>>(qb, kb, vb, attnO);
    k_transform<<<B_ * N2T, 64, 0, stream>>>(data, attnO, aout_T, attn_out_b,
                                             ln1_g, ln1_b, ff1_T, ff1_b, ff2_T, ff2_b,
                                             ln2_g, ln2_b, op1_T, b_op1, val);
    k_reduce_h0<<<B_, H_, 0, stream>>>(val, W_op2, b_op2, h0);
    k_den<<<T_, 256, 0, stream>>>(mask, den);
    k_scan<<<B_, 1024, 0, stream>>>(x, mask, deltas,
                                    wdh_b, b_dh, W_dx, b_dx, whist_b, b_hist, W_feat, b_feat,
                                    W_wc, b_wc, wihx_b, wihm_b, whh_b, b_ih, b_hh, W_cls, b_cls,
                                    h0, out, nump);
    k_loss<<<1, 64, 0, stream>>>(nump, den, out);
}

// Round 12
// 591.800 us; speedup vs baseline: 3.5972x; 1.0570x over previous
//
#include <hip/hip_runtime.h>
#include <math.h>

#define B_  256
#define T_  48
#define D_  89
#define H_  128
#define C_  64
#define NH_ 8
#define HD_ 8
#define N2T 96   // 2*T

// output layout (floats)
#define XIMP_OFF 0
#define LOSS_OFF 1093632
#define HID_OFF  1093633
#define Y_OFF    2666497
#define YS_OFF   2666753

typedef unsigned int uint_t;
typedef _Float16 h2_t __attribute__((ext_vector_type(2)));

__device__ __forceinline__ float wave_sum64(float v) {
    v += __shfl_xor(v, 32);
    v += __shfl_xor(v, 16);
    v += __shfl_xor(v, 8);
    v += __shfl_xor(v, 4);
    v += __shfl_xor(v, 2);
    v += __shfl_xor(v, 1);
    return v;
}

__device__ __forceinline__ uint_t packh2(float lo, float hi) {
    union { h2_t h; uint_t u; } c;
    c.h.x = (_Float16)lo;
    c.h.y = (_Float16)hi;
    return c.u;
}
__device__ __forceinline__ h2_t as_h2(uint_t u) {
    union { uint_t u; h2_t h; } c;
    c.u = u;
    return c.h;
}
// 2-MAC f16 dot: acc += w.x*ax + w.y*ay
__device__ __forceinline__ float dot2(uint_t w, float ax, float ay, float acc) {
#if __has_builtin(__builtin_amdgcn_fdot2) && __has_builtin(__builtin_amdgcn_cvt_pkrtz)
    return __builtin_amdgcn_fdot2(as_h2(w), __builtin_amdgcn_cvt_pkrtz(ax, ay), acc, false);
#else
    h2_t h = as_h2(w);
    return fmaf((float)h.y, ay, fmaf((float)h.x, ax, acc));
#endif
}
__device__ __forceinline__ float sigm(float v) { return 1.f / (1.f + __expf(-v)); }

// K=96 dot (48 packed uints/row), activations f32 in LDS, 8 j-slices
#define DOT96(W, A, acc) do { \
    _Pragma("unroll") \
    for (int it_ = 0; it_ < 3; ++it_) { \
        int idx_ = jj + 8 * it_; \
        uint2 w_ = ((const uint2*)(W))[idx_]; \
        float4 a_ = *(const float4*)((A) + 4 * idx_); \
        acc = dot2(w_.x, a_.x, a_.y, acc); \
        acc = dot2(w_.y, a_.z, a_.w, acc); \
    } } while (0)

// K=128 dot (64 packed uints/row)
#define DOT128(W, A, acc) do { \
    _Pragma("unroll") \
    for (int it_ = 0; it_ < 4; ++it_) { \
        int idx_ = jj + 8 * it_; \
        uint2 w_ = ((const uint2*)(W))[idx_]; \
        float4 a_ = *(const float4*)((A) + 4 * idx_); \
        acc = dot2(w_.x, a_.x, a_.y, acc); \
        acc = dot2(w_.y, a_.z, a_.w, acc); \
    } } while (0)

// ---------------- prep: f32 transposes for the transformer-phase kernels only
__device__ __forceinline__ void tr_f32(const float* __restrict__ s, float* __restrict__ d,
                                       int li, int R, int C) {
    int r = li / C, c = li - r * C;
    d[c * R + r] = s[li];
}

__global__ void k_prep(const float* W_wo, const float* W_inp, const float* ain_w,
                       const float* aout_w, const float* ff1_w, const float* ff2_w,
                       const float* W_op1,
                       float* W_woT, float* W_inpT, float* ain_T,
                       float* aout_T, float* ff1_T, float* ff2_T, float* op1_T) {
    int i = blockIdx.x * 256 + threadIdx.x;
    if (i < 7921)         tr_f32(W_wo,   W_woT,  i,          89, 89);
    else if (i < 13617)   tr_f32(W_inp,  W_inpT, i - 7921,   64, 89);
    else if (i < 25905)   tr_f32(ain_w,  ain_T,  i - 13617, 192, 64);
    else if (i < 30001)   tr_f32(aout_w, aout_T, i - 25905,  64, 64);
    else if (i < 34097)   tr_f32(ff1_w,  ff1_T,  i - 30001,  64, 64);
    else if (i < 38193)   tr_f32(ff2_w,  ff2_T,  i - 34097,  64, 64);
    else if (i < 46385)   tr_f32(W_op1,  op1_T,  i - 38193, 128, 64);
}

// ---------------- pack scan weights to f16x2 row-major, rows padded to 48/64 uints
__global__ void k_pack(const float* __restrict__ W_dh, const float* __restrict__ W_hist,
                       const float* __restrict__ W_ih, const float* __restrict__ W_hh,
                       uint_t* __restrict__ wdh_h, uint_t* __restrict__ whist_h,
                       uint_t* __restrict__ wihx_h, uint_t* __restrict__ wihm_h,
                       uint_t* __restrict__ whh_h) {
    int i = blockIdx.x * 256 + threadIdx.x;
    if (i < 6144) {                        // W_dh: 128 x 48 (K=89 padded to 96)
        int r = i / 48, c = i - r * 48;
        const float* src = W_dh + r * 89;
        float lo = (c < 45) ? src[2 * c] : 0.f;
        float hi = (c < 44) ? src[2 * c + 1] : 0.f;
        wdh_h[i] = packh2(lo, hi);
    } else if (i < 11840) {                // W_hist: 89 x 64 (K=128)
        int j = i - 6144;
        int r = j / 64, c = j - r * 64;
        const float* src = W_hist + r * 128;
        whist_h[j] = packh2(src[2 * c], src[2 * c + 1]);
    } else if (i < 30272) {                // W_ih x-part: 384 x 48 (cols 0..88)
        int j = i - 11840;
        int r = j / 48, c = j - r * 48;
        const float* src = W_ih + (size_t)r * 178;
        float lo = (c < 45) ? src[2 * c] : 0.f;
        float hi = (c < 44) ? src[2 * c + 1] : 0.f;
        wihx_h[j] = packh2(lo, hi);
    } else if (i < 48704) {                // W_ih m-part: 384 x 48 (cols 89..177)
        int j = i - 30272;
        int r = j / 48, c = j - r * 48;
        const float* src = W_ih + (size_t)r * 178 + 89;
        float lo = (c < 45) ? src[2 * c] : 0.f;
        float hi = (c < 44) ? src[2 * c + 1] : 0.f;
        wihm_h[j] = packh2(lo, hi);
    } else if (i < 73280) {                // W_hh: 384 x 64 (K=128)
        int j = i - 48704;
        int r = j / 64, c = j - r * 64;
        const float* src = W_hh + (size_t)r * 128;
        whh_h[j] = packh2(src[2 * c], src[2 * c + 1]);
    }
}

// ---------------- Phase A
__global__ void k_phaseA(const float* __restrict__ last_obs,
                         const float* __restrict__ deltas,
                         const float* __restrict__ medians,
                         const float* __restrict__ W_woT, const float* __restrict__ b_wo,
                         const float* __restrict__ W_inpT, const float* __restrict__ b_inp,
                         float* __restrict__ data) {
    int bt = blockIdx.x;
    int b = bt / T_;
    int t = bt - b * T_;
    __shared__ float dd[D_], lo[D_], dec[D_];
    int tid = threadIdx.x;
    int base = (b * T_ + t) * D_;
    if (tid < D_) {
        float dv = deltas[base + tid] - medians[tid];
        dd[tid] = dv;
        lo[tid] = last_obs[base + tid];
    }
    __syncthreads();
    if (tid < D_) {
        float acc = b_wo[tid];
        for (int j = 0; j < D_; ++j) acc = fmaf(dd[j], W_woT[j * D_ + tid], acc);
        float dv = dd[tid];
        float s = (dv > 0.f) ? 1.f : ((dv < 0.f) ? -1.f : 0.f);
        dec[tid] = 0.5f * (1.f - tanhf(s * fabsf(acc)));
    }
    __syncthreads();
    int c = tid & 63;
    int half = tid >> 6;
    const float* src = half ? dec : lo;
    float acc = b_inp[c];
    for (int j = 0; j < D_; ++j) acc = fmaf(src[j], W_inpT[j * C_ + c], acc);
    int i = c >> 1;
    float div = __expf((float)i * -0.28782313662425574f);
    float ang = (float)t * div;
    float pe = (c & 1) ? cosf(ang) : sinf(ang);
    data[((b * N2T) + half * T_ + t) * C_ + c] = acc + pe;
}

// ---------------- qkv
__global__ void k_qkv(const float* __restrict__ data,
                      const float* __restrict__ ain_T, const float* __restrict__ ain_b,
                      float* __restrict__ qb, float* __restrict__ kb, float* __restrict__ vb) {
    int bn = blockIdx.x;
    int s = bn / N2T;
    int n = bn - s * N2T;
    __shared__ float row[C_];
    int tid = threadIdx.x;
    if (tid < C_) row[tid] = data[bn * C_ + tid];
    __syncthreads();
    float acc = ain_b[tid];
    for (int j = 0; j < C_; ++j) acc = fmaf(row[j], ain_T[j * 192 + tid], acc);
    int part = tid >> 6;
    int c = tid & 63;
    int h = c >> 3, d = c & 7;
    float* dst = (part == 0) ? qb : ((part == 1) ? kb : vb);
    dst[(((n * NH_ + h) * B_ + s) * HD_) + d] = acc;
}

// ---------------- attention
__global__ void k_attn(const float* __restrict__ qb, const float* __restrict__ kb,
                       const float* __restrict__ vb, float* __restrict__ attnO) {
    int n = blockIdx.x >> 3;
    int h = blockIdx.x & 7;
    __shared__ float k_lds[B_][HD_ + 1];
    __shared__ float v_lds[B_][HD_ + 1];
    int s = threadIdx.x;
    const float scale = 0.35355339059327373f;
    size_t base = ((size_t)blockIdx.x * B_ + s) * HD_;
    float q[HD_];
    #pragma unroll
    for (int d = 0; d < HD_; ++d) q[d] = qb[base + d] * scale;
    #pragma unroll
    for (int d = 0; d < HD_; ++d) { k_lds[s][d] = kb[base + d]; v_lds[s][d] = vb[base + d]; }
    __syncthreads();
    float m = -1e30f;
    for (int t = 0; t < B_; ++t) {
        float sc = 0.f;
        #pragma unroll
        for (int d = 0; d < HD_; ++d) sc = fmaf(q[d], k_lds[t][d], sc);
        m = fmaxf(m, sc);
    }
    float l = 0.f;
    float acc[HD_] = {0.f, 0.f, 0.f, 0.f, 0.f, 0.f, 0.f, 0.f};
    for (int t = 0; t < B_; ++t) {
        float sc = 0.f;
        #pragma unroll
        for (int d = 0; d < HD_; ++d) sc = fmaf(q[d], k_lds[t][d], sc);
        float p = __expf(sc - m);
        l += p;
        #pragma unroll
        for (int d = 0; d < HD_; ++d) acc[d] = fmaf(p, v_lds[t][d], acc[d]);
    }
    float inv = 1.f / l;
    float* op = attnO + ((size_t)s * N2T + n) * C_ + h * HD_;
    #pragma unroll
    for (int d = 0; d < HD_; ++d) op[d] = acc[d] * inv;
}

// ---------------- transformer post-attn
__global__ void k_transform(const float* __restrict__ data,
                            const float* __restrict__ attnO,
                            const float* __restrict__ aout_T, const float* __restrict__ aout_b,
                            const float* __restrict__ ln1_g, const float* __restrict__ ln1_b,
                            const float* __restrict__ ff1_T, const float* __restrict__ ff1_b,
                            const float* __restrict__ ff2_T, const float* __restrict__ ff2_b,
                            const float* __restrict__ ln2_g, const float* __restrict__ ln2_b,
                            const float* __restrict__ op1_T, const float* __restrict__ b_op1,
                            float* __restrict__ val) {
    int bn = blockIdx.x;
    __shared__ float orow[C_], x1s[C_], hbuf[C_], x2s[C_];
    int c = threadIdx.x;
    float d0 = data[bn * C_ + c];
    orow[c] = attnO[bn * C_ + c];
    __syncthreads();
    float acc = aout_b[c];
    for (int j = 0; j < C_; ++j) acc = fmaf(orow[j], aout_T[j * C_ + c], acc);
    float r = d0 + acc;
    float mean = wave_sum64(r) * (1.f / 64.f);
    float df = r - mean;
    float var = wave_sum64(df * df) * (1.f / 64.f);
    float x1 = df * rsqrtf(var + 1e-5f) * ln1_g[c] + ln1_b[c];
    x1s[c] = x1;
    __syncthreads();
    acc = ff1_b[c];
    for (int j = 0; j < C_; ++j) acc = fmaf(x1s[j], ff1_T[j * C_ + c], acc);
    float ge = 0.5f * acc * (1.f + erff(acc * 0.7071067811865475f));
    hbuf[c] = ge;
    __syncthreads();
    acc = ff2_b[c];
    for (int j = 0; j < C_; ++j) acc = fmaf(hbuf[j], ff2_T[j * C_ + c], acc);
    float r2 = x1 + acc;
    float mean2 = wave_sum64(r2) * (1.f / 64.f);
    float df2 = r2 - mean2;
    float var2 = wave_sum64(df2 * df2) * (1.f / 64.f);
    float x2 = df2 * rsqrtf(var2 + 1e-5f) * ln2_g[c] + ln2_b[c];
    x2s[c] = x2;
    __syncthreads();
    #pragma unroll
    for (int rep = 0; rep < 2; ++rep) {
        int k = c + rep * 64;
        float a2 = b_op1[k];
        for (int j = 0; j < C_; ++j) a2 = fmaf(x2s[j], op1_T[j * H_ + k], a2);
        val[(size_t)bn * H_ + k] = a2;
    }
}

// ---------------- h0 reduce
__global__ void k_reduce_h0(const float* __restrict__ val,
                            const float* __restrict__ W_op2, const float* __restrict__ b_op2,
                            float* __restrict__ h0) {
    int b = blockIdx.x;
    int h = threadIdx.x;
    float acc = b_op2[0];
    for (int n = 0; n < N2T; ++n)
        acc = fmaf(val[((size_t)b * N2T + n) * H_ + h], W_op2[n], acc);
    h0[b * H_ + h] = acc;
}

// ---------------- per-step mask denominator
__global__ void k_den(const float* __restrict__ mask, float* __restrict__ den) {
    int t = blockIdx.x;
    int tid = threadIdx.x;
    float s = 0.f;
    const int total = B_ * D_;
    for (int i = tid; i < total; i += 256) {
        int b = i / D_;
        int d = i - b * D_;
        s += mask[(b * T_ + t) * D_ + d];
    }
    s = wave_sum64(s);
    __shared__ float red[4];
    if ((tid & 63) == 0) red[tid >> 6] = s;
    __syncthreads();
    if (tid == 0) den[t] = red[0] + red[1] + red[2] + red[3];
}

// ---------------- recurrent scan: 256 blocks x 1024 threads (16 waves), 1 batch/block.
// Round-11 phase structure; inner loops rebuilt: f16x2 weights + v_dot2_f32_f16
// (cvt_pkrtz on f32 LDS activations), uint2 weight loads (full 64B line per row),
// float4 activation reads. Rows padded to K=96/128 with zeroed pads on both
// weights and activations.
__global__ __launch_bounds__(1024)
void k_scan(const float* __restrict__ x, const float* __restrict__ mask,
            const float* __restrict__ deltas,
            const uint_t* __restrict__ wdh_h, const float* __restrict__ b_dh,
            const float* __restrict__ W_dx, const float* __restrict__ b_dx,
            const uint_t* __restrict__ whist_h, const float* __restrict__ b_hist,
            const float* __restrict__ W_feat, const float* __restrict__ b_feat,
            const float* __restrict__ W_wc, const float* __restrict__ b_wc,
            const uint_t* __restrict__ wihx_h, const uint_t* __restrict__ wihm_h,
            const uint_t* __restrict__ whh_h,
            const float* __restrict__ b_ih, const float* __restrict__ b_hh,
            const float* __restrict__ W_cls, const float* __restrict__ b_cls,
            const float* __restrict__ h0,
            float* __restrict__ out, float* __restrict__ num_part) {
    int b = blockIdx.x;
    int tid = threadIdx.x;
    int wave = tid >> 6;
    int lane = tid & 63;
    int oo = lane >> 3;       // row within chunk
    int jj = lane & 7;        // j-slice

    __shared__ __align__(16) float h_s[H_];
    __shared__ __align__(16) float xt_s[96], dt_s[96], xr_s[96], xh_s[96];
    __shared__ __align__(16) float m_s[96], gx_s[96], ximp_s[96], beta_s[96], diff_s[96];
    __shared__ __align__(16) float gis[384], ghs[384];
    __shared__ __align__(16) uint_t wwcg_l[89 * 48];  // W_wc gx-half f16x2
    __shared__ __align__(16) uint_t wwcm_l[89 * 48];  // W_wc m-half f16x2
    __shared__ __align__(16) uint_t wfeat_l[89 * 48]; // W_feat f16x2 (diag=0)

    // per-thread scalars for the gx-at-prefetch role (threads 320..408)
    float dxw = 0.f, dxb = 0.f;
    if (tid >= 320 && tid < 409) {
        int o = tid - 320;
        dxw = W_dx[o * 90];
        dxb = b_dx[o];
    }

    // ---- one-time LDS staging (f16x2, rows padded to 48 uints)
    for (int i = tid; i < 89 * 48; i += 1024) {
        int r = i / 48, c = i - r * 48;
        const float* wr = W_wc + (size_t)r * 178;
        float lo = (c < 45) ? wr[2 * c] : 0.f;
        float hi = (c < 44) ? wr[2 * c + 1] : 0.f;
        wwcg_l[i] = packh2(lo, hi);
        const float* wm = wr + 89;
        float lo2 = (c < 45) ? wm[2 * c] : 0.f;
        float hi2 = (c < 44) ? wm[2 * c + 1] : 0.f;
        wwcm_l[i] = packh2(lo2, hi2);
        const float* wf = W_feat + r * 89;
        float lo3 = (c < 45 && 2 * c != r) ? wf[2 * c] : 0.f;
        float hi3 = (c < 44 && 2 * c + 1 != r) ? wf[2 * c + 1] : 0.f;
        wfeat_l[i] = packh2(lo3, hi3);
    }
    if (tid < 128) h_s[tid] = h0[b * H_ + tid];
    if (tid >= 416 && tid < 423) {        // zero pads 89..95 on dot-read arrays
        int l = tid - 416;
        dt_s[89 + l] = 0.f; xr_s[89 + l] = 0.f; m_s[89 + l] = 0.f;
        gx_s[89 + l] = 0.f; ximp_s[89 + l] = 0.f;
    }
    {
        int base = b * T_ * D_;
        if (tid >= 128 && tid < 217) xt_s[tid - 128] = x[base + tid - 128];
        else if (tid >= 224 && tid < 313) m_s[tid - 224] = mask[base + tid - 224];
        else if (tid >= 320 && tid < 409) {
            int o = tid - 320;
            float dv = deltas[base + o];
            dt_s[o] = dv;
            gx_s[o] = __expf(-fmaxf(dv * dxw + dxb, 0.f));
        }
    }
    __syncthreads();

    for (int t = 0; t < T_; ++t) {
        // ---- P1: h-decay (16 chunks) | beta (12 chunks) | gi_m (48 chunks)
        for (int c = wave; c < 76; c += 16) {
            if (c < 16) {
                int o = c * 8 + oo;
                float acc = 0.f;
                DOT96(wdh_h + o * 48, dt_s, acc);
                acc += __shfl_xor(acc, 1); acc += __shfl_xor(acc, 2); acc += __shfl_xor(acc, 4);
                if (jj == 0) h_s[o] *= __expf(-fmaxf(acc + b_dh[o], 0.f));
            } else if (c < 28) {
                int o = (c - 16) * 8 + oo;
                int ro = (o < 89) ? o : 88;
                float acc = 0.f;
                DOT96(wwcg_l + ro * 48, gx_s, acc);
                DOT96(wwcm_l + ro * 48, m_s, acc);
                acc += __shfl_xor(acc, 1); acc += __shfl_xor(acc, 2); acc += __shfl_xor(acc, 4);
                if (jj == 0 && o < 89) beta_s[o] = acc + b_wc[o];
            } else {
                int o = (c - 28) * 8 + oo;
                float acc = 0.f;
                DOT96(wihm_h + o * 48, m_s, acc);
                acc += __shfl_xor(acc, 1); acc += __shfl_xor(acc, 2); acc += __shfl_xor(acc, 4);
                if (jj == 0) gis[o] = acc + b_ih[o];
            }
        }
        __syncthreads();
        // ---- P2: x_h (chunks 0-11) + gh (chunks 12-59). Both K=128 over h_s.
        for (int c = wave; c < 60; c += 16) {
            if (c < 12) {
                int o = c * 8 + oo;
                int ro = (o < 89) ? o : 88;
                float acc = 0.f;
                DOT128(whist_h + ro * 64, h_s, acc);
                acc += __shfl_xor(acc, 1); acc += __shfl_xor(acc, 2); acc += __shfl_xor(acc, 4);
                if (jj == 0 && o < 89) {
                    float xh = acc + b_hist[o];
                    xh_s[o] = xh;
                    float m = m_s[o];
                    xr_s[o] = m * xt_s[o] + (1.f - m) * xh;
                }
            } else {
                int o = (c - 12) * 8 + oo;
                float acc = 0.f;
                DOT128(whh_h + o * 64, h_s, acc);
                acc += __shfl_xor(acc, 1); acc += __shfl_xor(acc, 2); acc += __shfl_xor(acc, 4);
                if (jj == 0) ghs[o] = acc + b_hh[o];
            }
        }
        __syncthreads();
        // ---- P3: xu dot (12 chunks) + combine using precomputed beta.
        for (int c = wave; c < 12; c += 16) {
            int o = c * 8 + oo;
            int ro = (o < 89) ? o : 88;
            float xu = 0.f;
            DOT96(wfeat_l + ro * 48, xr_s, xu);
            xu += __shfl_xor(xu, 1); xu += __shfl_xor(xu, 2); xu += __shfl_xor(xu, 4);
            if (jj == 0 && o < 89) {
                float xuf = xu + b_feat[o];
                float btf = beta_s[o];
                float xc = btf * xuf + (1.f - btf) * xh_s[o];
                float m = m_s[o];
                float xtv = xt_s[o];
                float xi = m * xtv + (1.f - m) * xc;
                ximp_s[o] = xi;
                out[XIMP_OFF + (b * T_ + t) * D_ + o] = xi;
                diff_s[o] = fabsf(xtv - xc) * m;
            }
        }
        __syncthreads();
        // ---- P4: gi_x = W_ih[:, :89] . ximp (48 chunks, half-width).
        for (int c = wave; c < 48; c += 16) {
            int o = c * 8 + oo;
            float acc = 0.f;
            DOT96(wihx_h + o * 48, ximp_s, acc);
            acc += __shfl_xor(acc, 1); acc += __shfl_xor(acc, 2); acc += __shfl_xor(acc, 4);
            if (jj == 0) gis[o] += acc;
        }
        __syncthreads();
        // ---- P5: GRU (waves 0-1) | prefetch+gx (tid 128-408) | loss (wave 15)
        if (tid < 128) {
            float r = sigm(gis[tid] + ghs[tid]);
            float z = sigm(gis[128 + tid] + ghs[128 + tid]);
            float g = tanhf(gis[256 + tid] + r * ghs[256 + tid]);
            float hn = (1.f - z) * g + z * h_s[tid];
            h_s[tid] = hn;
            out[HID_OFF + (size_t)(b * T_ + t) * H_ + tid] = hn;
        } else if (tid >= 960) {
            int l = tid - 960;
            float s = diff_s[l] + ((l < 25) ? diff_s[64 + l] : 0.f);
            s = wave_sum64(s);
            if (l == 0) num_part[t * B_ + b] = s;
        } else if (t + 1 < T_) {
            int nb = (b * T_ + t + 1) * D_;
            if (tid < 217) xt_s[tid - 128] = x[nb + tid - 128];
            else if (tid >= 224 && tid < 313) m_s[tid - 224] = mask[nb + tid - 224];
            else if (tid >= 320 && tid < 409) {
                int o = tid - 320;
                float dv = deltas[nb + o];
                dt_s[o] = dv;
                gx_s[o] = __expf(-fmaxf(dv * dxw + dxb, 0.f));
            }
        }
        __syncthreads();
    }
    // classifier
    if (tid < 64) {
        float p = h_s[tid] * W_cls[tid] + h_s[tid + 64] * W_cls[tid + 64];
        p = wave_sum64(p);
        if (tid == 0) {
            float y = p + b_cls[0];
            out[Y_OFF + b] = y;
            out[YS_OFF + b] = 1.f / (1.f + __expf(-y));
        }
    }
}

// ---------------- final loss reduction
__global__ void k_loss(const float* __restrict__ num_part, const float* __restrict__ den,
                       float* __restrict__ out) {
    int tid = threadIdx.x;
    float v = 0.f;
    if (tid < T_) {
        float s = 0.f;
        const float* np_ = num_part + tid * B_;
        for (int b = 0; b < B_; ++b) s += np_[b];
        v = s / (den[tid] + 1e-5f);
    }
    v = wave_sum64(v);
    if (tid == 0) out[LOSS_OFF] = v;
}

extern "C" void kernel_launch(void* const* d_in, const int* in_sizes, int n_in,
                              void* d_out, int out_size, void* d_ws, size_t ws_size,
                              hipStream_t stream) {
    const float* x        = (const float*)d_in[0];
    const float* mask     = (const float*)d_in[1];
    const float* deltas   = (const float*)d_in[2];
    const float* last_obs = (const float*)d_in[3];
    const float* medians  = (const float*)d_in[4];
    const float* W_dh  = (const float*)d_in[5];
    const float* b_dh  = (const float*)d_in[6];
    const float* W_dx  = (const float*)d_in[7];
    const float* b_dx  = (const float*)d_in[8];
    const float* W_hist= (const float*)d_in[9];
    const float* b_hist= (const float*)d_in[10];
    const float* W_feat= (const float*)d_in[11];
    const float* b_feat= (const float*)d_in[12];
    const float* W_wc  = (const float*)d_in[13];
    const float* b_wc  = (const float*)d_in[14];
    const float* W_wo  = (const float*)d_in[15];
    const float* b_wo  = (const float*)d_in[16];
    const float* W_cls = (const float*)d_in[17];
    const float* b_cls = (const float*)d_in[18];
    const float* W_ih  = (const float*)d_in[19];
    const float* W_hh  = (const float*)d_in[20];
    const float* b_ih  = (const float*)d_in[21];
    const float* b_hh  = (const float*)d_in[22];
    const float* W_inp = (const float*)d_in[23];
    const float* b_inp = (const float*)d_in[24];
    const float* W_op1 = (const float*)d_in[25];
    const float* b_op1 = (const float*)d_in[26];
    const float* W_op2 = (const float*)d_in[27];
    const float* b_op2 = (const float*)d_in[28];
    const float* attn_in_w  = (const float*)d_in[29];
    const float* attn_in_b  = (const float*)d_in[30];
    const float* attn_out_w = (const float*)d_in[31];
    const float* attn_out_b = (const float*)d_in[32];
    const float* ln1_g = (const float*)d_in[33];
    const float* ln1_b = (const float*)d_in[34];
    const float* ln2_g = (const float*)d_in[35];
    const float* ln2_b = (const float*)d_in[36];
    const float* ff1_w = (const float*)d_in[37];
    const float* ff1_b = (const float*)d_in[38];
    const float* ff2_w = (const float*)d_in[39];
    const float* ff2_b = (const float*)d_in[40];

    float* out = (float*)d_out;
    float* ws = (float*)d_ws;

    float* data  = ws;
    float* qb    = data  + (size_t)B_ * N2T * C_;
    float* kb    = qb    + (size_t)N2T * NH_ * B_ * HD_;
    float* vb    = kb    + (size_t)N2T * NH_ * B_ * HD_;
    float* attnO = vb    + (size_t)N2T * NH_ * B_ * HD_;
    float* val   = attnO + (size_t)B_ * N2T * C_;
    float* h0    = val   + (size_t)B_ * N2T * H_;
    float* den   = h0    + (size_t)B_ * H_;
    float* nump  = den   + 64;
    float* W_woT = nump  + T_ * B_;
    float* W_inpT= W_woT + 7921;
    float* ain_T = W_inpT + 5696;
    float* aout_T= ain_T + 12288;
    float* ff1_T = aout_T + 4096;
    float* ff2_T = ff1_T + 4096;
    float* op1_T = ff2_T + 4096;
    uint_t* wdh_h   = (uint_t*)(op1_T + 8192);
    uint_t* whist_h = wdh_h + 6144;
    uint_t* wihx_h  = whist_h + 5696;
    uint_t* wihm_h  = wihx_h + 18432;
    uint_t* whh_h   = wihm_h + 18432;

    k_prep<<<182, 256, 0, stream>>>(W_wo, W_inp, attn_in_w, attn_out_w, ff1_w, ff2_w, W_op1,
                                    W_woT, W_inpT, ain_T, aout_T, ff1_T, ff2_T, op1_T);
    k_pack<<<287, 256, 0, stream>>>(W_dh, W_hist, W_ih, W_hh,
                                    wdh_h, whist_h, wihx_h, wihm_h, whh_h);
    k_phaseA<<<B_ * T_, 128, 0, stream>>>(last_obs, deltas, medians, W_woT, b_wo, W_inpT, b_inp, data);
    k_qkv<<<B_ * N2T, 192, 0, stream>>>(data, ain_T, attn_in_b, qb, kb, vb);
    k_attn<<<N2T * NH_, 256, 0, stream>>>(qb, kb, vb, attnO);
    k_transform<<<B_ * N2T, 64, 0, stream>>>(data, attnO, aout_T, attn_out_b,
                                             ln1_g, ln1_b, ff1_T, ff1_b, ff2_T, ff2_b,
                                             ln2_g, ln2_b, op1_T, b_op1, val);
    k_reduce_h0<<<B_, H_, 0, stream>>>(val, W_op2, b_op2, h0);
    k_den<<<T_, 256, 0, stream>>>(mask, den);
    k_scan<<<B_, 1024, 0, stream>>>(x, mask, deltas,
                                    wdh_h, b_dh, W_dx, b_dx, whist_h, b_hist, W_feat, b_feat,
                                    W_wc, b_wc, wihx_h, wihm_h, whh_h, b_ih, b_hh, W_cls, b_cls,
                                    h0, out, nump);
    k_loss<<<1, 64, 0, stream>>>(nump, den, out);
}